// Round 3
// baseline (46570.221 us; speedup 1.0000x reference)
//
#include <hip/hip_runtime.h>
#include <math.h>
#include <stdint.h>

typedef unsigned int u32;

// ---------------- Threefry-2x32 (20 rounds), matches JAX ----------------
__host__ __device__ __forceinline__ u32 rotl32(u32 x, int r) { return (x << r) | (x >> (32 - r)); }
__host__ __device__ __forceinline__ void tf_round(u32& x0, u32& x1, int r) {
  x0 += x1; x1 = rotl32(x1, r); x1 ^= x0;
}
__host__ __device__ __forceinline__ void tf_block(u32 k0, u32 k1, u32 x0, u32 x1, u32& o0, u32& o1) {
  u32 k2 = k0 ^ k1 ^ 0x1BD11BDAu;
  x0 += k0; x1 += k1;
  tf_round(x0,x1,13); tf_round(x0,x1,15); tf_round(x0,x1,26); tf_round(x0,x1,6);
  x0 += k1; x1 += k2 + 1u;
  tf_round(x0,x1,17); tf_round(x0,x1,29); tf_round(x0,x1,16); tf_round(x0,x1,24);
  x0 += k2; x1 += k0 + 2u;
  tf_round(x0,x1,13); tf_round(x0,x1,15); tf_round(x0,x1,26); tf_round(x0,x1,6);
  x0 += k0; x1 += k1 + 3u;
  tf_round(x0,x1,17); tf_round(x0,x1,29); tf_round(x0,x1,16); tf_round(x0,x1,24);
  x0 += k1; x1 += k2 + 4u;
  tf_round(x0,x1,13); tf_round(x0,x1,15); tf_round(x0,x1,26); tf_round(x0,x1,6);
  x0 += k2; x1 += k0 + 5u;
  o0 = x0; o1 = x1;
}

// idx[i] = (w0 ^ w1) & mask for block(k2,(0,i)) where k2 = split(fold_key)[1] (randint internals)
__global__ void k_idx(u32 ka, u32 kb, int n, int mask, int* __restrict__ idx) {
  int i = blockIdx.x * 256 + threadIdx.x;
  if (i >= n) return;
  u32 b1, b2; tf_block(ka, kb, 0u, (u32)i, b1, b2);
  idx[i] = (int)((b1 ^ b2) & (u32)mask);
}

// ---------------- positional embedding ----------------
__global__ void k_pe(float* __restrict__ pe) {
  int i = blockIdx.x * 256 + threadIdx.x;
  if (i >= 2048 * 512) return;
  int t = i >> 9, o = i & 511;
  float arg = (float)((o >> 1) * 2) * (float)(-(log(10000.0) / 512.0));
  float div = (float)exp((double)arg);
  float ang32 = (float)t * div;
  double ang = (double)ang32;
  pe[i] = (float)((o & 1) ? cos(ang) : sin(ang));
}

// ---------------- embedding: circular conv(7->512,k3) + pe + mark proj ----------------
__global__ __launch_bounds__(256) void k_embed(
    const float* __restrict__ x, const float* __restrict__ mark,
    const float* __restrict__ tw, const float* __restrict__ mw,
    const float* __restrict__ pe, float* __restrict__ o, int L, int total) {
  int i = blockIdx.x * 256 + threadIdx.x;
  if (i >= total) return;
  int oo = i & 511;
  int bt = i >> 9;
  int t = bt % L;
  int b = bt / L;
  float acc = pe[(t << 9) + oo];
  #pragma unroll
  for (int k = 0; k < 3; ++k) {
    int st = t + k - 1; if (st < 0) st += L; else if (st >= L) st -= L;
    const float* xr = x + (size_t)(b * L + st) * 7;
    const float* wr = tw + oo * 21 + k;   // tw[o][i][k] at o*21 + i*3 + k
    #pragma unroll
    for (int ii = 0; ii < 7; ++ii) acc += xr[ii] * wr[ii * 3];
  }
  const float* mr = mark + (size_t)bt * 4;
  #pragma unroll
  for (int m = 0; m < 4; ++m) acc += mr[m] * mw[(m << 9) + oo];
  o[((size_t)bt << 9) + oo] = acc;
}

// ---------------- GEMM: C = act(A@W + bias) (+resid). 64x64 tile, 4x4/thread ----------------
// GATHER=1: circular 3-tap gather (distil conv), K=1536; ACT: 0 none, 1 gelu, 2 bn+elu
template<int GATHER, int ACT>
__global__ __launch_bounds__(256) void k_gemm(
    const float* __restrict__ A, const float* __restrict__ W,
    const float* __restrict__ bias, const float* __restrict__ resid,
    const float* __restrict__ bns, const float* __restrict__ bnb,
    float* __restrict__ C, int M, int N, int K, int L) {
  __shared__ float As[64][17];
  __shared__ float Ws[16][65];
  const int tx = threadIdx.x;
  const int bm = blockIdx.y << 6, bn = blockIdx.x << 6;
  const int tm = (tx >> 4) << 2, tn = (tx & 15) << 2;
  const int ar = tx >> 2, ac = (tx & 3) << 2;
  const int wr = tx >> 4, wc = (tx & 15) << 2;
  float acc[4][4] = {};
  int ab = 0, at = 0;
  if (GATHER) { int m = bm + ar; ab = m / L; at = m - ab * L; }
  for (int k0 = 0; k0 < K; k0 += 16) {
    float4 a4;
    if (GATHER) {
      int tap = (k0 + ac) >> 9;
      int ii  = (k0 + ac) & 511;
      int st = at + tap - 1; if (st < 0) st += L; else if (st >= L) st -= L;
      a4 = *(const float4*)(A + ((size_t)(ab * L + st) << 9) + ii);
    } else {
      a4 = *(const float4*)(A + (size_t)(bm + ar) * K + k0 + ac);
    }
    As[ar][ac] = a4.x; As[ar][ac+1] = a4.y; As[ar][ac+2] = a4.z; As[ar][ac+3] = a4.w;
    float4 w4 = *(const float4*)(W + (size_t)(k0 + wr) * N + bn + wc);
    Ws[wr][wc] = w4.x; Ws[wr][wc+1] = w4.y; Ws[wr][wc+2] = w4.z; Ws[wr][wc+3] = w4.w;
    __syncthreads();
    #pragma unroll
    for (int kk = 0; kk < 16; ++kk) {
      float a0 = As[tm][kk], a1 = As[tm+1][kk], a2 = As[tm+2][kk], a3 = As[tm+3][kk];
      float b0 = Ws[kk][tn], b1 = Ws[kk][tn+1], b2 = Ws[kk][tn+2], b3 = Ws[kk][tn+3];
      acc[0][0] += a0*b0; acc[0][1] += a0*b1; acc[0][2] += a0*b2; acc[0][3] += a0*b3;
      acc[1][0] += a1*b0; acc[1][1] += a1*b1; acc[1][2] += a1*b2; acc[1][3] += a1*b3;
      acc[2][0] += a2*b0; acc[2][1] += a2*b1; acc[2][2] += a2*b2; acc[2][3] += a2*b3;
      acc[3][0] += a3*b0; acc[3][1] += a3*b1; acc[3][2] += a3*b2; acc[3][3] += a3*b3;
    }
    __syncthreads();
  }
  #pragma unroll
  for (int i = 0; i < 4; ++i) {
    int m = bm + tm + i;
    #pragma unroll
    for (int j = 0; j < 4; ++j) {
      int n = bn + tn + j;
      float v = acc[i][j];
      if (bias) v += bias[n];
      if (ACT == 1) v = 0.5f * v * (1.0f + erff(v * 0.70710678118654752f));
      if (ACT == 2) { v = v * (bns[n] * 0.9999950000375f) + bnb[n]; v = v > 0.f ? v : expm1f(v); }
      if (resid) v += resid[(size_t)m * N + n];
      C[(size_t)m * N + n] = v;
    }
  }
}

// ---------------- LayerNorm over last dim 512 (in-place safe) ----------------
__global__ __launch_bounds__(256) void k_ln(const float* __restrict__ x,
    const float* __restrict__ g, const float* __restrict__ b, float* __restrict__ o) {
  int row = blockIdx.x, t = threadIdx.x;
  const float* xr = x + ((size_t)row << 9);
  float v0 = xr[t], v1 = xr[t + 256];
  float s = v0 + v1;
  #pragma unroll
  for (int off = 32; off; off >>= 1) s += __shfl_down(s, off);
  __shared__ float ls[4];
  if ((t & 63) == 0) ls[t >> 6] = s;
  __syncthreads();
  float mean = (ls[0] + ls[1] + ls[2] + ls[3]) * (1.f / 512.f);
  __syncthreads();
  float d0 = v0 - mean, d1 = v1 - mean;
  float q = d0 * d0 + d1 * d1;
  #pragma unroll
  for (int off = 32; off; off >>= 1) q += __shfl_down(q, off);
  if ((t & 63) == 0) ls[t >> 6] = q;
  __syncthreads();
  float var = (ls[0] + ls[1] + ls[2] + ls[3]) * (1.f / 512.f);
  float rs = rsqrtf(var + 1e-5f);
  float* orow = o + ((size_t)row << 9);
  orow[t] = d0 * rs * g[t] + b[t];
  orow[t + 256] = d1 * rs * g[t + 256] + b[t + 256];
}

// ---------------- per-batch M[h,l] = max_s(q.k_idx) - sum_s(q.k_idx)/Lk ----------------
__global__ __launch_bounds__(256) void k_qkM(const float* __restrict__ Q, const float* __restrict__ K,
    const int* __restrict__ idx, float* __restrict__ M, int Lq, int Lk, int U) {
  int wid = (blockIdx.x * 256 + threadIdx.x) >> 6;
  int lane = threadIdx.x & 63;
  int l = wid & (Lq - 1); int h = wid / Lq;
  float dot = 0.f;
  if (lane < U) {
    int kr = idx[l * U + lane];
    const float4* q4 = (const float4*)(Q + ((size_t)l << 9) + (h << 6));
    const float4* k4 = (const float4*)(K + ((size_t)kr << 9) + (h << 6));
    #pragma unroll
    for (int i = 0; i < 16; ++i) {
      float4 a = q4[i], c = k4[i];
      dot += a.x * c.x + a.y * c.y + a.z * c.z + a.w * c.w;
    }
  }
  float mx = (lane < U) ? dot : -INFINITY;
  float sm = (lane < U) ? dot : 0.f;
  #pragma unroll
  for (int off = 32; off; off >>= 1) {
    mx = fmaxf(mx, __shfl_xor(mx, off));
    sm += __shfl_xor(sm, off);
  }
  if (lane == 0) M[h * Lq + l] = mx - sm / (float)Lk;
}

// ---------------- per-batch: iterative top-u of M per head (ties -> lower index) ----------------
__global__ __launch_bounds__(256) void k_topk(const float* __restrict__ M, int* __restrict__ mtop,
                                              int Lq, int u) {
  __shared__ float vals[2048];
  __shared__ float rv[256];
  __shared__ int ri[256];
  int h = blockIdx.x, t = threadIdx.x;
  const float* Mr = M + (size_t)h * Lq;
  for (int i = t; i < Lq; i += 256) vals[i] = Mr[i];
  __syncthreads();
  for (int it = 0; it < u; ++it) {
    float bv = -INFINITY; int bi = 0x7fffffff;
    for (int i = t; i < Lq; i += 256) {
      float v = vals[i];
      if (v > bv || (v == bv && i < bi)) { bv = v; bi = i; }
    }
    rv[t] = bv; ri[t] = bi;
    __syncthreads();
    for (int s = 128; s; s >>= 1) {
      if (t < s) {
        float v = rv[t + s]; int i2 = ri[t + s];
        if (v > rv[t] || (v == rv[t] && i2 < ri[t])) { rv[t] = v; ri[t] = i2; }
      }
      __syncthreads();
    }
    if (t == 0) { mtop[h * u + it] = ri[0]; vals[ri[0]] = -INFINITY; }
    __syncthreads();
  }
}

// ---------------- ctx mean, phase 1: partial column sums over 16 segments ----------------
__global__ void k_cm1(const float* __restrict__ V, float* __restrict__ PS, int rows) {
  int bid = blockIdx.x;            // h*16 + seg
  int h = bid >> 4, seg = bid & 15, d = threadIdx.x;
  const float* vp = V + ((size_t)(seg * rows) << 9) + (h << 6) + d;
  float acc = 0.f;
  for (int r = 0; r < rows; ++r) acc += vp[(size_t)r << 9];
  PS[(bid << 6) + d] = acc;
}

// ---------------- ctx mean, phase 2: broadcast mean to all Lq rows ----------------
__global__ void k_cm2(const float* __restrict__ PS, float* __restrict__ AO, float invLk, int total) {
  int i = blockIdx.x * 256 + threadIdx.x;
  if (i >= total) return;
  int c = i & 511; int h = c >> 6; int d = c & 63;
  float acc = 0.f;
  #pragma unroll
  for (int s = 0; s < 16; ++s) acc += PS[(((h << 4) + s) << 6) + d];
  AO[i] = acc * invLk;
}

// ---------------- cumsum: seg sums -> exclusive scan -> apply ----------------
__global__ void k_cs1(const float* __restrict__ V, float* __restrict__ PS, int rows) {
  int bid = blockIdx.x;            // h*8 + seg
  int h = bid >> 3, seg = bid & 7, d = threadIdx.x;
  const float* vp = V + ((size_t)(seg * rows) << 9) + (h << 6) + d;
  float acc = 0.f;
  for (int r = 0; r < rows; ++r) acc += vp[(size_t)r << 9];
  PS[(bid << 6) + d] = acc;
}
__global__ void k_cs2(float* __restrict__ PS) {
  int h = blockIdx.x, d = threadIdx.x;
  float run = 0.f;
  for (int s = 0; s < 8; ++s) {
    int id = (((h << 3) + s) << 6) + d;
    float t0 = PS[id]; PS[id] = run; run += t0;
  }
}
__global__ void k_cs3(const float* __restrict__ V, const float* __restrict__ PS,
                      float* __restrict__ AO, int rows) {
  int bid = blockIdx.x;
  int h = bid >> 3, seg = bid & 7, d = threadIdx.x;
  float acc = PS[(bid << 6) + d];
  const float* vp = V + ((size_t)(seg * rows) << 9) + (h << 6) + d;
  float* op = AO + ((size_t)(seg * rows) << 9) + (h << 6) + d;
  for (int r = 0; r < rows; ++r) { acc += vp[(size_t)r << 9]; op[(size_t)r << 9] = acc; }
}

// ---------------- per-batch sparse attn: scores->softmax->PV, scatter into AO ----------------
__global__ __launch_bounds__(256) void k_sattn(const float* __restrict__ Q, const float* __restrict__ K,
    const float* __restrict__ V, const int* __restrict__ mtop, float* __restrict__ AO,
    int Lk, int u, int masked) {
  __shared__ float sc[2048];
  __shared__ float red[256];
  __shared__ float qs[64];
  int ui = blockIdx.x % u, h = blockIdx.x / u;
  int t = threadIdx.x;
  int row = mtop[h * u + ui];
  if (t < 64) qs[t] = Q[((size_t)row << 9) + (h << 6) + t];
  __syncthreads();
  float lmax = -INFINITY;
  for (int c = t; c < Lk; c += 256) {
    const float4* kr = (const float4*)(K + ((size_t)c << 9) + (h << 6));
    float d = 0.f;
    #pragma unroll
    for (int i = 0; i < 16; ++i) {
      float4 kv = kr[i];
      d += qs[4*i] * kv.x + qs[4*i+1] * kv.y + qs[4*i+2] * kv.z + qs[4*i+3] * kv.w;
    }
    d *= 0.125f;
    if (masked && c > row) d = -INFINITY;
    sc[c] = d;
    lmax = fmaxf(lmax, d);
  }
  red[t] = lmax; __syncthreads();
  for (int s = 128; s; s >>= 1) { if (t < s) red[t] = fmaxf(red[t], red[t + s]); __syncthreads(); }
  float mx = red[0]; __syncthreads();
  float lsum = 0.f;
  for (int c = t; c < Lk; c += 256) { float e = expf(sc[c] - mx); sc[c] = e; lsum += e; }
  red[t] = lsum; __syncthreads();
  for (int s = 128; s; s >>= 1) { if (t < s) red[t] += red[t + s]; __syncthreads(); }
  float S = red[0]; __syncthreads();
  int d = t & 63, grp = t >> 6;
  float acc = 0.f;
  for (int c = grp; c < Lk; c += 4) acc += sc[c] * V[((size_t)c << 9) + (h << 6) + d];
  red[t] = acc; __syncthreads();
  if (t < 64) {
    float r = red[t] + red[64 + t] + red[128 + t] + red[192 + t];
    AO[((size_t)row << 9) + (h << 6) + t] = r / S;
  }
}

// ---------------- distil weight repack: wr[(tap*512+i)*512+o] = w[o,i,tap] ----------------
__global__ void k_repack(const float* __restrict__ w, float* __restrict__ wr) {
  int i = blockIdx.x * 256 + threadIdx.x;
  if (i >= 1536 * 512) return;
  int o = i & 511, kk = i >> 9;
  int tap = kk >> 9, ii = kk & 511;
  wr[i] = w[((size_t)(o << 9) + ii) * 3 + tap];
}

// ---------------- maxpool window 3 stride 2 pad 1 along L ----------------
__global__ void k_maxpool(const float* __restrict__ y, float* __restrict__ o, int L) {
  int Lo = L >> 1;
  int i = blockIdx.x * 256 + threadIdx.x;
  int c = i & 511; int bj = i >> 9;
  int j = bj % Lo; int b = bj / Lo;
  float m = -INFINITY;
  int t0 = 2 * j - 1;
  #pragma unroll
  for (int k = 0; k < 3; ++k) {
    int tt = t0 + k;
    if (tt >= 0 && tt < L) m = fmaxf(m, y[((size_t)(b * L + tt) << 9) + c]);
  }
  o[((size_t)(b * Lo + j) << 9) + c] = m;
}

// ---------------- final projection 512->7 on last 512 rows ----------------
__global__ void k_proj(const float* __restrict__ Xn, const float* __restrict__ pw,
                       const float* __restrict__ pb, float* __restrict__ out) {
  int i = blockIdx.x * 256 + threadIdx.x;
  if (i >= 16 * 512 * 7) return;
  int c = i % 7; int r = i / 7;
  int b = r >> 9; int j = r & 511;
  const float* xr = Xn + ((size_t)(b * 1024 + 512 + j) << 9);
  float acc = pb[c];
  for (int d2 = 0; d2 < 512; ++d2) acc += xr[d2] * pw[d2 * 7 + c];
  out[i] = acc;
}

// =====================================================================
extern "C" void kernel_launch(void* const* d_in, const int* in_sizes, int n_in,
                              void* d_out, int out_size, void* d_ws, size_t ws_size,
                              hipStream_t stream) {
  const float* x_enc      = (const float*)d_in[0];
  const float* x_mark_enc = (const float*)d_in[1];
  const float* x_dec      = (const float*)d_in[2];
  const float* x_mark_dec = (const float*)d_in[3];
  const float* enc_tok_w  = (const float*)d_in[4];
  const float* enc_mark_w = (const float*)d_in[5];
  const float* dec_tok_w  = (const float*)d_in[6];
  const float* dec_mark_w = (const float*)d_in[7];
  const float* enc_attn_w = (const float*)d_in[8];
  const float* enc_attn_b = (const float*)d_in[9];
  const float* enc_ffn1_w = (const float*)d_in[10];
  const float* enc_ffn1_b = (const float*)d_in[11];
  const float* enc_ffn2_w = (const float*)d_in[12];
  const float* enc_ffn2_b = (const float*)d_in[13];
  const float* enc_ln_g   = (const float*)d_in[14];
  const float* enc_ln_b   = (const float*)d_in[15];
  const float* distil_w   = (const float*)d_in[16];
  const float* distil_b   = (const float*)d_in[17];
  const float* distil_bn_g= (const float*)d_in[18];
  const float* distil_bn_b= (const float*)d_in[19];
  const float* enc_norm_g = (const float*)d_in[20];
  const float* enc_norm_b = (const float*)d_in[21];
  const float* dec_self_w = (const float*)d_in[22];
  const float* dec_self_b = (const float*)d_in[23];
  const float* dec_cross_w= (const float*)d_in[24];
  const float* dec_cross_b= (const float*)d_in[25];
  const float* dec_ffn1_w = (const float*)d_in[26];
  const float* dec_ffn1_b = (const float*)d_in[27];
  const float* dec_ffn2_w = (const float*)d_in[28];
  const float* dec_ffn2_b = (const float*)d_in[29];
  const float* dec_ln_g   = (const float*)d_in[30];
  const float* dec_ln_b   = (const float*)d_in[31];
  const float* dec_norm_g = (const float*)d_in[32];
  const float* dec_norm_b = (const float*)d_in[33];
  const float* proj_w     = (const float*)d_in[34];
  const float* proj_b     = (const float*)d_in[35];

  // -------- workspace layout (floats) — total ~161 MiB --------
  float* ws = (float*)d_ws;
  float* X   = ws;                    // 16,777,216 (activations, in-place chain)
  float* Y   = X   + 16777216;        // 16,777,216 (FFN intermediate / distil out)
  float* Qs  = Y   + 16777216;        // 1,048,576 (per-batch)
  float* Ks  = Qs  + 1048576;
  float* Vs  = Ks  + 1048576;
  float* AOs = Vs  + 1048576;
  float* ENC = AOs + 1048576;         // 4,194,304
  float* PE  = ENC + 4194304;         // 1,048,576
  float* WR  = PE  + 1048576;         //   786,432
  float* Mb  = WR  + 786432;          //    16,384
  float* PS  = Mb  + 16384;           //     8,192
  int* IDXi  = (int*)(PS + 8192);     //    81,920 ints
  int* MTi   = IDXi + 81920;          //       512 ints
  {
    size_t needF = 16777216ull*2 + 1048576ull*4 + 4194304 + 1048576 + 786432 + 16384 + 8192;
    size_t needB = (needF + 81920 + 512) * 4;
    if (ws_size < needB) return;   // clean absmax-fail instead of fault (diagnostic)
  }

  auto ln = [&](const float* x, const float* g, const float* b, float* o, int rows) {
    k_ln<<<rows, 256, 0, stream>>>(x, g, b, o);
  };
  auto gemm = [&](const float* A, const float* W, const float* bias, const float* resid,
                  float* C, int M, int N, int K) {
    dim3 g(N >> 6, M >> 6);
    k_gemm<0, 0><<<g, 256, 0, stream>>>(A, W, bias, resid, nullptr, nullptr, C, M, N, K, 0);
  };
  auto gemmg = [&](const float* A, const float* W, const float* bias, float* C, int M, int N, int K) {
    dim3 g(N >> 6, M >> 6);
    k_gemm<0, 1><<<g, 256, 0, stream>>>(A, W, bias, nullptr, nullptr, nullptr, C, M, N, K, 0);
  };
  auto Uof = [](int Lx) { int v = 5 * (int)ceil(log((double)Lx)); return v < Lx ? v : Lx; };

  // per-batch ProbSparse attention; out_base may equal xq_base (in-place residual chain)
  auto attn = [&](const float* xq_base, const float* xkv_base, int Lq, int Lk, const float* w,
                  const float* bias, bool masked, u32 fold, float* out_base) {
    int U = Uof(Lk), uu = Uof(Lq);
    u32 r0, r1, ka, kb;
    tf_block(0u, 42u, 0u, fold, r0, r1);   // fold_in(key(42), fold)
    tf_block(r0, r1, 0u, 1u, ka, kb);      // randint internal: k2 = split(key)[1] (foldlike)
    int n = Lq * U;
    k_idx<<<(n + 255) / 256, 256, 0, stream>>>(ka, kb, n, Lk - 1, IDXi);
    for (int b = 0; b < 16; ++b) {
      const float* xq  = xq_base  + (size_t)b * Lq * 512;
      const float* xkv = xkv_base + (size_t)b * Lk * 512;
      float* outp      = out_base + (size_t)b * Lq * 512;
      gemm(xq,  w,          bias,        nullptr, Qs, Lq, 512, 512);
      gemm(xkv, w + 262144, bias + 512,  nullptr, Ks, Lk, 512, 512);
      gemm(xkv, w + 524288, bias + 1024, nullptr, Vs, Lk, 512, 512);
      k_qkM<<<(8 * Lq) / 4, 256, 0, stream>>>(Qs, Ks, IDXi, Mb, Lq, Lk, U);
      k_topk<<<8, 256, 0, stream>>>(Mb, MTi, Lq, uu);
      if (masked) {
        k_cs1<<<64, 64, 0, stream>>>(Vs, PS, Lq >> 3);
        k_cs2<<<8, 64, 0, stream>>>(PS);
        k_cs3<<<64, 64, 0, stream>>>(Vs, PS, AOs, Lq >> 3);
      } else {
        k_cm1<<<128, 64, 0, stream>>>(Vs, PS, Lk >> 4);
        k_cm2<<<(Lq * 512) / 256, 256, 0, stream>>>(PS, AOs, 1.0f / (float)Lk, Lq * 512);
      }
      k_sattn<<<8 * uu, 256, 0, stream>>>(Qs, Ks, Vs, MTi, AOs, Lk, uu, masked ? 1 : 0);
      gemm(AOs, w + 786432, bias + 1536, xq, outp, Lq, 512, 512);
    }
  };

  auto ffn = [&](float* x, const float* w1, const float* b1,
                 const float* w2, const float* b2, int Mtot) {
    for (int c0 = 0; c0 < Mtot; c0 += 8192) {
      gemmg(x + (size_t)c0 * 512, w1, b1, Y, 8192, 2048, 512);
      gemm(Y, w2, b2, x + (size_t)c0 * 512, x + (size_t)c0 * 512, 8192, 512, 2048);
    }
  };

  // ---------------- encoder ----------------
  k_pe<<<(2048 * 512) / 256, 256, 0, stream>>>(PE);
  k_embed<<<(16 * 2048 * 512) / 256, 256, 0, stream>>>(x_enc, x_mark_enc, enc_tok_w, enc_mark_w,
                                                       PE, X, 2048, 16 * 2048 * 512);
  int L = 2048;
  for (int l = 0; l < 3; ++l) {
    attn(X, X, L, L, enc_attn_w + (size_t)l * 4 * 262144, enc_attn_b + (size_t)l * 2048,
         false, (u32)l, X);
    ln(X, enc_ln_g + (size_t)(l * 2) * 512, enc_ln_b + (size_t)(l * 2) * 512, X, 16 * L);
    ffn(X, enc_ffn1_w + (size_t)l * 512 * 2048, enc_ffn1_b + (size_t)l * 2048,
        enc_ffn2_w + (size_t)l * 2048 * 512, enc_ffn2_b + (size_t)l * 512, 16 * L);
    ln(X, enc_ln_g + (size_t)(l * 2 + 1) * 512, enc_ln_b + (size_t)(l * 2 + 1) * 512, X, 16 * L);
    if (l < 2) {
      k_repack<<<(1536 * 512) / 256, 256, 0, stream>>>(distil_w + (size_t)l * 512 * 512 * 3, WR);
      dim3 g(8, (16 * L) >> 6);
      k_gemm<1, 2><<<g, 256, 0, stream>>>(X, WR, distil_b + (size_t)l * 512, nullptr,
          distil_bn_g + (size_t)l * 512, distil_bn_b + (size_t)l * 512, Y, 16 * L, 512, 1536, L);
      int Lo = L >> 1;
      k_maxpool<<<(16 * Lo * 512) / 256, 256, 0, stream>>>(Y, X, L);
      L = Lo;
    }
  }
  ln(X, enc_norm_g, enc_norm_b, ENC, 16 * 512);

  // ---------------- decoder (single in-place chain in X) ----------------
  k_embed<<<(16 * 1024 * 512) / 256, 256, 0, stream>>>(x_dec, x_mark_dec, dec_tok_w, dec_mark_w,
                                                       PE, X, 1024, 16 * 1024 * 512);
  for (int l = 0; l < 2; ++l) {
    attn(X, X, 1024, 1024, dec_self_w + (size_t)l * 4 * 262144, dec_self_b + (size_t)l * 2048,
         true, (u32)(100 + 2 * l), X);
    ln(X, dec_ln_g + (size_t)(l * 3) * 512, dec_ln_b + (size_t)(l * 3) * 512, X, 16384);
    attn(X, ENC, 1024, 512, dec_cross_w + (size_t)l * 4 * 262144, dec_cross_b + (size_t)l * 2048,
         false, (u32)(101 + 2 * l), X);
    ln(X, dec_ln_g + (size_t)(l * 3 + 1) * 512, dec_ln_b + (size_t)(l * 3 + 1) * 512, X, 16384);
    ffn(X, dec_ffn1_w + (size_t)l * 512 * 2048, dec_ffn1_b + (size_t)l * 2048,
        dec_ffn2_w + (size_t)l * 2048 * 512, dec_ffn2_b + (size_t)l * 512, 16384);
    ln(X, dec_ln_g + (size_t)(l * 3 + 2) * 512, dec_ln_b + (size_t)(l * 3 + 2) * 512, X, 16384);
  }
  ln(X, dec_norm_g, dec_norm_b, X, 16384);
  k_proj<<<(16 * 512 * 7 + 255) / 256, 256, 0, stream>>>(X, proj_w, proj_b, (float*)d_out);
}

// Round 4
// 15684.361 us; speedup vs baseline: 2.9692x; 2.9692x over previous
//
#include <hip/hip_runtime.h>
#include <math.h>
#include <stdint.h>

typedef unsigned int u32;
typedef _Float16 f16;
typedef __attribute__((ext_vector_type(8))) _Float16 f16x8;
typedef __attribute__((ext_vector_type(4))) float f32x4;

// ---------------- Threefry-2x32 (20 rounds), matches JAX ----------------
__host__ __device__ __forceinline__ u32 rotl32(u32 x, int r) { return (x << r) | (x >> (32 - r)); }
__host__ __device__ __forceinline__ void tf_round(u32& x0, u32& x1, int r) {
  x0 += x1; x1 = rotl32(x1, r); x1 ^= x0;
}
__host__ __device__ __forceinline__ void tf_block(u32 k0, u32 k1, u32 x0, u32 x1, u32& o0, u32& o1) {
  u32 k2 = k0 ^ k1 ^ 0x1BD11BDAu;
  x0 += k0; x1 += k1;
  tf_round(x0,x1,13); tf_round(x0,x1,15); tf_round(x0,x1,26); tf_round(x0,x1,6);
  x0 += k1; x1 += k2 + 1u;
  tf_round(x0,x1,17); tf_round(x0,x1,29); tf_round(x0,x1,16); tf_round(x0,x1,24);
  x0 += k2; x1 += k0 + 2u;
  tf_round(x0,x1,13); tf_round(x0,x1,15); tf_round(x0,x1,26); tf_round(x0,x1,6);
  x0 += k0; x1 += k1 + 3u;
  tf_round(x0,x1,17); tf_round(x0,x1,29); tf_round(x0,x1,16); tf_round(x0,x1,24);
  x0 += k1; x1 += k2 + 4u;
  tf_round(x0,x1,13); tf_round(x0,x1,15); tf_round(x0,x1,26); tf_round(x0,x1,6);
  x0 += k2; x1 += k0 + 5u;
  o0 = x0; o1 = x1;
}

__global__ void k_idx(u32 ka, u32 kb, int n, int mask, int* __restrict__ idx) {
  int i = blockIdx.x * 256 + threadIdx.x;
  if (i >= n) return;
  u32 b1, b2; tf_block(ka, kb, 0u, (u32)i, b1, b2);
  idx[i] = (int)((b1 ^ b2) & (u32)mask);
}

// ---------------- positional embedding ----------------
__global__ void k_pe(float* __restrict__ pe) {
  int i = blockIdx.x * 256 + threadIdx.x;
  if (i >= 2048 * 512) return;
  int t = i >> 9, o = i & 511;
  float arg = (float)((o >> 1) * 2) * (float)(-(log(10000.0) / 512.0));
  float div = (float)exp((double)arg);
  float ang32 = (float)t * div;
  double ang = (double)ang32;
  pe[i] = (float)((o & 1) ? cos(ang) : sin(ang));
}

// ---------------- embedding ----------------
__global__ __launch_bounds__(256) void k_embed(
    const float* __restrict__ x, const float* __restrict__ mark,
    const float* __restrict__ tw, const float* __restrict__ mw,
    const float* __restrict__ pe, float* __restrict__ o, int L, int total) {
  int i = blockIdx.x * 256 + threadIdx.x;
  if (i >= total) return;
  int oo = i & 511;
  int bt = i >> 9;
  int t = bt % L;
  int b = bt / L;
  float acc = pe[(t << 9) + oo];
  #pragma unroll
  for (int k = 0; k < 3; ++k) {
    int st = t + k - 1; if (st < 0) st += L; else if (st >= L) st -= L;
    const float* xr = x + (size_t)(b * L + st) * 7;
    const float* wr = tw + oo * 21 + k;
    #pragma unroll
    for (int ii = 0; ii < 7; ++ii) acc += xr[ii] * wr[ii * 3];
  }
  const float* mr = mark + (size_t)bt * 4;
  #pragma unroll
  for (int m = 0; m < 4; ++m) acc += mr[m] * mw[(m << 9) + oo];
  o[((size_t)bt << 9) + oo] = acc;
}

// ---------------- weight transpose + f16 split: W fp32 [K][N] -> Wh/Wl f16 [N][K] ----------------
__global__ __launch_bounds__(256) void k_wsplit(const float* __restrict__ W,
    f16* __restrict__ Wh, f16* __restrict__ Wl, int K, int N) {
  __shared__ float tile[32][33];
  int kb = blockIdx.x << 5, nb = blockIdx.y << 5;
  int t = threadIdx.x;
  int tr = t >> 5, tc = t & 31;
  #pragma unroll
  for (int p = 0; p < 4; ++p)
    tile[tr + p * 8][tc] = W[(size_t)(kb + tr + p * 8) * N + nb + tc];
  __syncthreads();
  #pragma unroll
  for (int p = 0; p < 4; ++p) {
    int n = tr + p * 8, k = tc;
    float v = tile[k][n];
    f16 h = (f16)v;
    size_t o = (size_t)(nb + n) * K + kb + k;
    Wh[o] = h;
    Wl[o] = (f16)((v - (float)h) * 2048.0f);
  }
}

// distil conv weight: w[o][i][tap] -> [N=o][K=tap*512+i] f16 split
__global__ void k_wsplit_conv(const float* __restrict__ w, f16* __restrict__ Wh, f16* __restrict__ Wl) {
  int i = blockIdx.x * 256 + threadIdx.x;
  if (i >= 512 * 1536) return;
  int o = i / 1536, k = i - o * 1536;
  float v = w[(size_t)o * 1536 + (k & 511) * 3 + (k >> 9)];
  f16 h = (f16)v;
  Wh[i] = h;
  Wl[i] = (f16)((v - (float)h) * 2048.0f);
}

// ---------------- MFMA GEMM, f16 2-level split (fp32-equivalent) ----------------
// C = act(A@W + bias) (+resid); A fp32 [M][K]; W pre-split f16 [N][K] (hi/lo*2^11)
// GATHER=1: A rows gathered circularly (distil conv), K=1536, stride 512
// ACT: 0 none, 1 gelu, 2 bn+elu
__device__ __forceinline__ int swz(int row, int kb) {
  return row * 128 + (kb ^ ((row & 7) << 4));
}

template<int GATHER, int ACT>
__global__ __launch_bounds__(256) void k_mgemm(
    const float* __restrict__ A, const f16* __restrict__ Bh, const f16* __restrict__ Bl,
    const float* __restrict__ bias, const float* __restrict__ resid,
    const float* __restrict__ bns, const float* __restrict__ bnb,
    float* __restrict__ C, int M, int N, int K, int L) {
  __shared__ f16x8 smv[4096];                 // 64 KiB: Ah, Al, Bh, Bl each 128x32 f16 (128B row stride)
  char* pAh = (char*)smv;
  char* pAl = pAh + 16384;
  char* pBh = pAh + 32768;
  char* pBl = pAh + 49152;
  const int t = threadIdx.x;
  const int bm = blockIdx.y << 7, bn = blockIdx.x << 7;
  const int srow = t >> 1, skh = (t & 1) << 4;   // staging: row, k-elem offset {0,16}
  int ab = 0, at = 0;
  if (GATHER) { int m = bm + srow; ab = m / L; at = m - ab * L; }
  const int lane = t & 63, wid = t >> 6;
  const int wr = (wid >> 1) << 6, wc = (wid & 1) << 6;
  const int fr = lane & 15;
  const int fk = (lane >> 4) << 4;               // byte offset of 8 f16
  const f32x4 zero = {0.f, 0.f, 0.f, 0.f};
  f32x4 acc1[4][4], acc2[4][4];
  #pragma unroll
  for (int i = 0; i < 4; ++i)
    #pragma unroll
    for (int j = 0; j < 4; ++j) { acc1[i][j] = zero; acc2[i][j] = zero; }

  for (int k0 = 0; k0 < K; k0 += 32) {
    __syncthreads();
    // ---- stage A (fp32 -> split f16) ----
    const float* ap;
    if (GATHER) {
      int kk = k0 + skh;
      int tap = kk >> 9, ii = kk & 511;
      int st = at + tap - 1; if (st < 0) st += L; else if (st >= L) st -= L;
      ap = A + (((size_t)(ab * L + st)) << 9) + ii;
    } else {
      ap = A + (size_t)(bm + srow) * K + k0 + skh;
    }
    float va[16];
    *(float4*)(va + 0)  = ((const float4*)ap)[0];
    *(float4*)(va + 4)  = ((const float4*)ap)[1];
    *(float4*)(va + 8)  = ((const float4*)ap)[2];
    *(float4*)(va + 12) = ((const float4*)ap)[3];
    f16 hh[16], ll[16];
    #pragma unroll
    for (int q = 0; q < 16; ++q) {
      f16 h = (f16)va[q]; hh[q] = h; ll[q] = (f16)((va[q] - (float)h) * 2048.0f);
    }
    int wb  = swz(srow, skh * 2);
    int wb2 = swz(srow, skh * 2 + 16);
    *(f16x8*)(pAh + wb)  = *(f16x8*)hh;
    *(f16x8*)(pAh + wb2) = *(f16x8*)(hh + 8);
    *(f16x8*)(pAl + wb)  = *(f16x8*)ll;
    *(f16x8*)(pAl + wb2) = *(f16x8*)(ll + 8);
    // ---- stage B (pre-split f16 [N][K]) ----
    const f16* bhp = Bh + (size_t)(bn + srow) * K + k0 + skh;
    const f16* blp = Bl + (size_t)(bn + srow) * K + k0 + skh;
    *(f16x8*)(pBh + wb)  = *(const f16x8*)(bhp);
    *(f16x8*)(pBh + wb2) = *(const f16x8*)(bhp + 8);
    *(f16x8*)(pBl + wb)  = *(const f16x8*)(blp);
    *(f16x8*)(pBl + wb2) = *(const f16x8*)(blp + 8);
    __syncthreads();
    // ---- fragments + MFMA ----
    f16x8 a_h[4], a_l[4];
    #pragma unroll
    for (int i = 0; i < 4; ++i) {
      int r = wr + i * 16 + fr;
      a_h[i] = *(f16x8*)(pAh + swz(r, fk));
      a_l[i] = *(f16x8*)(pAl + swz(r, fk));
    }
    #pragma unroll
    for (int j = 0; j < 4; ++j) {
      int r = wc + j * 16 + fr;
      f16x8 b_h = *(f16x8*)(pBh + swz(r, fk));
      f16x8 b_l = *(f16x8*)(pBl + swz(r, fk));
      #pragma unroll
      for (int i = 0; i < 4; ++i) {
        acc1[i][j] = __builtin_amdgcn_mfma_f32_16x16x32_f16(a_h[i], b_h, acc1[i][j], 0, 0, 0);
        acc2[i][j] = __builtin_amdgcn_mfma_f32_16x16x32_f16(a_h[i], b_l, acc2[i][j], 0, 0, 0);
        acc2[i][j] = __builtin_amdgcn_mfma_f32_16x16x32_f16(a_l[i], b_h, acc2[i][j], 0, 0, 0);
      }
    }
  }
  // ---- epilogue ----
  #pragma unroll
  for (int j = 0; j < 4; ++j) {
    int col = bn + wc + j * 16 + fr;
    float bsv = bias[col];
    float g2 = 0.f, b2 = 0.f;
    if (ACT == 2) { g2 = bns[col] * 0.9999950000375f; b2 = bnb[col]; }
    #pragma unroll
    for (int i = 0; i < 4; ++i) {
      #pragma unroll
      for (int r = 0; r < 4; ++r) {
        int row = bm + wr + i * 16 + ((lane >> 4) << 2) + r;
        float v = acc1[i][j][r] + acc2[i][j][r] * (1.0f / 2048.0f) + bsv;
        if (ACT == 1) v = 0.5f * v * (1.0f + erff(v * 0.70710678118654752f));
        if (ACT == 2) { v = v * g2 + b2; v = v > 0.f ? v : expm1f(v); }
        if (resid) v += resid[(size_t)row * N + col];
        C[(size_t)row * N + col] = v;
      }
    }
  }
}

// ---------------- LayerNorm (dim 512, in-place safe) ----------------
__global__ __launch_bounds__(256) void k_ln(const float* __restrict__ x,
    const float* __restrict__ g, const float* __restrict__ b, float* __restrict__ o) {
  int row = blockIdx.x, t = threadIdx.x;
  const float* xr = x + ((size_t)row << 9);
  float v0 = xr[t], v1 = xr[t + 256];
  float s = v0 + v1;
  #pragma unroll
  for (int off = 32; off; off >>= 1) s += __shfl_down(s, off);
  __shared__ float ls[4];
  if ((t & 63) == 0) ls[t >> 6] = s;
  __syncthreads();
  float mean = (ls[0] + ls[1] + ls[2] + ls[3]) * (1.f / 512.f);
  __syncthreads();
  float d0 = v0 - mean, d1 = v1 - mean;
  float q = d0 * d0 + d1 * d1;
  #pragma unroll
  for (int off = 32; off; off >>= 1) q += __shfl_down(q, off);
  if ((t & 63) == 0) ls[t >> 6] = q;
  __syncthreads();
  float var = (ls[0] + ls[1] + ls[2] + ls[3]) * (1.f / 512.f);
  float rs = rsqrtf(var + 1e-5f);
  float* orow = o + ((size_t)row << 9);
  orow[t] = d0 * rs * g[t] + b[t];
  orow[t + 256] = d1 * rs * g[t + 256] + b[t + 256];
}

// ---------------- z-slice (4 batches) M[bh,l] scoring ----------------
__global__ __launch_bounds__(256) void k_qkM(const float* __restrict__ Q, const float* __restrict__ K,
    const int* __restrict__ idx, float* __restrict__ M, int Lq, int Lk, int U) {
  int wid = (blockIdx.x * 256 + threadIdx.x) >> 6;
  int lane = threadIdx.x & 63;
  int l = wid & (Lq - 1); int bh = wid / Lq; int h = bh & 7; int b = bh >> 3;
  float dot = 0.f;
  if (lane < U) {
    int kr = idx[l * U + lane];
    const float4* q4 = (const float4*)(Q + ((size_t)(b * Lq + l) << 9) + (h << 6));
    const float4* k4 = (const float4*)(K + ((size_t)(b * Lk + kr) << 9) + (h << 6));
    #pragma unroll
    for (int i = 0; i < 16; ++i) {
      float4 a = q4[i], c = k4[i];
      dot += a.x * c.x + a.y * c.y + a.z * c.z + a.w * c.w;
    }
  }
  float mx = (lane < U) ? dot : -INFINITY;
  float sm = (lane < U) ? dot : 0.f;
  #pragma unroll
  for (int off = 32; off; off >>= 1) {
    mx = fmaxf(mx, __shfl_xor(mx, off));
    sm += __shfl_xor(sm, off);
  }
  if (lane == 0) M[(size_t)bh * Lq + l] = mx - sm / (float)Lk;
}

// ---------------- per (slice-bh): iterative top-u (ties -> lower index) ----------------
__global__ __launch_bounds__(256) void k_topk(const float* __restrict__ M, int* __restrict__ mtop,
                                              int Lq, int u) {
  __shared__ float vals[2048];
  __shared__ float rv[256];
  __shared__ int ri[256];
  int bh = blockIdx.x, t = threadIdx.x;
  const float* Mr = M + (size_t)bh * Lq;
  for (int i = t; i < Lq; i += 256) vals[i] = Mr[i];
  __syncthreads();
  for (int it = 0; it < u; ++it) {
    float bv = -INFINITY; int bi = 0x7fffffff;
    for (int i = t; i < Lq; i += 256) {
      float v = vals[i];
      if (v > bv || (v == bv && i < bi)) { bv = v; bi = i; }
    }
    rv[t] = bv; ri[t] = bi;
    __syncthreads();
    for (int s = 128; s; s >>= 1) {
      if (t < s) {
        float v = rv[t + s]; int i2 = ri[t + s];
        if (v > rv[t] || (v == rv[t] && i2 < ri[t])) { rv[t] = v; ri[t] = i2; }
      }
      __syncthreads();
    }
    if (t == 0) { mtop[bh * u + it] = ri[0]; vals[ri[0]] = -INFINITY; }
    __syncthreads();
  }
}

// ---------------- ctx mean (z-slice) ----------------
__global__ void k_cm1(const float* __restrict__ V, float* __restrict__ PS, int Lk, int rows) {
  int bid = blockIdx.x;            // bh*16 + seg, bh in [0,32)
  int bh = bid >> 4, seg = bid & 15, d = threadIdx.x;
  int b = bh >> 3, h = bh & 7;
  const float* vp = V + ((size_t)(b * Lk + seg * rows) << 9) + (h << 6) + d;
  float acc = 0.f;
  for (int r = 0; r < rows; ++r) acc += vp[(size_t)r << 9];
  PS[(bid << 6) + d] = acc;
}
__global__ void k_cm2(const float* __restrict__ PS, float* __restrict__ AO, float invLk,
                      int Lq, int total) {
  int i = blockIdx.x * 256 + threadIdx.x;
  if (i >= total) return;
  int c = i & 511; int h = c >> 6; int d = c & 63;
  int r = i >> 9; int b = r / Lq;
  float acc = 0.f;
  #pragma unroll
  for (int s = 0; s < 16; ++s) acc += PS[((((b << 3) + h) << 4) + s << 6) + d];
  AO[i] = acc * invLk;
}

// ---------------- cumsum (z-slice, masked) ----------------
__global__ void k_cs1(const float* __restrict__ V, float* __restrict__ PS, int Lq, int rows) {
  int bid = blockIdx.x;            // bh*8 + seg
  int bh = bid >> 3, seg = bid & 7, d = threadIdx.x;
  int b = bh >> 3, h = bh & 7;
  const float* vp = V + ((size_t)(b * Lq + seg * rows) << 9) + (h << 6) + d;
  float acc = 0.f;
  for (int r = 0; r < rows; ++r) acc += vp[(size_t)r << 9];
  PS[(bid << 6) + d] = acc;
}
__global__ void k_cs2(float* __restrict__ PS) {
  int bh = blockIdx.x, d = threadIdx.x;
  float run = 0.f;
  for (int s = 0; s < 8; ++s) {
    int id = (((bh << 3) + s) << 6) + d;
    float t0 = PS[id]; PS[id] = run; run += t0;
  }
}
__global__ void k_cs3(const float* __restrict__ V, const float* __restrict__ PS,
                      float* __restrict__ AO, int Lq, int rows) {
  int bid = blockIdx.x;
  int bh = bid >> 3, seg = bid & 7, d = threadIdx.x;
  int b = bh >> 3, h = bh & 7;
  float acc = PS[(bid << 6) + d];
  const float* vp = V + ((size_t)(b * Lq + seg * rows) << 9) + (h << 6) + d;
  float* op = AO + ((size_t)(b * Lq + seg * rows) << 9) + (h << 6) + d;
  for (int r = 0; r < rows; ++r) { acc += vp[(size_t)r << 9]; op[(size_t)r << 9] = acc; }
}

// ---------------- sparse attn for selected rows (z-slice) ----------------
__global__ __launch_bounds__(256) void k_sattn(const float* __restrict__ Q, const float* __restrict__ K,
    const float* __restrict__ V, const int* __restrict__ mtop, float* __restrict__ AO,
    int Lq, int Lk, int u, int masked) {
  __shared__ float sc[2048];
  __shared__ float red[256];
  __shared__ float qs[64];
  int ui = blockIdx.x % u, bh = blockIdx.x / u;
  int b = bh >> 3, h = bh & 7;
  int t = threadIdx.x;
  int row = mtop[bh * u + ui];
  if (t < 64) qs[t] = Q[((size_t)(b * Lq + row) << 9) + (h << 6) + t];
  __syncthreads();
  float lmax = -INFINITY;
  for (int c = t; c < Lk; c += 256) {
    const float4* kr = (const float4*)(K + ((size_t)(b * Lk + c) << 9) + (h << 6));
    float d = 0.f;
    #pragma unroll
    for (int i = 0; i < 16; ++i) {
      float4 kv = kr[i];
      d += qs[4*i] * kv.x + qs[4*i+1] * kv.y + qs[4*i+2] * kv.z + qs[4*i+3] * kv.w;
    }
    d *= 0.125f;
    if (masked && c > row) d = -INFINITY;
    sc[c] = d;
    lmax = fmaxf(lmax, d);
  }
  red[t] = lmax; __syncthreads();
  for (int s = 128; s; s >>= 1) { if (t < s) red[t] = fmaxf(red[t], red[t + s]); __syncthreads(); }
  float mx = red[0]; __syncthreads();
  float lsum = 0.f;
  for (int c = t; c < Lk; c += 256) { float e = expf(sc[c] - mx); sc[c] = e; lsum += e; }
  red[t] = lsum; __syncthreads();
  for (int s = 128; s; s >>= 1) { if (t < s) red[t] += red[t + s]; __syncthreads(); }
  float S = red[0]; __syncthreads();
  int d = t & 63, grp = t >> 6;
  float acc = 0.f;
  for (int c = grp; c < Lk; c += 4) acc += sc[c] * V[((size_t)(b * Lk + c) << 9) + (h << 6) + d];
  red[t] = acc; __syncthreads();
  if (t < 64) {
    float r = red[t] + red[64 + t] + red[128 + t] + red[192 + t];
    AO[((size_t)(b * Lq + row) << 9) + (h << 6) + t] = r / S;
  }
}

// ---------------- maxpool w3 s2 p1 along L ----------------
__global__ void k_maxpool(const float* __restrict__ y, float* __restrict__ o, int L) {
  int Lo = L >> 1;
  int i = blockIdx.x * 256 + threadIdx.x;
  int c = i & 511; int bj = i >> 9;
  int j = bj % Lo; int b = bj / Lo;
  float m = -INFINITY;
  int t0 = 2 * j - 1;
  #pragma unroll
  for (int k = 0; k < 3; ++k) {
    int tt = t0 + k;
    if (tt >= 0 && tt < L) m = fmaxf(m, y[((size_t)(b * L + tt) << 9) + c]);
  }
  o[((size_t)(b * Lo + j) << 9) + c] = m;
}

// ---------------- final projection 512->7 ----------------
__global__ void k_proj(const float* __restrict__ Xn, const float* __restrict__ pw,
                       const float* __restrict__ pb, float* __restrict__ out) {
  int i = blockIdx.x * 256 + threadIdx.x;
  if (i >= 16 * 512 * 7) return;
  int c = i % 7; int r = i / 7;
  int b = r >> 9; int j = r & 511;
  const float* xr = Xn + ((size_t)(b * 1024 + 512 + j) << 9);
  float acc = pb[c];
  for (int d2 = 0; d2 < 512; ++d2) acc += xr[d2] * pw[d2 * 7 + c];
  out[i] = acc;
}

// =====================================================================
extern "C" void kernel_launch(void* const* d_in, const int* in_sizes, int n_in,
                              void* d_out, int out_size, void* d_ws, size_t ws_size,
                              hipStream_t stream) {
  const float* x_enc      = (const float*)d_in[0];
  const float* x_mark_enc = (const float*)d_in[1];
  const float* x_dec      = (const float*)d_in[2];
  const float* x_mark_dec = (const float*)d_in[3];
  const float* enc_tok_w  = (const float*)d_in[4];
  const float* enc_mark_w = (const float*)d_in[5];
  const float* dec_tok_w  = (const float*)d_in[6];
  const float* dec_mark_w = (const float*)d_in[7];
  const float* enc_attn_w = (const float*)d_in[8];
  const float* enc_attn_b = (const float*)d_in[9];
  const float* enc_ffn1_w = (const float*)d_in[10];
  const float* enc_ffn1_b = (const float*)d_in[11];
  const float* enc_ffn2_w = (const float*)d_in[12];
  const float* enc_ffn2_b = (const float*)d_in[13];
  const float* enc_ln_g   = (const float*)d_in[14];
  const float* enc_ln_b   = (const float*)d_in[15];
  const float* distil_w   = (const float*)d_in[16];
  const float* distil_b   = (const float*)d_in[17];
  const float* distil_bn_g= (const float*)d_in[18];
  const float* distil_bn_b= (const float*)d_in[19];
  const float* enc_norm_g = (const float*)d_in[20];
  const float* enc_norm_b = (const float*)d_in[21];
  const float* dec_self_w = (const float*)d_in[22];
  const float* dec_self_b = (const float*)d_in[23];
  const float* dec_cross_w= (const float*)d_in[24];
  const float* dec_cross_b= (const float*)d_in[25];
  const float* dec_ffn1_w = (const float*)d_in[26];
  const float* dec_ffn1_b = (const float*)d_in[27];
  const float* dec_ffn2_w = (const float*)d_in[28];
  const float* dec_ffn2_b = (const float*)d_in[29];
  const float* dec_ln_g   = (const float*)d_in[30];
  const float* dec_ln_b   = (const float*)d_in[31];
  const float* dec_norm_g = (const float*)d_in[32];
  const float* dec_norm_b = (const float*)d_in[33];
  const float* proj_w     = (const float*)d_in[34];
  const float* proj_b     = (const float*)d_in[35];

  // -------- workspace layout (~157 MiB) --------
  float* ws = (float*)d_ws;
  float* X   = ws;                        // 16,777,216
  float* Y   = X   + 16777216;            // 16,777,216 (FFN inter / distil out / attn QKVAO alias)
  float* ENC = Y   + 16777216;            // 4,194,304
  float* PE  = ENC + 4194304;             // 1,048,576
  float* Mb  = PE  + 1048576;             //    65,536 (slice M: 32 bh x 2048)
  float* PS  = Mb  + 65536;               //    32,768
  f16*  WSP  = (f16*)(PS + 32768);        // 4,194,304 f16 (8 MiB) weight split region
  int* IDXi  = (int*)(WSP + 4194304);     //    81,920
  int* MTi   = IDXi + 81920;              //     1,280
  {
    size_t needF = 16777216ull*2 + 4194304 + 1048576 + 65536 + 32768 + 2097152;
    size_t needB = needF * 4 + (81920 + 1280) * 4;
    if (ws_size < needB) return;
  }
  // attn per-slice buffers alias Y
  float* Qb  = Y;
  float* Kb  = Y + 4194304;
  float* Vb  = Y + 8388608;
  float* AOb = Y + 12582912;

  auto ln = [&](const float* x, const float* g, const float* b, float* o, int rows) {
    k_ln<<<rows, 256, 0, stream>>>(x, g, b, o);
  };
  auto wsplit = [&](const float* W, f16* Wh, f16* Wl, int K, int N) {
    dim3 g(K >> 5, N >> 5);
    k_wsplit<<<g, 256, 0, stream>>>(W, Wh, Wl, K, N);
  };
  // mgemm: ACT 0/1, optional resid
  auto mgemm = [&](const float* A, const f16* Wh, const f16* Wl, const float* bias,
                   const float* resid, float* C, int M, int N, int K, int act) {
    dim3 g(N >> 7, M >> 7);
    if (act == 1)
      k_mgemm<0,1><<<g, 256, 0, stream>>>(A, Wh, Wl, bias, resid, nullptr, nullptr, C, M, N, K, 0);
    else
      k_mgemm<0,0><<<g, 256, 0, stream>>>(A, Wh, Wl, bias, resid, nullptr, nullptr, C, M, N, K, 0);
  };
  auto Uof = [](int Lx) { int v = 5 * (int)ceil(log((double)Lx)); return v < Lx ? v : Lx; };

  // ProbSparse attention over 4 z-slices of 4 batches each
  auto attn = [&](float* xq_base, const float* xkv_base, int Lq, int Lk, const float* w,
                  const float* bias, bool masked, u32 fold) {
    int U = Uof(Lk), uu = Uof(Lq);
    u32 r0, r1, ka, kb2;
    tf_block(0u, 42u, 0u, fold, r0, r1);   // fold_in(key(42), fold)
    tf_block(r0, r1, 0u, 1u, ka, kb2);     // randint internal split -> k2
    int n = Lq * U;
    k_idx<<<(n + 255) / 256, 256, 0, stream>>>(ka, kb2, n, Lk - 1, IDXi);
    f16 *WQh = WSP,            *WQl = WSP + 262144,
        *WKh = WSP + 524288,   *WKl = WSP + 786432,
        *WVh = WSP + 1048576,  *WVl = WSP + 1310720,
        *WOh = WSP + 1572864,  *WOl = WSP + 1835008;
    wsplit(w,          WQh, WQl, 512, 512);
    wsplit(w + 262144, WKh, WKl, 512, 512);
    wsplit(w + 524288, WVh, WVl, 512, 512);
    wsplit(w + 786432, WOh, WOl, 512, 512);
    for (int s = 0; s < 4; ++s) {
      float* xq        = xq_base  + (size_t)s * 4 * Lq * 512;
      const float* xkv = xkv_base + (size_t)s * 4 * Lk * 512;
      mgemm(xq,  WQh, WQl, bias,        nullptr, Qb, 4 * Lq, 512, 512, 0);
      mgemm(xkv, WKh, WKl, bias + 512,  nullptr, Kb, 4 * Lk, 512, 512, 0);
      mgemm(xkv, WVh, WVl, bias + 1024, nullptr, Vb, 4 * Lk, 512, 512, 0);
      int wids = 32 * Lq;
      k_qkM<<<wids / 4, 256, 0, stream>>>(Qb, Kb, IDXi, Mb, Lq, Lk, U);
      k_topk<<<32, 256, 0, stream>>>(Mb, MTi, Lq, uu);
      if (masked) {
        k_cs1<<<256, 64, 0, stream>>>(Vb, PS, Lq, Lq >> 3);
        k_cs2<<<32, 64, 0, stream>>>(PS);
        k_cs3<<<256, 64, 0, stream>>>(Vb, PS, AOb, Lq, Lq >> 3);
      } else {
        k_cm1<<<512, 64, 0, stream>>>(Vb, PS, Lk, Lk >> 4);
        int tot = 4 * Lq * 512;
        k_cm2<<<tot / 256, 256, 0, stream>>>(PS, AOb, 1.0f / (float)Lk, Lq, tot);
      }
      k_sattn<<<32 * uu, 256, 0, stream>>>(Qb, Kb, Vb, MTi, AOb, Lq, Lk, uu, masked ? 1 : 0);
      mgemm(AOb, WOh, WOl, bias + 1536, xq, xq, 4 * Lq, 512, 512, 0);
    }
  };

  auto ffn = [&](float* x, const float* w1, const float* b1,
                 const float* w2, const float* b2, int Mtot) {
    f16 *W1h = WSP,           *W1l = WSP + 1048576,
        *W2h = WSP + 2097152, *W2l = WSP + 3145728;
    wsplit(w1, W1h, W1l, 512, 2048);
    wsplit(w2, W2h, W2l, 2048, 512);
    for (int c0 = 0; c0 < Mtot; c0 += 8192) {
      mgemm(x + (size_t)c0 * 512, W1h, W1l, b1, nullptr, Y, 8192, 2048, 512, 1);
      mgemm(Y, W2h, W2l, b2, x + (size_t)c0 * 512, x + (size_t)c0 * 512, 8192, 512, 2048, 0);
    }
  };

  // ---------------- encoder ----------------
  k_pe<<<(2048 * 512) / 256, 256, 0, stream>>>(PE);
  k_embed<<<(16 * 2048 * 512) / 256, 256, 0, stream>>>(x_enc, x_mark_enc, enc_tok_w, enc_mark_w,
                                                       PE, X, 2048, 16 * 2048 * 512);
  int L = 2048;
  for (int l = 0; l < 3; ++l) {
    attn(X, X, L, L, enc_attn_w + (size_t)l * 4 * 262144, enc_attn_b + (size_t)l * 2048,
         false, (u32)l);
    ln(X, enc_ln_g + (size_t)(l * 2) * 512, enc_ln_b + (size_t)(l * 2) * 512, X, 16 * L);
    ffn(X, enc_ffn1_w + (size_t)l * 512 * 2048, enc_ffn1_b + (size_t)l * 2048,
        enc_ffn2_w + (size_t)l * 2048 * 512, enc_ffn2_b + (size_t)l * 512, 16 * L);
    ln(X, enc_ln_g + (size_t)(l * 2 + 1) * 512, enc_ln_b + (size_t)(l * 2 + 1) * 512, X, 16 * L);
    if (l < 2) {
      f16 *Dh = WSP, *Dl = WSP + 786432;
      k_wsplit_conv<<<(512 * 1536) / 256, 256, 0, stream>>>(distil_w + (size_t)l * 512 * 512 * 3, Dh, Dl);
      dim3 g(512 >> 7, (16 * L) >> 7);
      k_mgemm<1,2><<<g, 256, 0, stream>>>(X, Dh, Dl, distil_b + (size_t)l * 512, nullptr,
          distil_bn_g + (size_t)l * 512, distil_bn_b + (size_t)l * 512, Y, 16 * L, 512, 1536, L);
      int Lo = L >> 1;
      k_maxpool<<<(16 * Lo * 512) / 256, 256, 0, stream>>>(Y, X, L);
      L = Lo;
    }
  }
  ln(X, enc_norm_g, enc_norm_b, ENC, 16 * 512);

  // ---------------- decoder (in-place chain in X) ----------------
  k_embed<<<(16 * 1024 * 512) / 256, 256, 0, stream>>>(x_dec, x_mark_dec, dec_tok_w, dec_mark_w,
                                                       PE, X, 1024, 16 * 1024 * 512);
  for (int l = 0; l < 2; ++l) {
    attn(X, X, 1024, 1024, dec_self_w + (size_t)l * 4 * 262144, dec_self_b + (size_t)l * 2048,
         true, (u32)(100 + 2 * l));
    ln(X, dec_ln_g + (size_t)(l * 3) * 512, dec_ln_b + (size_t)(l * 3) * 512, X, 16384);
    attn(X, ENC, 1024, 512, dec_cross_w + (size_t)l * 4 * 262144, dec_cross_b + (size_t)l * 2048,
         false, (u32)(101 + 2 * l));
    ln(X, dec_ln_g + (size_t)(l * 3 + 1) * 512, dec_ln_b + (size_t)(l * 3 + 1) * 512, X, 16384);
    ffn(X, dec_ffn1_w + (size_t)l * 512 * 2048, dec_ffn1_b + (size_t)l * 2048,
        dec_ffn2_w + (size_t)l * 2048 * 512, dec_ffn2_b + (size_t)l * 512, 16384);
    ln(X, dec_ln_g + (size_t)(l * 3 + 2) * 512, dec_ln_b + (size_t)(l * 3 + 2) * 512, X, 16384);
  }
  ln(X, dec_norm_g, dec_norm_b, X, 16384);
  k_proj<<<(16 * 512 * 7 + 255) / 256, 256, 0, stream>>>(X, proj_w, proj_b, (float*)d_out);
}

// Round 5
// 14158.824 us; speedup vs baseline: 3.2891x; 1.1077x over previous
//
#include <hip/hip_runtime.h>
#include <math.h>
#include <stdint.h>

typedef unsigned int u32;
typedef _Float16 f16;
typedef __attribute__((ext_vector_type(8))) _Float16 f16x8;
typedef __attribute__((ext_vector_type(4))) float f32x4;

// ---------------- Threefry-2x32 (20 rounds), matches JAX ----------------
__host__ __device__ __forceinline__ u32 rotl32(u32 x, int r) { return (x << r) | (x >> (32 - r)); }
__host__ __device__ __forceinline__ void tf_round(u32& x0, u32& x1, int r) {
  x0 += x1; x1 = rotl32(x1, r); x1 ^= x0;
}
__host__ __device__ __forceinline__ void tf_block(u32 k0, u32 k1, u32 x0, u32 x1, u32& o0, u32& o1) {
  u32 k2 = k0 ^ k1 ^ 0x1BD11BDAu;
  x0 += k0; x1 += k1;
  tf_round(x0,x1,13); tf_round(x0,x1,15); tf_round(x0,x1,26); tf_round(x0,x1,6);
  x0 += k1; x1 += k2 + 1u;
  tf_round(x0,x1,17); tf_round(x0,x1,29); tf_round(x0,x1,16); tf_round(x0,x1,24);
  x0 += k2; x1 += k0 + 2u;
  tf_round(x0,x1,13); tf_round(x0,x1,15); tf_round(x0,x1,26); tf_round(x0,x1,6);
  x0 += k0; x1 += k1 + 3u;
  tf_round(x0,x1,17); tf_round(x0,x1,29); tf_round(x0,x1,16); tf_round(x0,x1,24);
  x0 += k1; x1 += k2 + 4u;
  tf_round(x0,x1,13); tf_round(x0,x1,15); tf_round(x0,x1,26); tf_round(x0,x1,6);
  x0 += k2; x1 += k0 + 5u;
  o0 = x0; o1 = x1;
}

__global__ void k_idx(u32 ka, u32 kb, int n, int mask, int* __restrict__ idx) {
  int i = blockIdx.x * 256 + threadIdx.x;
  if (i >= n) return;
  u32 b1, b2; tf_block(ka, kb, 0u, (u32)i, b1, b2);
  idx[i] = (int)((b1 ^ b2) & (u32)mask);
}

// ---------------- positional embedding ----------------
__global__ void k_pe(float* __restrict__ pe) {
  int i = blockIdx.x * 256 + threadIdx.x;
  if (i >= 2048 * 512) return;
  int t = i >> 9, o = i & 511;
  float arg = (float)((o >> 1) * 2) * (float)(-(log(10000.0) / 512.0));
  float div = (float)exp((double)arg);
  float ang32 = (float)t * div;
  double ang = (double)ang32;
  pe[i] = (float)((o & 1) ? cos(ang) : sin(ang));
}

// ---------------- embedding ----------------
__global__ __launch_bounds__(256) void k_embed(
    const float* __restrict__ x, const float* __restrict__ mark,
    const float* __restrict__ tw, const float* __restrict__ mw,
    const float* __restrict__ pe, float* __restrict__ o, int L, int total) {
  int i = blockIdx.x * 256 + threadIdx.x;
  if (i >= total) return;
  int oo = i & 511;
  int bt = i >> 9;
  int t = bt % L;
  int b = bt / L;
  float acc = pe[(t << 9) + oo];
  #pragma unroll
  for (int k = 0; k < 3; ++k) {
    int st = t + k - 1; if (st < 0) st += L; else if (st >= L) st -= L;
    const float* xr = x + (size_t)(b * L + st) * 7;
    const float* wr = tw + oo * 21 + k;
    #pragma unroll
    for (int ii = 0; ii < 7; ++ii) acc += xr[ii] * wr[ii * 3];
  }
  const float* mr = mark + (size_t)bt * 4;
  #pragma unroll
  for (int m = 0; m < 4; ++m) acc += mr[m] * mw[(m << 9) + oo];
  o[((size_t)bt << 9) + oo] = acc;
}

// ---------------- weight transpose + f16 split: W fp32 [K][N] -> Wh/Wl f16 [N][K] ----------------
__global__ __launch_bounds__(256) void k_wsplit(const float* __restrict__ W,
    f16* __restrict__ Wh, f16* __restrict__ Wl, int K, int N) {
  __shared__ float tile[32][33];
  int kb = blockIdx.x << 5, nb = blockIdx.y << 5;
  int t = threadIdx.x;
  int tr = t >> 5, tc = t & 31;
  #pragma unroll
  for (int p = 0; p < 4; ++p)
    tile[tr + p * 8][tc] = W[(size_t)(kb + tr + p * 8) * N + nb + tc];
  __syncthreads();
  #pragma unroll
  for (int p = 0; p < 4; ++p) {
    int n = tr + p * 8, k = tc;
    float v = tile[k][n];
    f16 h = (f16)v;
    size_t o = (size_t)(nb + n) * K + kb + k;
    Wh[o] = h;
    Wl[o] = (f16)((v - (float)h) * 2048.0f);
  }
}

// distil conv weight: w[o][i][tap] -> [N=o][K=tap*512+i] f16 split
__global__ void k_wsplit_conv(const float* __restrict__ w, f16* __restrict__ Wh, f16* __restrict__ Wl) {
  int i = blockIdx.x * 256 + threadIdx.x;
  if (i >= 512 * 1536) return;
  int o = i / 1536, k = i - o * 1536;
  float v = w[(size_t)o * 1536 + (k & 511) * 3 + (k >> 9)];
  f16 h = (f16)v;
  Wh[i] = h;
  Wl[i] = (f16)((v - (float)h) * 2048.0f);
}

// ---------------- MFMA GEMM, f16 2-level split (fp32-equivalent), BK=64 ----------------
// C = act(A@W + bias) (+resid); A fp32 [M][K]; W pre-split f16 [N][K]
// GATHER=1: circular 3-tap row gather (distil conv), K=1536
// ACT: 0 none, 1 gelu, 2 bn+elu
template<int GATHER, int ACT>
__global__ __launch_bounds__(256, 2) void k_mgemm(
    const float* __restrict__ A, const f16* __restrict__ Bh, const f16* __restrict__ Bl,
    const float* __restrict__ bias, const float* __restrict__ resid,
    const float* __restrict__ bns, const float* __restrict__ bnb,
    float* __restrict__ C, int M, int N, int K, int L) {
  __shared__ char lds[65536];          // 4 arrays x 128 rows x 128B (64 f16)
  char* pAh = lds;
  char* pAl = lds + 16384;
  char* pBh = lds + 32768;
  char* pBl = lds + 49152;
  const int t = threadIdx.x;
  const int bm = blockIdx.y << 7, bn = blockIdx.x << 7;
  const int srow = t >> 1;             // 0..127
  const int ske  = (t & 1) << 5;       // elem offset 0/32
  const int skB  = (t & 1) << 6;       // byte offset 0/64
  const int rowxor = (srow & 7) << 4;
  int ab = 0, at = 0;
  if (GATHER) { int m = bm + srow; ab = m / L; at = m - ab * L; }
  const int lane = t & 63, wid = t >> 6;
  const int wr = (wid >> 1) << 6, wc = (wid & 1) << 6;
  const int fr = lane & 15;
  const int fkB = (lane >> 4) << 4;    // 0,16,32,48
  const f32x4 zero = {0.f, 0.f, 0.f, 0.f};
  f32x4 acc1[4][4], acc2[4][4];
  #pragma unroll
  for (int i = 0; i < 4; ++i)
    #pragma unroll
    for (int j = 0; j < 4; ++j) { acc1[i][j] = zero; acc2[i][j] = zero; }

  for (int k0 = 0; k0 < K; k0 += 64) {
    __syncthreads();
    // ---- stage A: 32 fp32 per thread -> split f16 ----
    const float* ap;
    if (GATHER) {
      int kk = k0 + ske;               // 32-aligned, never crosses a 512 tap boundary
      int tap = kk >> 9, ii = kk & 511;
      int st = at + tap - 1; if (st < 0) st += L; else if (st >= L) st -= L;
      ap = A + (((size_t)(ab * L + st)) << 9) + ii;
    } else {
      ap = A + (size_t)(bm + srow) * K + k0 + ske;
    }
    #pragma unroll
    for (int q = 0; q < 4; ++q) {
      float4 u0 = ((const float4*)ap)[2 * q];
      float4 u1 = ((const float4*)ap)[2 * q + 1];
      float uv[8] = {u0.x, u0.y, u0.z, u0.w, u1.x, u1.y, u1.z, u1.w};
      f16 h8[8], l8[8];
      #pragma unroll
      for (int e = 0; e < 8; ++e) {
        f16 h = (f16)uv[e]; h8[e] = h; l8[e] = (f16)((uv[e] - (float)h) * 2048.0f);
      }
      int ob = srow * 128 + ((skB + q * 16) ^ rowxor);
      *(f16x8*)(pAh + ob) = *(f16x8*)h8;
      *(f16x8*)(pAl + ob) = *(f16x8*)l8;
    }
    // ---- stage B: pre-split f16 ----
    const f16* bhp = Bh + (size_t)(bn + srow) * K + k0 + ske;
    const f16* blp = Bl + (size_t)(bn + srow) * K + k0 + ske;
    #pragma unroll
    for (int q = 0; q < 4; ++q) {
      int ob = srow * 128 + ((skB + q * 16) ^ rowxor);
      *(f16x8*)(pBh + ob) = *(const f16x8*)(bhp + q * 8);
      *(f16x8*)(pBl + ob) = *(const f16x8*)(blp + q * 8);
    }
    __syncthreads();
    // ---- fragments + MFMA ----
    f16x8 ah[4][2], al[4][2];
    #pragma unroll
    for (int i = 0; i < 4; ++i) {
      int r = wr + i * 16 + fr;
      int rx = (r & 7) << 4;
      #pragma unroll
      for (int kk = 0; kk < 2; ++kk) {
        int ob = r * 128 + ((fkB + kk * 64) ^ rx);
        ah[i][kk] = *(f16x8*)(pAh + ob);
        al[i][kk] = *(f16x8*)(pAl + ob);
      }
    }
    #pragma unroll
    for (int j = 0; j < 4; ++j) {
      int r = wc + j * 16 + fr;
      int rx = (r & 7) << 4;
      #pragma unroll
      for (int kk = 0; kk < 2; ++kk) {
        int ob = r * 128 + ((fkB + kk * 64) ^ rx);
        f16x8 bh_ = *(f16x8*)(pBh + ob);
        f16x8 bl_ = *(f16x8*)(pBl + ob);
        #pragma unroll
        for (int i = 0; i < 4; ++i) {
          acc1[i][j] = __builtin_amdgcn_mfma_f32_16x16x32_f16(ah[i][kk], bh_, acc1[i][j], 0, 0, 0);
          acc2[i][j] = __builtin_amdgcn_mfma_f32_16x16x32_f16(ah[i][kk], bl_, acc2[i][j], 0, 0, 0);
          acc2[i][j] = __builtin_amdgcn_mfma_f32_16x16x32_f16(al[i][kk], bh_, acc2[i][j], 0, 0, 0);
        }
      }
    }
  }
  // ---- epilogue ----
  #pragma unroll
  for (int j = 0; j < 4; ++j) {
    int col = bn + wc + j * 16 + fr;
    float bsv = bias[col];
    float g2 = 0.f, b2 = 0.f;
    if (ACT == 2) { g2 = bns[col] * 0.9999950000375f; b2 = bnb[col]; }
    #pragma unroll
    for (int i = 0; i < 4; ++i) {
      #pragma unroll
      for (int r = 0; r < 4; ++r) {
        int row = bm + wr + i * 16 + ((lane >> 4) << 2) + r;
        float v = acc1[i][j][r] + acc2[i][j][r] * (1.0f / 2048.0f) + bsv;
        if (ACT == 1) v = 0.5f * v * (1.0f + erff(v * 0.70710678118654752f));
        if (ACT == 2) { v = v * g2 + b2; v = v > 0.f ? v : expm1f(v); }
        if (resid) v += resid[(size_t)row * N + col];
        C[(size_t)row * N + col] = v;
      }
    }
  }
}

// ---------------- LayerNorm (dim 512, in-place safe) ----------------
__global__ __launch_bounds__(256) void k_ln(const float* __restrict__ x,
    const float* __restrict__ g, const float* __restrict__ b, float* __restrict__ o) {
  int row = blockIdx.x, t = threadIdx.x;
  const float* xr = x + ((size_t)row << 9);
  float v0 = xr[t], v1 = xr[t + 256];
  float s = v0 + v1;
  #pragma unroll
  for (int off = 32; off; off >>= 1) s += __shfl_down(s, off);
  __shared__ float ls[4];
  if ((t & 63) == 0) ls[t >> 6] = s;
  __syncthreads();
  float mean = (ls[0] + ls[1] + ls[2] + ls[3]) * (1.f / 512.f);
  __syncthreads();
  float d0 = v0 - mean, d1 = v1 - mean;
  float q = d0 * d0 + d1 * d1;
  #pragma unroll
  for (int off = 32; off; off >>= 1) q += __shfl_down(q, off);
  if ((t & 63) == 0) ls[t >> 6] = q;
  __syncthreads();
  float var = (ls[0] + ls[1] + ls[2] + ls[3]) * (1.f / 512.f);
  float rs = rsqrtf(var + 1e-5f);
  float* orow = o + ((size_t)row << 9);
  orow[t] = d0 * rs * g[t] + b[t];
  orow[t + 256] = d1 * rs * g[t + 256] + b[t + 256];
}

// ---------------- M[bh,l] scoring (strided Q/K) ----------------
__global__ __launch_bounds__(256) void k_qkM(const float* __restrict__ Q, int qstr,
    const float* __restrict__ Kp, int kstr, const int* __restrict__ idx,
    float* __restrict__ M, int Lq, int Lk, int U) {
  int wid = (blockIdx.x * 256 + threadIdx.x) >> 6;
  int lane = threadIdx.x & 63;
  int l = wid & (Lq - 1); int bh = wid / Lq; int h = bh & 7; int b = bh >> 3;
  float dot = 0.f;
  if (lane < U) {
    int kr = idx[l * U + lane];
    const float4* q4 = (const float4*)(Q + (size_t)(b * Lq + l) * qstr + (h << 6));
    const float4* k4 = (const float4*)(Kp + (size_t)(b * Lk + kr) * kstr + (h << 6));
    #pragma unroll
    for (int i = 0; i < 16; ++i) {
      float4 a = q4[i], c = k4[i];
      dot += a.x * c.x + a.y * c.y + a.z * c.z + a.w * c.w;
    }
  }
  float mx = (lane < U) ? dot : -INFINITY;
  float sm = (lane < U) ? dot : 0.f;
  #pragma unroll
  for (int off = 32; off; off >>= 1) {
    mx = fmaxf(mx, __shfl_xor(mx, off));
    sm += __shfl_xor(sm, off);
  }
  if (lane == 0) M[(size_t)bh * Lq + l] = mx - sm / (float)Lk;
}

// ---------------- single-wave top-u per (b,h), ties -> lower index ----------------
__global__ void k_topk64(const float* __restrict__ M, int* __restrict__ mtop, int Lq, int u) {
  __shared__ float vals[2048];
  int bh = blockIdx.x, l = threadIdx.x;
  const float* Mr = M + (size_t)bh * Lq;
  for (int i = l; i < Lq; i += 64) vals[i] = Mr[i];
  __syncthreads();
  for (int it = 0; it < u; ++it) {
    float bv = -INFINITY; int bi = 0x7fffffff;
    for (int i = l; i < Lq; i += 64) {
      float v = vals[i];
      if (v > bv || (v == bv && i < bi)) { bv = v; bi = i; }
    }
    #pragma unroll
    for (int off = 32; off; off >>= 1) {
      float vv = __shfl_xor(bv, off); int ii = __shfl_xor(bi, off);
      if (vv > bv || (vv == bv && ii < bi)) { bv = vv; bi = ii; }
    }
    if (l == 0) { mtop[bh * u + it] = bi; vals[bi] = -INFINITY; }
    __syncthreads();
  }
}

// ---------------- ctx mean ----------------
__global__ void k_cm1(const float* __restrict__ V, int vstr, float* __restrict__ PS,
                      int Lk, int rows) {
  int bid = blockIdx.x;            // bh*16 + seg, bh in [0,32)
  int bh = bid >> 4, seg = bid & 15, d = threadIdx.x;
  int b = bh >> 3, h = bh & 7;
  const float* vp = V + (size_t)(b * Lk + seg * rows) * vstr + (h << 6) + d;
  float acc = 0.f;
  for (int r = 0; r < rows; ++r) acc += vp[(size_t)r * vstr];
  PS[(bid << 6) + d] = acc;
}
__global__ void k_cm2(const float* __restrict__ PS, float* __restrict__ AO, float invLk,
                      int Lq, int total) {
  int i = blockIdx.x * 256 + threadIdx.x;
  if (i >= total) return;
  int c = i & 511; int h = c >> 6; int d = c & 63;
  int r = i >> 9; int b = r / Lq;
  float acc = 0.f;
  #pragma unroll
  for (int s = 0; s < 16; ++s) acc += PS[(((((b << 3) + h) << 4) + s) << 6) + d];
  AO[i] = acc * invLk;
}

// ---------------- cumsum (masked ctx) ----------------
__global__ void k_cs1(const float* __restrict__ V, int vstr, float* __restrict__ PS,
                      int Lq, int rows) {
  int bid = blockIdx.x;            // bh*8 + seg
  int bh = bid >> 3, seg = bid & 7, d = threadIdx.x;
  int b = bh >> 3, h = bh & 7;
  const float* vp = V + (size_t)(b * Lq + seg * rows) * vstr + (h << 6) + d;
  float acc = 0.f;
  for (int r = 0; r < rows; ++r) acc += vp[(size_t)r * vstr];
  PS[(bid << 6) + d] = acc;
}
__global__ void k_cs2(float* __restrict__ PS) {
  int bh = blockIdx.x, d = threadIdx.x;
  float run = 0.f;
  for (int s = 0; s < 8; ++s) {
    int id = (((bh << 3) + s) << 6) + d;
    float t0 = PS[id]; PS[id] = run; run += t0;
  }
}
__global__ void k_cs3(const float* __restrict__ V, int vstr, const float* __restrict__ PS,
                      float* __restrict__ AO, int Lq, int rows) {
  int bid = blockIdx.x;
  int bh = bid >> 3, seg = bid & 7, d = threadIdx.x;
  int b = bh >> 3, h = bh & 7;
  float acc = PS[(bid << 6) + d];
  const float* vp = V + (size_t)(b * Lq + seg * rows) * vstr + (h << 6) + d;
  float* op = AO + ((size_t)(b * Lq + seg * rows) << 9) + (h << 6) + d;
  for (int r = 0; r < rows; ++r) { acc += vp[(size_t)r * vstr]; op[(size_t)r << 9] = acc; }
}

// ---------------- sparse attn: 4 selected rows per block ----------------
__global__ __launch_bounds__(256) void k_sattn4(
    const float* __restrict__ Q, int qstr, const float* __restrict__ Kp, int kstr,
    const float* __restrict__ Vp, int vstr, const int* __restrict__ mtop,
    float* __restrict__ AO, int Lq, int Lk, int u, int masked) {
  __shared__ float sc[4][2048];
  __shared__ float qs[4][64];
  __shared__ float red[4][256];
  __shared__ float pv[4][4][64];
  __shared__ int rowsh[4];
  __shared__ float mxs[4], sss[4];
  int nb = (u + 3) >> 2;
  int ub = blockIdx.x % nb, bh = blockIdx.x / nb;
  int b = bh >> 3, h = bh & 7;
  int t = threadIdx.x;
  if (t < 4) {
    int ui = ub * 4 + t;
    rowsh[t] = (ui < u) ? mtop[bh * u + ui] : -1;
  }
  __syncthreads();
  {
    int r = t >> 6, d = t & 63;
    int row = rowsh[r];
    qs[r][d] = (row >= 0) ? Q[(size_t)(b * Lq + row) * qstr + (h << 6) + d] : 0.f;
  }
  __syncthreads();
  float lm0 = -INFINITY, lm1 = -INFINITY, lm2 = -INFINITY, lm3 = -INFINITY;
  for (int c = t; c < Lk; c += 256) {
    const float4* kr = (const float4*)(Kp + (size_t)(b * Lk + c) * kstr + (h << 6));
    float d0 = 0.f, d1 = 0.f, d2 = 0.f, d3 = 0.f;
    #pragma unroll
    for (int e = 0; e < 16; ++e) {
      float4 kk = kr[e];
      d0 += qs[0][4*e]*kk.x + qs[0][4*e+1]*kk.y + qs[0][4*e+2]*kk.z + qs[0][4*e+3]*kk.w;
      d1 += qs[1][4*e]*kk.x + qs[1][4*e+1]*kk.y + qs[1][4*e+2]*kk.z + qs[1][4*e+3]*kk.w;
      d2 += qs[2][4*e]*kk.x + qs[2][4*e+1]*kk.y + qs[2][4*e+2]*kk.z + qs[2][4*e+3]*kk.w;
      d3 += qs[3][4*e]*kk.x + qs[3][4*e+1]*kk.y + qs[3][4*e+2]*kk.z + qs[3][4*e+3]*kk.w;
    }
    float dd[4] = {d0, d1, d2, d3};
    #pragma unroll
    for (int r = 0; r < 4; ++r) {
      float v = dd[r] * 0.125f;
      if (masked && c > rowsh[r]) v = -INFINITY;
      sc[r][c] = v;
    }
    lm0 = fmaxf(lm0, sc[0][c]); lm1 = fmaxf(lm1, sc[1][c]);
    lm2 = fmaxf(lm2, sc[2][c]); lm3 = fmaxf(lm3, sc[3][c]);
  }
  red[0][t] = lm0; red[1][t] = lm1; red[2][t] = lm2; red[3][t] = lm3;
  __syncthreads();
  {
    int w = t >> 6, lane = t & 63;
    float m = fmaxf(fmaxf(red[w][lane], red[w][lane + 64]),
                    fmaxf(red[w][lane + 128], red[w][lane + 192]));
    #pragma unroll
    for (int off = 32; off; off >>= 1) m = fmaxf(m, __shfl_xor(m, off));
    if (lane == 0) mxs[w] = m;
  }
  __syncthreads();
  float ls0 = 0.f, ls1 = 0.f, ls2 = 0.f, ls3 = 0.f;
  float m0 = mxs[0], m1 = mxs[1], m2 = mxs[2], m3 = mxs[3];
  for (int c = t; c < Lk; c += 256) {
    float e0 = expf(sc[0][c] - m0); sc[0][c] = e0; ls0 += e0;
    float e1 = expf(sc[1][c] - m1); sc[1][c] = e1; ls1 += e1;
    float e2 = expf(sc[2][c] - m2); sc[2][c] = e2; ls2 += e2;
    float e3 = expf(sc[3][c] - m3); sc[3][c] = e3; ls3 += e3;
  }
  red[0][t] = ls0; red[1][t] = ls1; red[2][t] = ls2; red[3][t] = ls3;
  __syncthreads();
  {
    int w = t >> 6, lane = t & 63;
    float s = red[w][lane] + red[w][lane + 64] + red[w][lane + 128] + red[w][lane + 192];
    #pragma unroll
    for (int off = 32; off; off >>= 1) s += __shfl_xor(s, off);
    if (lane == 0) sss[w] = s;
  }
  __syncthreads();
  {
    int g = t >> 6, d = t & 63;
    float a0 = 0.f, a1 = 0.f, a2 = 0.f, a3 = 0.f;
    for (int c = g; c < Lk; c += 4) {
      float v = Vp[(size_t)(b * Lk + c) * vstr + (h << 6) + d];
      a0 += sc[0][c] * v; a1 += sc[1][c] * v; a2 += sc[2][c] * v; a3 += sc[3][c] * v;
    }
    pv[g][0][d] = a0; pv[g][1][d] = a1; pv[g][2][d] = a2; pv[g][3][d] = a3;
  }
  __syncthreads();
  {
    int r = t >> 6, d = t & 63;
    int row = rowsh[r];
    if (row >= 0) {
      float s = pv[0][r][d] + pv[1][r][d] + pv[2][r][d] + pv[3][r][d];
      AO[((size_t)(b * Lq + row) << 9) + (h << 6) + d] = s / sss[r];
    }
  }
}

// ---------------- maxpool w3 s2 p1 along L ----------------
__global__ void k_maxpool(const float* __restrict__ y, float* __restrict__ o, int L) {
  int Lo = L >> 1;
  int i = blockIdx.x * 256 + threadIdx.x;
  int c = i & 511; int bj = i >> 9;
  int j = bj % Lo; int b = bj / Lo;
  float m = -INFINITY;
  int t0 = 2 * j - 1;
  #pragma unroll
  for (int k = 0; k < 3; ++k) {
    int tt = t0 + k;
    if (tt >= 0 && tt < L) m = fmaxf(m, y[((size_t)(b * L + tt) << 9) + c]);
  }
  o[((size_t)(b * Lo + j) << 9) + c] = m;
}

// ---------------- final projection 512->7 ----------------
__global__ void k_proj(const float* __restrict__ Xn, const float* __restrict__ pw,
                       const float* __restrict__ pb, float* __restrict__ out) {
  int i = blockIdx.x * 256 + threadIdx.x;
  if (i >= 16 * 512 * 7) return;
  int c = i % 7; int r = i / 7;
  int b = r >> 9; int j = r & 511;
  const float* xr = Xn + ((size_t)(b * 1024 + 512 + j) << 9);
  float acc = pb[c];
  for (int d2 = 0; d2 < 512; ++d2) acc += xr[d2] * pw[d2 * 7 + c];
  out[i] = acc;
}

// =====================================================================
extern "C" void kernel_launch(void* const* d_in, const int* in_sizes, int n_in,
                              void* d_out, int out_size, void* d_ws, size_t ws_size,
                              hipStream_t stream) {
  const float* x_enc      = (const float*)d_in[0];
  const float* x_mark_enc = (const float*)d_in[1];
  const float* x_dec      = (const float*)d_in[2];
  const float* x_mark_dec = (const float*)d_in[3];
  const float* enc_tok_w  = (const float*)d_in[4];
  const float* enc_mark_w = (const float*)d_in[5];
  const float* dec_tok_w  = (const float*)d_in[6];
  const float* dec_mark_w = (const float*)d_in[7];
  const float* enc_attn_w = (const float*)d_in[8];
  const float* enc_attn_b = (const float*)d_in[9];
  const float* enc_ffn1_w = (const float*)d_in[10];
  const float* enc_ffn1_b = (const float*)d_in[11];
  const float* enc_ffn2_w = (const float*)d_in[12];
  const float* enc_ffn2_b = (const float*)d_in[13];
  const float* enc_ln_g   = (const float*)d_in[14];
  const float* enc_ln_b   = (const float*)d_in[15];
  const float* distil_w   = (const float*)d_in[16];
  const float* distil_b   = (const float*)d_in[17];
  const float* distil_bn_g= (const float*)d_in[18];
  const float* distil_bn_b= (const float*)d_in[19];
  const float* enc_norm_g = (const float*)d_in[20];
  const float* enc_norm_b = (const float*)d_in[21];
  const float* dec_self_w = (const float*)d_in[22];
  const float* dec_self_b = (const float*)d_in[23];
  const float* dec_cross_w= (const float*)d_in[24];
  const float* dec_cross_b= (const float*)d_in[25];
  const float* dec_ffn1_w = (const float*)d_in[26];
  const float* dec_ffn1_b = (const float*)d_in[27];
  const float* dec_ffn2_w = (const float*)d_in[28];
  const float* dec_ffn2_b = (const float*)d_in[29];
  const float* dec_ln_g   = (const float*)d_in[30];
  const float* dec_ln_b   = (const float*)d_in[31];
  const float* dec_norm_g = (const float*)d_in[32];
  const float* dec_norm_b = (const float*)d_in[33];
  const float* proj_w     = (const float*)d_in[34];
  const float* proj_b     = (const float*)d_in[35];

  // -------- workspace layout (~157 MiB, same as round 4) --------
  float* ws = (float*)d_ws;
  float* X   = ws;                        // 16,777,216
  float* Y   = X   + 16777216;            // 16,777,216 (FFN inter / distil out / attn bufs)
  float* ENC = Y   + 16777216;            // 4,194,304
  float* PE  = ENC + 4194304;             // 1,048,576
  float* Mb  = PE  + 1048576;             //    65,536
  float* PS  = Mb  + 65536;               //    32,768
  f16*  WSP  = (f16*)(PS + 32768);        // 4,194,304 f16 (8 MiB)
  int* IDXi  = (int*)(WSP + 4194304);     //    81,920
  int* MTi   = IDXi + 81920;              //     1,280
  {
    size_t needF = 16777216ull*2 + 4194304 + 1048576 + 65536 + 32768 + 2097152;
    size_t needB = needF * 4 + (81920 + 1280) * 4;
    if (ws_size < needB) return;
  }

  auto ln = [&](const float* x, const float* g, const float* b, float* o, int rows) {
    k_ln<<<rows, 256, 0, stream>>>(x, g, b, o);
  };
  auto wsplit = [&](const float* W, f16* Wh, f16* Wl, int K, int N) {
    dim3 g(K >> 5, N >> 5);
    k_wsplit<<<g, 256, 0, stream>>>(W, Wh, Wl, K, N);
  };
  auto mgemm = [&](const float* A, const f16* Wh, const f16* Wl, const float* bias,
                   const float* resid, float* C, int M, int N, int K, int act) {
    dim3 g(N >> 7, M >> 7);
    if (act == 1)
      k_mgemm<0,1><<<g, 256, 0, stream>>>(A, Wh, Wl, bias, resid, nullptr, nullptr, C, M, N, K, 0);
    else
      k_mgemm<0,0><<<g, 256, 0, stream>>>(A, Wh, Wl, bias, resid, nullptr, nullptr, C, M, N, K, 0);
  };
  auto Uof = [](int Lx) { int v = 5 * (int)ceil(log((double)Lx)); return v < Lx ? v : Lx; };

  // ProbSparse attention over 4 z-slices of 4 batches each.
  // selfa: merged QKV (N=1536); else separate Q (512) + merged KV (1024).
  auto attn = [&](float* xq_base, const float* xkv_base, int Lq, int Lk, const float* w,
                  const float* bias, bool masked, u32 fold, bool selfa) {
    int U = Uof(Lk), uu = Uof(Lq);
    u32 r0, r1, ka, kb2;
    tf_block(0u, 42u, 0u, fold, r0, r1);   // fold_in(key(42), fold)
    tf_block(r0, r1, 0u, 1u, ka, kb2);     // randint internal split -> k2
    int n = Lq * U;
    k_idx<<<(n + 255) / 256, 256, 0, stream>>>(ka, kb2, n, Lk - 1, IDXi);

    f16 *Wqkvh = WSP,            *Wqkvl = WSP + 786432;   // selfa: [1536][512]
    f16 *WQh   = WSP,            *WQl   = WSP + 262144;   // cross: Q [512][512]
    f16 *WKVh  = WSP + 524288,   *WKVl  = WSP + 1048576;  // cross: KV [1024][512]
    f16 *WOh   = WSP + 1572864,  *WOl   = WSP + 1835008;
    if (selfa) {
      for (int i = 0; i < 3; ++i)
        wsplit(w + (size_t)i * 262144, Wqkvh + (size_t)i * 262144, Wqkvl + (size_t)i * 262144, 512, 512);
    } else {
      wsplit(w, WQh, WQl, 512, 512);
      for (int i = 0; i < 2; ++i)
        wsplit(w + 262144 + (size_t)i * 262144, WKVh + (size_t)i * 262144, WKVl + (size_t)i * 262144, 512, 512);
    }
    wsplit(w + 786432, WOh, WOl, 512, 512);

    for (int s = 0; s < 4; ++s) {
      float* xq        = xq_base  + (size_t)s * 4 * Lq * 512;
      const float* xkv = xkv_base + (size_t)s * 4 * Lk * 512;
      const float *qp, *kp, *vp;
      int qstr, kstr, vstr;
      float* AOb;
      if (selfa) {
        float* QKV = Y;
        AOb = Y + (size_t)4 * Lq * 1536;
        mgemm(xq, Wqkvh, Wqkvl, bias, nullptr, QKV, 4 * Lq, 1536, 512, 0);
        qp = QKV; qstr = 1536; kp = QKV + 512; kstr = 1536; vp = QKV + 1024; vstr = 1536;
      } else {
        float* Qb  = Y;
        float* KVb = Y + (size_t)4 * Lq * 512;
        AOb        = KVb + (size_t)4 * Lk * 1024;
        mgemm(xq,  WQh,  WQl,  bias,       nullptr, Qb,  4 * Lq, 512,  512, 0);
        mgemm(xkv, WKVh, WKVl, bias + 512, nullptr, KVb, 4 * Lk, 1024, 512, 0);
        qp = Qb; qstr = 512; kp = KVb; kstr = 1024; vp = KVb + 512; vstr = 1024;
      }
      int wids = 32 * Lq;
      k_qkM<<<wids / 4, 256, 0, stream>>>(qp, qstr, kp, kstr, IDXi, Mb, Lq, Lk, U);
      k_topk64<<<32, 64, 0, stream>>>(Mb, MTi, Lq, uu);
      if (masked) {
        k_cs1<<<256, 64, 0, stream>>>(vp, vstr, PS, Lq, Lq >> 3);
        k_cs2<<<32, 64, 0, stream>>>(PS);
        k_cs3<<<256, 64, 0, stream>>>(vp, vstr, PS, AOb, Lq, Lq >> 3);
      } else {
        k_cm1<<<512, 64, 0, stream>>>(vp, vstr, PS, Lk, Lk >> 4);
        int tot = 4 * Lq * 512;
        k_cm2<<<tot / 256, 256, 0, stream>>>(PS, AOb, 1.0f / (float)Lk, Lq, tot);
      }
      int nb = (uu + 3) >> 2;
      k_sattn4<<<32 * nb, 256, 0, stream>>>(qp, qstr, kp, kstr, vp, vstr, MTi, AOb,
                                            Lq, Lk, uu, masked ? 1 : 0);
      mgemm(AOb, WOh, WOl, bias + 1536, xq, xq, 4 * Lq, 512, 512, 0);
    }
  };

  auto ffn = [&](float* x, const float* w1, const float* b1,
                 const float* w2, const float* b2, int Mtot) {
    f16 *W1h = WSP,           *W1l = WSP + 1048576,
        *W2h = WSP + 2097152, *W2l = WSP + 3145728;
    wsplit(w1, W1h, W1l, 512, 2048);
    wsplit(w2, W2h, W2l, 2048, 512);
    for (int c0 = 0; c0 < Mtot; c0 += 8192) {
      mgemm(x + (size_t)c0 * 512, W1h, W1l, b1, nullptr, Y, 8192, 2048, 512, 1);
      mgemm(Y, W2h, W2l, b2, x + (size_t)c0 * 512, x + (size_t)c0 * 512, 8192, 512, 2048, 0);
    }
  };

  // ---------------- encoder ----------------
  k_pe<<<(2048 * 512) / 256, 256, 0, stream>>>(PE);
  k_embed<<<(16 * 2048 * 512) / 256, 256, 0, stream>>>(x_enc, x_mark_enc, enc_tok_w, enc_mark_w,
                                                       PE, X, 2048, 16 * 2048 * 512);
  int L = 2048;
  for (int l = 0; l < 3; ++l) {
    attn(X, X, L, L, enc_attn_w + (size_t)l * 4 * 262144, enc_attn_b + (size_t)l * 2048,
         false, (u32)l, true);
    ln(X, enc_ln_g + (size_t)(l * 2) * 512, enc_ln_b + (size_t)(l * 2) * 512, X, 16 * L);
    ffn(X, enc_ffn1_w + (size_t)l * 512 * 2048, enc_ffn1_b + (size_t)l * 2048,
        enc_ffn2_w + (size_t)l * 2048 * 512, enc_ffn2_b + (size_t)l * 512, 16 * L);
    ln(X, enc_ln_g + (size_t)(l * 2 + 1) * 512, enc_ln_b + (size_t)(l * 2 + 1) * 512, X, 16 * L);
    if (l < 2) {
      f16 *Dh = WSP, *Dl = WSP + 786432;
      k_wsplit_conv<<<(512 * 1536) / 256, 256, 0, stream>>>(distil_w + (size_t)l * 512 * 512 * 3, Dh, Dl);
      dim3 g(512 >> 7, (16 * L) >> 7);
      k_mgemm<1,2><<<g, 256, 0, stream>>>(X, Dh, Dl, distil_b + (size_t)l * 512, nullptr,
          distil_bn_g + (size_t)l * 512, distil_bn_b + (size_t)l * 512, Y, 16 * L, 512, 1536, L);
      int Lo = L >> 1;
      k_maxpool<<<(16 * Lo * 512) / 256, 256, 0, stream>>>(Y, X, L);
      L = Lo;
    }
  }
  ln(X, enc_norm_g, enc_norm_b, ENC, 16 * 512);

  // ---------------- decoder (in-place chain in X) ----------------
  k_embed<<<(16 * 1024 * 512) / 256, 256, 0, stream>>>(x_dec, x_mark_dec, dec_tok_w, dec_mark_w,
                                                       PE, X, 1024, 16 * 1024 * 512);
  for (int l = 0; l < 2; ++l) {
    attn(X, X, 1024, 1024, dec_self_w + (size_t)l * 4 * 262144, dec_self_b + (size_t)l * 2048,
         true, (u32)(100 + 2 * l), true);
    ln(X, dec_ln_g + (size_t)(l * 3) * 512, dec_ln_b + (size_t)(l * 3) * 512, X, 16384);
    attn(X, ENC, 1024, 512, dec_cross_w + (size_t)l * 4 * 262144, dec_cross_b + (size_t)l * 2048,
         false, (u32)(101 + 2 * l), false);
    ln(X, dec_ln_g + (size_t)(l * 3 + 1) * 512, dec_ln_b + (size_t)(l * 3 + 1) * 512, X, 16384);
    ffn(X, dec_ffn1_w + (size_t)l * 512 * 2048, dec_ffn1_b + (size_t)l * 2048,
        dec_ffn2_w + (size_t)l * 2048 * 512, dec_ffn2_b + (size_t)l * 512, 16384);
    ln(X, dec_ln_g + (size_t)(l * 3 + 2) * 512, dec_ln_b + (size_t)(l * 3 + 2) * 512, X, 16384);
  }
  ln(X, dec_norm_g, dec_norm_b, X, 16384);
  k_proj<<<(16 * 512 * 7 + 255) / 256, 256, 0, stream>>>(X, proj_w, proj_b, (float*)d_out);
}

// Round 7
// 14046.881 us; speedup vs baseline: 3.3153x; 1.0080x over previous
//
#include <hip/hip_runtime.h>
#include <math.h>
#include <stdint.h>

typedef unsigned int u32;
typedef _Float16 f16;
typedef __attribute__((ext_vector_type(8))) _Float16 f16x8;
typedef __attribute__((ext_vector_type(4))) float f32x4;

// ---------------- Threefry-2x32 (20 rounds), matches JAX ----------------
__host__ __device__ __forceinline__ u32 rotl32(u32 x, int r) { return (x << r) | (x >> (32 - r)); }
__host__ __device__ __forceinline__ void tf_round(u32& x0, u32& x1, int r) {
  x0 += x1; x1 = rotl32(x1, r); x1 ^= x0;
}
__host__ __device__ __forceinline__ void tf_block(u32 k0, u32 k1, u32 x0, u32 x1, u32& o0, u32& o1) {
  u32 k2 = k0 ^ k1 ^ 0x1BD11BDAu;
  x0 += k0; x1 += k1;
  tf_round(x0,x1,13); tf_round(x0,x1,15); tf_round(x0,x1,26); tf_round(x0,x1,6);
  x0 += k1; x1 += k2 + 1u;
  tf_round(x0,x1,17); tf_round(x0,x1,29); tf_round(x0,x1,16); tf_round(x0,x1,24);
  x0 += k2; x1 += k0 + 2u;
  tf_round(x0,x1,13); tf_round(x0,x1,15); tf_round(x0,x1,26); tf_round(x0,x1,6);
  x0 += k0; x1 += k1 + 3u;
  tf_round(x0,x1,17); tf_round(x0,x1,29); tf_round(x0,x1,16); tf_round(x0,x1,24);
  x0 += k1; x1 += k2 + 4u;
  tf_round(x0,x1,13); tf_round(x0,x1,15); tf_round(x0,x1,26); tf_round(x0,x1,6);
  x0 += k2; x1 += k0 + 5u;
  o0 = x0; o1 = x1;
}

__global__ void k_idx(u32 ka, u32 kb, int n, int mask, int* __restrict__ idx) {
  int i = blockIdx.x * 256 + threadIdx.x;
  if (i >= n) return;
  u32 b1, b2; tf_block(ka, kb, 0u, (u32)i, b1, b2);
  idx[i] = (int)((b1 ^ b2) & (u32)mask);
}

// ---------------- positional embedding ----------------
__global__ void k_pe(float* __restrict__ pe) {
  int i = blockIdx.x * 256 + threadIdx.x;
  if (i >= 2048 * 512) return;
  int t = i >> 9, o = i & 511;
  float arg = (float)((o >> 1) * 2) * (float)(-(log(10000.0) / 512.0));
  float div = (float)exp((double)arg);
  float ang32 = (float)t * div;
  double ang = (double)ang32;
  pe[i] = (float)((o & 1) ? cos(ang) : sin(ang));
}

// ---------------- embedding ----------------
__global__ __launch_bounds__(256) void k_embed(
    const float* __restrict__ x, const float* __restrict__ mark,
    const float* __restrict__ tw, const float* __restrict__ mw,
    const float* __restrict__ pe, float* __restrict__ o, int L, int total) {
  int i = blockIdx.x * 256 + threadIdx.x;
  if (i >= total) return;
  int oo = i & 511;
  int bt = i >> 9;
  int t = bt % L;
  int b = bt / L;
  float acc = pe[(t << 9) + oo];
  #pragma unroll
  for (int k = 0; k < 3; ++k) {
    int st = t + k - 1; if (st < 0) st += L; else if (st >= L) st -= L;
    const float* xr = x + (size_t)(b * L + st) * 7;
    const float* wr = tw + oo * 21 + k;
    #pragma unroll
    for (int ii = 0; ii < 7; ++ii) acc += xr[ii] * wr[ii * 3];
  }
  const float* mr = mark + (size_t)bt * 4;
  #pragma unroll
  for (int m = 0; m < 4; ++m) acc += mr[m] * mw[(m << 9) + oo];
  o[((size_t)bt << 9) + oo] = acc;
}

// ---------------- weight transpose + f16 split: W fp32 [K][N] -> Wh/Wl f16 [N][K] ----------------
__global__ __launch_bounds__(256) void k_wsplit(const float* __restrict__ W,
    f16* __restrict__ Wh, f16* __restrict__ Wl, int K, int N) {
  __shared__ float tile[32][33];
  int kb = blockIdx.x << 5, nb = blockIdx.y << 5;
  int t = threadIdx.x;
  int tr = t >> 5, tc = t & 31;
  #pragma unroll
  for (int p = 0; p < 4; ++p)
    tile[tr + p * 8][tc] = W[(size_t)(kb + tr + p * 8) * N + nb + tc];
  __syncthreads();
  #pragma unroll
  for (int p = 0; p < 4; ++p) {
    int n = tr + p * 8, k = tc;
    float v = tile[k][n];
    f16 h = (f16)v;
    size_t o = (size_t)(nb + n) * K + kb + k;
    Wh[o] = h;
    Wl[o] = (f16)((v - (float)h) * 2048.0f);
  }
}

// distil conv weight: w[o][i][tap] -> [N=o][K=tap*512+i] f16 split
__global__ void k_wsplit_conv(const float* __restrict__ w, f16* __restrict__ Wh, f16* __restrict__ Wl) {
  int i = blockIdx.x * 256 + threadIdx.x;
  if (i >= 512 * 1536) return;
  int o = i / 1536, k = i - o * 1536;
  float v = w[(size_t)o * 1536 + (k & 511) * 3 + (k >> 9)];
  f16 h = (f16)v;
  Wh[i] = h;
  Wl[i] = (f16)((v - (float)h) * 2048.0f);
}

// ---------------- MFMA GEMM, f16 2-level split (fp32-equivalent), BK=32 ----------------
// A,B both 2-level split -> 3 MFMA/slot. ALL GEMMs exact: any activation upstream of a
// top-k selection must be fp32-grade (round-6 lesson: f16-rounded A flips selections).
// GATHER=1: circular 3-tap row gather (distil conv), K=1536
// ACT: 0 none, 1 gelu, 2 bn+elu
__device__ __forceinline__ int swz_x(int r) { return ((((r >> 1) & 3) ^ ((r >> 3) & 3)) << 4); }

template<int GATHER, int ACT>
__global__ __launch_bounds__(256, 2) void k_mgemm(
    const float* __restrict__ A, const f16* __restrict__ Bh, const f16* __restrict__ Bl,
    const float* __restrict__ bias, const float* __restrict__ resid,
    const float* __restrict__ bns, const float* __restrict__ bnb,
    float* __restrict__ C, int M, int N, int K, int L) {
  __shared__ char lds[32768];
  char* pAh = lds;
  char* pAl = lds + 8192;
  char* pBh = lds + 16384;
  char* pBl = lds + 24576;
  const int t = threadIdx.x;
  const int bm = blockIdx.y << 7, bn = blockIdx.x << 7;
  const int sr = t >> 1;               // staging row 0..127
  const int e0 = (t & 1) << 4;         // k-elem offset 0/16
  int ab = 0, at = 0;
  if (GATHER) { int m = bm + sr; ab = m / L; at = m - ab * L; }
  const int lane = t & 63, wid = t >> 6;
  const int wr = (wid >> 1) << 6, wc = (wid & 1) << 6;
  const int fr = lane & 15;
  const int fkB = (lane >> 4) << 4;    // byte offset 0,16,32,48
  const f32x4 zero = {0.f, 0.f, 0.f, 0.f};
  f32x4 acc1[4][4], acc2[4][4];
  #pragma unroll
  for (int i = 0; i < 4; ++i)
    #pragma unroll
    for (int j = 0; j < 4; ++j) { acc1[i][j] = zero; acc2[i][j] = zero; }

  const int sxor = swz_x(sr);
  for (int k0 = 0; k0 < K; k0 += 32) {
    __syncthreads();
    // ---- stage A: 16 fp32 per thread -> split f16 ----
    const float* ap;
    if (GATHER) {
      int kk = k0 + e0;                 // 16-aligned, never crosses a 512 tap boundary
      int tap = kk >> 9, ii = kk & 511;
      int st = at + tap - 1; if (st < 0) st += L; else if (st >= L) st -= L;
      ap = A + (((size_t)(ab * L + st)) << 9) + ii;
    } else {
      ap = A + (size_t)(bm + sr) * K + k0 + e0;
    }
    float va[16];
    *(float4*)(va + 0)  = ((const float4*)ap)[0];
    *(float4*)(va + 4)  = ((const float4*)ap)[1];
    *(float4*)(va + 8)  = ((const float4*)ap)[2];
    *(float4*)(va + 12) = ((const float4*)ap)[3];
    f16 h16[16], l16[16];
    #pragma unroll
    for (int q = 0; q < 16; ++q) {
      f16 h = (f16)va[q]; h16[q] = h; l16[q] = (f16)((va[q] - (float)h) * 2048.0f);
    }
    {
      int ob0 = sr * 64 + ((e0 * 2) ^ sxor);
      int ob1 = sr * 64 + ((e0 * 2 + 16) ^ sxor);
      *(f16x8*)(pAh + ob0) = *(f16x8*)h16;
      *(f16x8*)(pAh + ob1) = *(f16x8*)(h16 + 8);
      *(f16x8*)(pAl + ob0) = *(f16x8*)l16;
      *(f16x8*)(pAl + ob1) = *(f16x8*)(l16 + 8);
    }
    // ---- stage B (pre-split f16 [N][K]) ----
    {
      const f16* bhp = Bh + (size_t)(bn + sr) * K + k0 + e0;
      const f16* blp = Bl + (size_t)(bn + sr) * K + k0 + e0;
      int ob0 = sr * 64 + ((e0 * 2) ^ sxor);
      int ob1 = sr * 64 + ((e0 * 2 + 16) ^ sxor);
      *(f16x8*)(pBh + ob0) = *(const f16x8*)(bhp);
      *(f16x8*)(pBh + ob1) = *(const f16x8*)(bhp + 8);
      *(f16x8*)(pBl + ob0) = *(const f16x8*)(blp);
      *(f16x8*)(pBl + ob1) = *(const f16x8*)(blp + 8);
    }
    __syncthreads();
    // ---- fragments + MFMA ----
    f16x8 ah4[4], al4[4];
    #pragma unroll
    for (int i = 0; i < 4; ++i) {
      int r = wr + i * 16 + fr;
      int ob = r * 64 + (fkB ^ swz_x(r));
      ah4[i] = *(f16x8*)(pAh + ob);
      al4[i] = *(f16x8*)(pAl + ob);
    }
    #pragma unroll
    for (int j = 0; j < 4; ++j) {
      int r = wc + j * 16 + fr;
      int ob = r * 64 + (fkB ^ swz_x(r));
      f16x8 bh_ = *(f16x8*)(pBh + ob);
      f16x8 bl_ = *(f16x8*)(pBl + ob);
      #pragma unroll
      for (int i = 0; i < 4; ++i) {
        acc1[i][j] = __builtin_amdgcn_mfma_f32_16x16x32_f16(ah4[i], bh_, acc1[i][j], 0, 0, 0);
        acc2[i][j] = __builtin_amdgcn_mfma_f32_16x16x32_f16(ah4[i], bl_, acc2[i][j], 0, 0, 0);
        acc2[i][j] = __builtin_amdgcn_mfma_f32_16x16x32_f16(al4[i], bh_, acc2[i][j], 0, 0, 0);
      }
    }
  }
  // ---- epilogue ----
  #pragma unroll
  for (int j = 0; j < 4; ++j) {
    int col = bn + wc + j * 16 + fr;
    float bsv = bias[col];
    float g2 = 0.f, b2 = 0.f;
    if (ACT == 2) { g2 = bns[col] * 0.9999950000375f; b2 = bnb[col]; }
    #pragma unroll
    for (int i = 0; i < 4; ++i) {
      #pragma unroll
      for (int r = 0; r < 4; ++r) {
        int row = bm + wr + i * 16 + ((lane >> 4) << 2) + r;
        float v = acc1[i][j][r] + acc2[i][j][r] * (1.0f / 2048.0f) + bsv;
        if (ACT == 1) v = 0.5f * v * (1.0f + erff(v * 0.70710678118654752f));
        if (ACT == 2) { v = v * g2 + b2; v = v > 0.f ? v : expm1f(v); }
        if (resid) v += resid[(size_t)row * N + col];
        C[(size_t)row * N + col] = v;
      }
    }
  }
}

// ---------------- LayerNorm (dim 512, in-place safe) ----------------
__global__ __launch_bounds__(256) void k_ln(const float* __restrict__ x,
    const float* __restrict__ g, const float* __restrict__ b, float* __restrict__ o) {
  int row = blockIdx.x, t = threadIdx.x;
  const float* xr = x + ((size_t)row << 9);
  float v0 = xr[t], v1 = xr[t + 256];
  float s = v0 + v1;
  #pragma unroll
  for (int off = 32; off; off >>= 1) s += __shfl_down(s, off);
  __shared__ float ls[4];
  if ((t & 63) == 0) ls[t >> 6] = s;
  __syncthreads();
  float mean = (ls[0] + ls[1] + ls[2] + ls[3]) * (1.f / 512.f);
  __syncthreads();
  float d0 = v0 - mean, d1 = v1 - mean;
  float q = d0 * d0 + d1 * d1;
  #pragma unroll
  for (int off = 32; off; off >>= 1) q += __shfl_down(q, off);
  if ((t & 63) == 0) ls[t >> 6] = q;
  __syncthreads();
  float var = (ls[0] + ls[1] + ls[2] + ls[3]) * (1.f / 512.f);
  float rs = rsqrtf(var + 1e-5f);
  float* orow = o + ((size_t)row << 9);
  orow[t] = d0 * rs * g[t] + b[t];
  orow[t + 256] = d1 * rs * g[t + 256] + b[t + 256];
}

// ---------------- M[bh,l] scoring (strided Q/K) ----------------
__global__ __launch_bounds__(256) void k_qkM(const float* __restrict__ Q, int qstr,
    const float* __restrict__ Kp, int kstr, const int* __restrict__ idx,
    float* __restrict__ M, int Lq, int Lk, int U) {
  int wid = (blockIdx.x * 256 + threadIdx.x) >> 6;
  int lane = threadIdx.x & 63;
  int l = wid & (Lq - 1); int bh = wid / Lq; int h = bh & 7; int b = bh >> 3;
  float dot = 0.f;
  if (lane < U) {
    int kr = idx[l * U + lane];
    const float4* q4 = (const float4*)(Q + (size_t)(b * Lq + l) * qstr + (h << 6));
    const float4* k4 = (const float4*)(Kp + (size_t)(b * Lk + kr) * kstr + (h << 6));
    #pragma unroll
    for (int i = 0; i < 16; ++i) {
      float4 a = q4[i], c = k4[i];
      dot += a.x * c.x + a.y * c.y + a.z * c.z + a.w * c.w;
    }
  }
  float mx = (lane < U) ? dot : -INFINITY;
  float sm = (lane < U) ? dot : 0.f;
  #pragma unroll
  for (int off = 32; off; off >>= 1) {
    mx = fmaxf(mx, __shfl_xor(mx, off));
    sm += __shfl_xor(sm, off);
  }
  if (lane == 0) M[(size_t)bh * Lq + l] = mx - sm / (float)Lk;
}

// ---------------- single-wave top-u per (b,h), ties -> lower index ----------------
__global__ void k_topk64(const float* __restrict__ M, int* __restrict__ mtop, int Lq, int u) {
  __shared__ float vals[2048];
  int bh = blockIdx.x, l = threadIdx.x;
  const float* Mr = M + (size_t)bh * Lq;
  for (int i = l; i < Lq; i += 64) vals[i] = Mr[i];
  __syncthreads();
  for (int it = 0; it < u; ++it) {
    float bv = -INFINITY; int bi = 0x7fffffff;
    for (int i = l; i < Lq; i += 64) {
      float v = vals[i];
      if (v > bv || (v == bv && i < bi)) { bv = v; bi = i; }
    }
    #pragma unroll
    for (int off = 32; off; off >>= 1) {
      float vv = __shfl_xor(bv, off); int ii = __shfl_xor(bi, off);
      if (vv > bv || (vv == bv && ii < bi)) { bv = vv; bi = ii; }
    }
    if (l == 0) { mtop[bh * u + it] = bi; vals[bi] = -INFINITY; }
    __syncthreads();
  }
}

// ---------------- ctx mean ----------------
__global__ void k_cm1(const float* __restrict__ V, int vstr, float* __restrict__ PS,
                      int Lk, int rows) {
  int bid = blockIdx.x;            // bh*16 + seg, bh in [0,32)
  int bh = bid >> 4, seg = bid & 15, d = threadIdx.x;
  int b = bh >> 3, h = bh & 7;
  const float* vp = V + (size_t)(b * Lk + seg * rows) * vstr + (h << 6) + d;
  float acc = 0.f;
  for (int r = 0; r < rows; ++r) acc += vp[(size_t)r * vstr];
  PS[(bid << 6) + d] = acc;
}
__global__ void k_cm2(const float* __restrict__ PS, float* __restrict__ AO, float invLk,
                      int Lq, int total) {
  int i = blockIdx.x * 256 + threadIdx.x;
  if (i >= total) return;
  int c = i & 511; int h = c >> 6; int d = c & 63;
  int r = i >> 9; int b = r / Lq;
  float acc = 0.f;
  #pragma unroll
  for (int s = 0; s < 16; ++s) acc += PS[(((((b << 3) + h) << 4) + s) << 6) + d];
  AO[i] = acc * invLk;
}

// ---------------- cumsum (masked ctx) ----------------
__global__ void k_cs1(const float* __restrict__ V, int vstr, float* __restrict__ PS,
                      int Lq, int rows) {
  int bid = blockIdx.x;            // bh*8 + seg
  int bh = bid >> 3, seg = bid & 7, d = threadIdx.x;
  int b = bh >> 3, h = bh & 7;
  const float* vp = V + (size_t)(b * Lq + seg * rows) * vstr + (h << 6) + d;
  float acc = 0.f;
  for (int r = 0; r < rows; ++r) acc += vp[(size_t)r * vstr];
  PS[(bid << 6) + d] = acc;
}
__global__ void k_cs2(float* __restrict__ PS) {
  int bh = blockIdx.x, d = threadIdx.x;
  float run = 0.f;
  for (int s = 0; s < 8; ++s) {
    int id = (((bh << 3) + s) << 6) + d;
    float t0 = PS[id]; PS[id] = run; run += t0;
  }
}
__global__ void k_cs3(const float* __restrict__ V, int vstr, const float* __restrict__ PS,
                      float* __restrict__ AO, int Lq, int rows) {
  int bid = blockIdx.x;
  int bh = bid >> 3, seg = bid & 7, d = threadIdx.x;
  int b = bh >> 3, h = bh & 7;
  float acc = PS[(bid << 6) + d];
  const float* vp = V + (size_t)(b * Lq + seg * rows) * vstr + (h << 6) + d;
  float* op = AO + ((size_t)(b * Lq + seg * rows) << 9) + (h << 6) + d;
  for (int r = 0; r < rows; ++r) { acc += vp[(size_t)r * vstr]; op[(size_t)r << 9] = acc; }
}

// ---------------- sparse attn: 4 selected rows per block ----------------
__global__ __launch_bounds__(256) void k_sattn4(
    const float* __restrict__ Q, int qstr, const float* __restrict__ Kp, int kstr,
    const float* __restrict__ Vp, int vstr, const int* __restrict__ mtop,
    float* __restrict__ AO, int Lq, int Lk, int u, int masked) {
  __shared__ float sc[4][2048];
  __shared__ float qs[4][64];
  __shared__ float red[4][256];
  __shared__ float pv[4][4][64];
  __shared__ int rowsh[4];
  __shared__ float mxs[4], sss[4];
  int nb = (u + 3) >> 2;
  int ub = blockIdx.x % nb, bh = blockIdx.x / nb;
  int b = bh >> 3, h = bh & 7;
  int t = threadIdx.x;
  if (t < 4) {
    int ui = ub * 4 + t;
    rowsh[t] = (ui < u) ? mtop[bh * u + ui] : -1;
  }
  __syncthreads();
  {
    int r = t >> 6, d = t & 63;
    int row = rowsh[r];
    qs[r][d] = (row >= 0) ? Q[(size_t)(b * Lq + row) * qstr + (h << 6) + d] : 0.f;
  }
  __syncthreads();
  float lm0 = -INFINITY, lm1 = -INFINITY, lm2 = -INFINITY, lm3 = -INFINITY;
  for (int c = t; c < Lk; c += 256) {
    const float4* kr = (const float4*)(Kp + (size_t)(b * Lk + c) * kstr + (h << 6));
    float d0 = 0.f, d1 = 0.f, d2 = 0.f, d3 = 0.f;
    #pragma unroll
    for (int e = 0; e < 16; ++e) {
      float4 kk = kr[e];
      d0 += qs[0][4*e]*kk.x + qs[0][4*e+1]*kk.y + qs[0][4*e+2]*kk.z + qs[0][4*e+3]*kk.w;
      d1 += qs[1][4*e]*kk.x + qs[1][4*e+1]*kk.y + qs[1][4*e+2]*kk.z + qs[1][4*e+3]*kk.w;
      d2 += qs[2][4*e]*kk.x + qs[2][4*e+1]*kk.y + qs[2][4*e+2]*kk.z + qs[2][4*e+3]*kk.w;
      d3 += qs[3][4*e]*kk.x + qs[3][4*e+1]*kk.y + qs[3][4*e+2]*kk.z + qs[3][4*e+3]*kk.w;
    }
    float dd[4] = {d0, d1, d2, d3};
    #pragma unroll
    for (int r = 0; r < 4; ++r) {
      float v = dd[r] * 0.125f;
      if (masked && c > rowsh[r]) v = -INFINITY;
      sc[r][c] = v;
    }
    lm0 = fmaxf(lm0, sc[0][c]); lm1 = fmaxf(lm1, sc[1][c]);
    lm2 = fmaxf(lm2, sc[2][c]); lm3 = fmaxf(lm3, sc[3][c]);
  }
  red[0][t] = lm0; red[1][t] = lm1; red[2][t] = lm2; red[3][t] = lm3;
  __syncthreads();
  {
    int w = t >> 6, lane = t & 63;
    float m = fmaxf(fmaxf(red[w][lane], red[w][lane + 64]),
                    fmaxf(red[w][lane + 128], red[w][lane + 192]));
    #pragma unroll
    for (int off = 32; off; off >>= 1) m = fmaxf(m, __shfl_xor(m, off));
    if (lane == 0) mxs[w] = m;
  }
  __syncthreads();
  float ls0 = 0.f, ls1 = 0.f, ls2 = 0.f, ls3 = 0.f;
  float m0 = mxs[0], m1 = mxs[1], m2 = mxs[2], m3 = mxs[3];
  for (int c = t; c < Lk; c += 256) {
    float e0 = expf(sc[0][c] - m0); sc[0][c] = e0; ls0 += e0;
    float e1 = expf(sc[1][c] - m1); sc[1][c] = e1; ls1 += e1;
    float e2 = expf(sc[2][c] - m2); sc[2][c] = e2; ls2 += e2;
    float e3 = expf(sc[3][c] - m3); sc[3][c] = e3; ls3 += e3;
  }
  red[0][t] = ls0; red[1][t] = ls1; red[2][t] = ls2; red[3][t] = ls3;
  __syncthreads();
  {
    int w = t >> 6, lane = t & 63;
    float s = red[w][lane] + red[w][lane + 64] + red[w][lane + 128] + red[w][lane + 192];
    #pragma unroll
    for (int off = 32; off; off >>= 1) s += __shfl_xor(s, off);
    if (lane == 0) sss[w] = s;
  }
  __syncthreads();
  {
    int g = t >> 6, d = t & 63;
    float a0 = 0.f, a1 = 0.f, a2 = 0.f, a3 = 0.f;
    for (int c = g; c < Lk; c += 4) {
      float v = Vp[(size_t)(b * Lk + c) * vstr + (h << 6) + d];
      a0 += sc[0][c] * v; a1 += sc[1][c] * v; a2 += sc[2][c] * v; a3 += sc[3][c] * v;
    }
    pv[g][0][d] = a0; pv[g][1][d] = a1; pv[g][2][d] = a2; pv[g][3][d] = a3;
  }
  __syncthreads();
  {
    int r = t >> 6, d = t & 63;
    int row = rowsh[r];
    if (row >= 0) {
      float s = pv[0][r][d] + pv[1][r][d] + pv[2][r][d] + pv[3][r][d];
      AO[((size_t)(b * Lq + row) << 9) + (h << 6) + d] = s / sss[r];
    }
  }
}

// ---------------- maxpool w3 s2 p1 along L ----------------
__global__ void k_maxpool(const float* __restrict__ y, float* __restrict__ o, int L) {
  int Lo = L >> 1;
  int i = blockIdx.x * 256 + threadIdx.x;
  int c = i & 511; int bj = i >> 9;
  int j = bj % Lo; int b = bj / Lo;
  float m = -INFINITY;
  int t0 = 2 * j - 1;
  #pragma unroll
  for (int k = 0; k < 3; ++k) {
    int tt = t0 + k;
    if (tt >= 0 && tt < L) m = fmaxf(m, y[((size_t)(b * L + tt) << 9) + c]);
  }
  o[((size_t)(b * Lo + j) << 9) + c] = m;
}

// ---------------- final projection 512->7 ----------------
__global__ void k_proj(const float* __restrict__ Xn, const float* __restrict__ pw,
                       const float* __restrict__ pb, float* __restrict__ out) {
  int i = blockIdx.x * 256 + threadIdx.x;
  if (i >= 16 * 512 * 7) return;
  int c = i % 7; int r = i / 7;
  int b = r >> 9; int j = r & 511;
  const float* xr = Xn + ((size_t)(b * 1024 + 512 + j) << 9);
  float acc = pb[c];
  for (int d2 = 0; d2 < 512; ++d2) acc += xr[d2] * pw[d2 * 7 + c];
  out[i] = acc;
}

// =====================================================================
extern "C" void kernel_launch(void* const* d_in, const int* in_sizes, int n_in,
                              void* d_out, int out_size, void* d_ws, size_t ws_size,
                              hipStream_t stream) {
  const float* x_enc      = (const float*)d_in[0];
  const float* x_mark_enc = (const float*)d_in[1];
  const float* x_dec      = (const float*)d_in[2];
  const float* x_mark_dec = (const float*)d_in[3];
  const float* enc_tok_w  = (const float*)d_in[4];
  const float* enc_mark_w = (const float*)d_in[5];
  const float* dec_tok_w  = (const float*)d_in[6];
  const float* dec_mark_w = (const float*)d_in[7];
  const float* enc_attn_w = (const float*)d_in[8];
  const float* enc_attn_b = (const float*)d_in[9];
  const float* enc_ffn1_w = (const float*)d_in[10];
  const float* enc_ffn1_b = (const float*)d_in[11];
  const float* enc_ffn2_w = (const float*)d_in[12];
  const float* enc_ffn2_b = (const float*)d_in[13];
  const float* enc_ln_g   = (const float*)d_in[14];
  const float* enc_ln_b   = (const float*)d_in[15];
  const float* distil_w   = (const float*)d_in[16];
  const float* distil_b   = (const float*)d_in[17];
  const float* distil_bn_g= (const float*)d_in[18];
  const float* distil_bn_b= (const float*)d_in[19];
  const float* enc_norm_g = (const float*)d_in[20];
  const float* enc_norm_b = (const float*)d_in[21];
  const float* dec_self_w = (const float*)d_in[22];
  const float* dec_self_b = (const float*)d_in[23];
  const float* dec_cross_w= (const float*)d_in[24];
  const float* dec_cross_b= (const float*)d_in[25];
  const float* dec_ffn1_w = (const float*)d_in[26];
  const float* dec_ffn1_b = (const float*)d_in[27];
  const float* dec_ffn2_w = (const float*)d_in[28];
  const float* dec_ffn2_b = (const float*)d_in[29];
  const float* dec_ln_g   = (const float*)d_in[30];
  const float* dec_ln_b   = (const float*)d_in[31];
  const float* dec_norm_g = (const float*)d_in[32];
  const float* dec_norm_b = (const float*)d_in[33];
  const float* proj_w     = (const float*)d_in[34];
  const float* proj_b     = (const float*)d_in[35];

  // -------- workspace layout (~157 MiB) --------
  float* ws = (float*)d_ws;
  float* X   = ws;                        // 16,777,216
  float* Y   = X   + 16777216;            // 16,777,216 (FFN inter / distil out / attn bufs)
  float* ENC = Y   + 16777216;            // 4,194,304
  float* PE  = ENC + 4194304;             // 1,048,576
  float* Mb  = PE  + 1048576;             //    65,536
  float* PS  = Mb  + 65536;               //    32,768
  f16*  WSP  = (f16*)(PS + 32768);        // 4,194,304 f16 (8 MiB)
  int* IDXi  = (int*)(WSP + 4194304);     //    81,920
  int* MTi   = IDXi + 81920;              //     1,280
  {
    size_t needF = 16777216ull*2 + 4194304 + 1048576 + 65536 + 32768 + 2097152;
    size_t needB = needF * 4 + (81920 + 1280) * 4;
    if (ws_size < needB) return;
  }

  auto ln = [&](const float* x, const float* g, const float* b, float* o, int rows) {
    k_ln<<<rows, 256, 0, stream>>>(x, g, b, o);
  };
  auto wsplit = [&](const float* W, f16* Wh, f16* Wl, int K, int N) {
    dim3 g(K >> 5, N >> 5);
    k_wsplit<<<g, 256, 0, stream>>>(W, Wh, Wl, K, N);
  };
  auto mgemm = [&](const float* A, const f16* Wh, const f16* Wl, const float* bias,
                   const float* resid, float* C, int M, int N, int K, int act) {
    dim3 g(N >> 7, M >> 7);
    if (act == 1)
      k_mgemm<0,1><<<g, 256, 0, stream>>>(A, Wh, Wl, bias, resid, nullptr, nullptr, C, M, N, K, 0);
    else
      k_mgemm<0,0><<<g, 256, 0, stream>>>(A, Wh, Wl, bias, resid, nullptr, nullptr, C, M, N, K, 0);
  };
  auto Uof = [](int Lx) { int v = 5 * (int)ceil(log((double)Lx)); return v < Lx ? v : Lx; };

  // ProbSparse attention over 4 z-slices of 4 batches each.
  // selfa: merged QKV (N=1536); else separate Q (512) + merged KV (1024).
  auto attn = [&](float* xq_base, const float* xkv_base, int Lq, int Lk, const float* w,
                  const float* bias, bool masked, u32 fold, bool selfa) {
    int U = Uof(Lk), uu = Uof(Lq);
    u32 r0, r1, ka, kb2;
    tf_block(0u, 42u, 0u, fold, r0, r1);   // fold_in(key(42), fold)
    tf_block(r0, r1, 0u, 1u, ka, kb2);     // randint internal split -> k2
    int n = Lq * U;
    k_idx<<<(n + 255) / 256, 256, 0, stream>>>(ka, kb2, n, Lk - 1, IDXi);

    f16 *Wqkvh = WSP,            *Wqkvl = WSP + 786432;   // selfa: [1536][512]
    f16 *WQh   = WSP,            *WQl   = WSP + 262144;   // cross: Q [512][512]
    f16 *WKVh  = WSP + 524288,   *WKVl  = WSP + 1048576;  // cross: KV [1024][512]
    f16 *WOh   = WSP + 1572864,  *WOl   = WSP + 1835008;
    if (selfa) {
      for (int i = 0; i < 3; ++i)
        wsplit(w + (size_t)i * 262144, Wqkvh + (size_t)i * 262144, Wqkvl + (size_t)i * 262144, 512, 512);
    } else {
      wsplit(w, WQh, WQl, 512, 512);
      for (int i = 0; i < 2; ++i)
        wsplit(w + 262144 + (size_t)i * 262144, WKVh + (size_t)i * 262144, WKVl + (size_t)i * 262144, 512, 512);
    }
    wsplit(w + 786432, WOh, WOl, 512, 512);

    for (int s = 0; s < 4; ++s) {
      float* xq        = xq_base  + (size_t)s * 4 * Lq * 512;
      const float* xkv = xkv_base + (size_t)s * 4 * Lk * 512;
      const float *qp, *kp, *vp;
      int qstr, kstr, vstr;
      float* AOb;
      if (selfa) {
        float* QKV = Y;
        AOb = Y + (size_t)4 * Lq * 1536;
        mgemm(xq, Wqkvh, Wqkvl, bias, nullptr, QKV, 4 * Lq, 1536, 512, 0);
        qp = QKV; qstr = 1536; kp = QKV + 512; kstr = 1536; vp = QKV + 1024; vstr = 1536;
      } else {
        float* Qb  = Y;
        float* KVb = Y + (size_t)4 * Lq * 512;
        AOb        = KVb + (size_t)4 * Lk * 1024;
        mgemm(xq,  WQh,  WQl,  bias,       nullptr, Qb,  4 * Lq, 512,  512, 0);
        mgemm(xkv, WKVh, WKVl, bias + 512, nullptr, KVb, 4 * Lk, 1024, 512, 0);
        qp = Qb; qstr = 512; kp = KVb; kstr = 1024; vp = KVb + 512; vstr = 1024;
      }
      int wids = 32 * Lq;
      k_qkM<<<wids / 4, 256, 0, stream>>>(qp, qstr, kp, kstr, IDXi, Mb, Lq, Lk, U);
      k_topk64<<<32, 64, 0, stream>>>(Mb, MTi, Lq, uu);
      if (masked) {
        k_cs1<<<256, 64, 0, stream>>>(vp, vstr, PS, Lq, Lq >> 3);
        k_cs2<<<32, 64, 0, stream>>>(PS);
        k_cs3<<<256, 64, 0, stream>>>(vp, vstr, PS, AOb, Lq, Lq >> 3);
      } else {
        k_cm1<<<512, 64, 0, stream>>>(vp, vstr, PS, Lk, Lk >> 4);
        int tot = 4 * Lq * 512;
        k_cm2<<<tot / 256, 256, 0, stream>>>(PS, AOb, 1.0f / (float)Lk, Lq, tot);
      }
      int nb = (uu + 3) >> 2;
      k_sattn4<<<32 * nb, 256, 0, stream>>>(qp, qstr, kp, kstr, vp, vstr, MTi, AOb,
                                            Lq, Lk, uu, masked ? 1 : 0);
      mgemm(AOb, WOh, WOl, bias + 1536, xq, xq, 4 * Lq, 512, 512, 0);
    }
  };

  auto ffn = [&](float* x, const float* w1, const float* b1,
                 const float* w2, const float* b2, int Mtot) {
    f16 *W1h = WSP,           *W1l = WSP + 1048576,
        *W2h = WSP + 2097152, *W2l = WSP + 3145728;
    wsplit(w1, W1h, W1l, 512, 2048);
    wsplit(w2, W2h, W2l, 2048, 512);
    for (int c0 = 0; c0 < Mtot; c0 += 8192) {
      mgemm(x + (size_t)c0 * 512, W1h, W1l, b1, nullptr, Y, 8192, 2048, 512, 1);
      mgemm(Y, W2h, W2l, b2, x + (size_t)c0 * 512, x + (size_t)c0 * 512, 8192, 512, 2048, 0);
    }
  };

  // ---------------- encoder ----------------
  k_pe<<<(2048 * 512) / 256, 256, 0, stream>>>(PE);
  k_embed<<<(16 * 2048 * 512) / 256, 256, 0, stream>>>(x_enc, x_mark_enc, enc_tok_w, enc_mark_w,
                                                       PE, X, 2048, 16 * 2048 * 512);
  int L = 2048;
  for (int l = 0; l < 3; ++l) {
    attn(X, X, L, L, enc_attn_w + (size_t)l * 4 * 262144, enc_attn_b + (size_t)l * 2048,
         false, (u32)l, true);
    ln(X, enc_ln_g + (size_t)(l * 2) * 512, enc_ln_b + (size_t)(l * 2) * 512, X, 16 * L);
    ffn(X, enc_ffn1_w + (size_t)l * 512 * 2048, enc_ffn1_b + (size_t)l * 2048,
        enc_ffn2_w + (size_t)l * 2048 * 512, enc_ffn2_b + (size_t)l * 512, 16 * L);
    ln(X, enc_ln_g + (size_t)(l * 2 + 1) * 512, enc_ln_b + (size_t)(l * 2 + 1) * 512, X, 16 * L);
    if (l < 2) {
      f16 *Dh = WSP, *Dl = WSP + 786432;
      k_wsplit_conv<<<(512 * 1536) / 256, 256, 0, stream>>>(distil_w + (size_t)l * 512 * 512 * 3, Dh, Dl);
      dim3 g(512 >> 7, (16 * L) >> 7);
      k_mgemm<1,2><<<g, 256, 0, stream>>>(X, Dh, Dl, distil_b + (size_t)l * 512, nullptr,
          distil_bn_g + (size_t)l * 512, distil_bn_b + (size_t)l * 512, Y, 16 * L, 512, 1536, L);
      int Lo = L >> 1;
      k_maxpool<<<(16 * Lo * 512) / 256, 256, 0, stream>>>(Y, X, L);
      L = Lo;
    }
  }
  ln(X, enc_norm_g, enc_norm_b, ENC, 16 * 512);

  // ---------------- decoder (in-place chain in X) ----------------
  k_embed<<<(16 * 1024 * 512) / 256, 256, 0, stream>>>(x_dec, x_mark_dec, dec_tok_w, dec_mark_w,
                                                       PE, X, 1024, 16 * 1024 * 512);
  for (int l = 0; l < 2; ++l) {
    attn(X, X, 1024, 1024, dec_self_w + (size_t)l * 4 * 262144, dec_self_b + (size_t)l * 2048,
         true, (u32)(100 + 2 * l), true);
    ln(X, dec_ln_g + (size_t)(l * 3) * 512, dec_ln_b + (size_t)(l * 3) * 512, X, 16384);
    attn(X, ENC, 1024, 512, dec_cross_w + (size_t)l * 4 * 262144, dec_cross_b + (size_t)l * 2048,
         false, (u32)(101 + 2 * l), false);
    ln(X, dec_ln_g + (size_t)(l * 3 + 1) * 512, dec_ln_b + (size_t)(l * 3 + 1) * 512, X, 16384);
    ffn(X, dec_ffn1_w + (size_t)l * 512 * 2048, dec_ffn1_b + (size_t)l * 2048,
        dec_ffn2_w + (size_t)l * 2048 * 512, dec_ffn2_b + (size_t)l * 512, 16384);
    ln(X, dec_ln_g + (size_t)(l * 3 + 2) * 512, dec_ln_b + (size_t)(l * 3 + 2) * 512, X, 16384);
  }
  ln(X, dec_norm_g, dec_norm_b, X, 16384);
  k_proj<<<(16 * 512 * 7 + 255) / 256, 256, 0, stream>>>(X, proj_w, proj_b, (float*)d_out);
}

// Round 8
// 13788.351 us; speedup vs baseline: 3.3775x; 1.0187x over previous
//
#include <hip/hip_runtime.h>
#include <math.h>
#include <stdint.h>

typedef unsigned int u32;
typedef _Float16 f16;
typedef __attribute__((ext_vector_type(8))) _Float16 f16x8;
typedef __attribute__((ext_vector_type(4))) float f32x4;

// ---------------- Threefry-2x32 (20 rounds), matches JAX ----------------
__host__ __device__ __forceinline__ u32 rotl32(u32 x, int r) { return (x << r) | (x >> (32 - r)); }
__host__ __device__ __forceinline__ void tf_round(u32& x0, u32& x1, int r) {
  x0 += x1; x1 = rotl32(x1, r); x1 ^= x0;
}
__host__ __device__ __forceinline__ void tf_block(u32 k0, u32 k1, u32 x0, u32 x1, u32& o0, u32& o1) {
  u32 k2 = k0 ^ k1 ^ 0x1BD11BDAu;
  x0 += k0; x1 += k1;
  tf_round(x0,x1,13); tf_round(x0,x1,15); tf_round(x0,x1,26); tf_round(x0,x1,6);
  x0 += k1; x1 += k2 + 1u;
  tf_round(x0,x1,17); tf_round(x0,x1,29); tf_round(x0,x1,16); tf_round(x0,x1,24);
  x0 += k2; x1 += k0 + 2u;
  tf_round(x0,x1,13); tf_round(x0,x1,15); tf_round(x0,x1,26); tf_round(x0,x1,6);
  x0 += k0; x1 += k1 + 3u;
  tf_round(x0,x1,17); tf_round(x0,x1,29); tf_round(x0,x1,16); tf_round(x0,x1,24);
  x0 += k1; x1 += k2 + 4u;
  tf_round(x0,x1,13); tf_round(x0,x1,15); tf_round(x0,x1,26); tf_round(x0,x1,6);
  x0 += k2; x1 += k0 + 5u;
  o0 = x0; o1 = x1;
}

__global__ void k_idx(u32 ka, u32 kb, int n, int mask, int* __restrict__ idx) {
  int i = blockIdx.x * 256 + threadIdx.x;
  if (i >= n) return;
  u32 b1, b2; tf_block(ka, kb, 0u, (u32)i, b1, b2);
  idx[i] = (int)((b1 ^ b2) & (u32)mask);
}

// ---------------- positional embedding ----------------
__global__ void k_pe(float* __restrict__ pe) {
  int i = blockIdx.x * 256 + threadIdx.x;
  if (i >= 2048 * 512) return;
  int t = i >> 9, o = i & 511;
  float arg = (float)((o >> 1) * 2) * (float)(-(log(10000.0) / 512.0));
  float div = (float)exp((double)arg);
  float ang32 = (float)t * div;
  double ang = (double)ang32;
  pe[i] = (float)((o & 1) ? cos(ang) : sin(ang));
}

// ---------------- embedding ----------------
__global__ __launch_bounds__(256) void k_embed(
    const float* __restrict__ x, const float* __restrict__ mark,
    const float* __restrict__ tw, const float* __restrict__ mw,
    const float* __restrict__ pe, float* __restrict__ o, int L, int total) {
  int i = blockIdx.x * 256 + threadIdx.x;
  if (i >= total) return;
  int oo = i & 511;
  int bt = i >> 9;
  int t = bt % L;
  int b = bt / L;
  float acc = pe[(t << 9) + oo];
  #pragma unroll
  for (int k = 0; k < 3; ++k) {
    int st = t + k - 1; if (st < 0) st += L; else if (st >= L) st -= L;
    const float* xr = x + (size_t)(b * L + st) * 7;
    const float* wr = tw + oo * 21 + k;
    #pragma unroll
    for (int ii = 0; ii < 7; ++ii) acc += xr[ii] * wr[ii * 3];
  }
  const float* mr = mark + (size_t)bt * 4;
  #pragma unroll
  for (int m = 0; m < 4; ++m) acc += mr[m] * mw[(m << 9) + oo];
  o[((size_t)bt << 9) + oo] = acc;
}

// ---------------- weight transpose + f16 split: W fp32 [K][N] -> Wh/Wl f16 [N][K] ----------------
__global__ __launch_bounds__(256) void k_wsplit(const float* __restrict__ W,
    f16* __restrict__ Wh, f16* __restrict__ Wl, int K, int N) {
  __shared__ float tile[32][33];
  int kb = blockIdx.x << 5, nb = blockIdx.y << 5;
  int t = threadIdx.x;
  int tr = t >> 5, tc = t & 31;
  #pragma unroll
  for (int p = 0; p < 4; ++p)
    tile[tr + p * 8][tc] = W[(size_t)(kb + tr + p * 8) * N + nb + tc];
  __syncthreads();
  #pragma unroll
  for (int p = 0; p < 4; ++p) {
    int n = tr + p * 8, k = tc;
    float v = tile[k][n];
    f16 h = (f16)v;
    size_t o = (size_t)(nb + n) * K + kb + k;
    Wh[o] = h;
    Wl[o] = (f16)((v - (float)h) * 2048.0f);
  }
}

// distil conv weight: w[o][i][tap] -> [N=o][K=tap*512+i] f16 split
__global__ void k_wsplit_conv(const float* __restrict__ w, f16* __restrict__ Wh, f16* __restrict__ Wl) {
  int i = blockIdx.x * 256 + threadIdx.x;
  if (i >= 512 * 1536) return;
  int o = i / 1536, k = i - o * 1536;
  float v = w[(size_t)o * 1536 + (k & 511) * 3 + (k >> 9)];
  f16 h = (f16)v;
  Wh[i] = h;
  Wl[i] = (f16)((v - (float)h) * 2048.0f);
}

// ---------------- activation split: A fp32 [M][K] -> Ah/Al f16 [M][K] ----------------
__global__ void k_asplit(const float* __restrict__ A, f16* __restrict__ Ah,
                         f16* __restrict__ Al, int total8) {
  int i = blockIdx.x * 256 + threadIdx.x;
  if (i >= total8) return;
  const float4* ap = (const float4*)(A + (size_t)i * 8);
  float4 u0 = ap[0], u1 = ap[1];
  float uv[8] = {u0.x, u0.y, u0.z, u0.w, u1.x, u1.y, u1.z, u1.w};
  f16 h8[8], l8[8];
  #pragma unroll
  for (int e = 0; e < 8; ++e) {
    f16 h = (f16)uv[e]; h8[e] = h; l8[e] = (f16)((uv[e] - (float)h) * 2048.0f);
  }
  *(f16x8*)(Ah + (size_t)i * 8) = *(f16x8*)h8;
  *(f16x8*)(Al + (size_t)i * 8) = *(f16x8*)l8;
}

__device__ __forceinline__ int swz_x(int r) { return ((((r >> 1) & 3) ^ ((r >> 3) & 3)) << 4); }

__device__ __forceinline__ void gload16(const void* g, void* l) {
  __builtin_amdgcn_global_load_lds(
      (const __attribute__((address_space(1))) void*)g,
      (__attribute__((address_space(3))) void*)l, 16, 0, 0);
}

// ---------------- MFMA GEMM v2: pre-split f16 A and B, async LDS staging, dbuf ----------------
// 3 MFMA/slot (fp32-equivalent). OSPLIT=1: write C as split f16 pair (post-GELU).
template<int ACT, int OSPLIT>
__global__ __launch_bounds__(256, 2) void k_mgemm2(
    const f16* __restrict__ Ah, const f16* __restrict__ Al,
    const f16* __restrict__ Bh, const f16* __restrict__ Bl,
    const float* __restrict__ bias, const float* __restrict__ resid,
    float* __restrict__ C, f16* __restrict__ Ch, f16* __restrict__ Cl,
    int M, int N, int K) {
  __shared__ char lds[65536];          // 2 bufs x 4 arrays x 8KB (128 rows x 64B)
  const int t = threadIdx.x;
  const int bm = blockIdx.y << 7, bn = blockIdx.x << 7;
  const int w = t >> 6, l = t & 63;
  const int lr = l >> 2;               // row within 16-row block
  const int qx = (l & 3) << 4;         // byte chunk within 64B row
  const int wr = (w >> 1) << 6, wc = (w & 1) << 6;
  const int fr = l & 15;
  const int fkB = (l >> 4) << 4;
  const f32x4 zero = {0.f, 0.f, 0.f, 0.f};
  f32x4 acc1[4][4], acc2[4][4];
  #pragma unroll
  for (int i = 0; i < 4; ++i)
    #pragma unroll
    for (int j = 0; j < 4; ++j) { acc1[i][j] = zero; acc2[i][j] = zero; }

  // stage one 128x32 K-tile of all four arrays into buffer bufo (linear LDS dest,
  // inverse-swizzled global source so swizzled ds_reads see linear columns)
  auto stage = [&](int k0, int bufo) {
    #pragma unroll
    for (int c = 0; c < 2; ++c) {
      int r = w * 32 + c * 16 + lr;
      int sx = qx ^ swz_x(r);
      const char* gAh = (const char*)(Ah + (size_t)(bm + r) * K + k0) + sx;
      const char* gAl = (const char*)(Al + (size_t)(bm + r) * K + k0) + sx;
      const char* gBh = (const char*)(Bh + (size_t)(bn + r) * K + k0) + sx;
      const char* gBl = (const char*)(Bl + (size_t)(bn + r) * K + k0) + sx;
      char* base = lds + bufo + w * 2048 + c * 1024;   // + lane*16 by HW
      gload16(gAh, base);
      gload16(gAl, base + 8192);
      gload16(gBh, base + 16384);
      gload16(gBl, base + 24576);
    }
  };

  int nt = K >> 5;
  stage(0, 0);
  __syncthreads();
  int bufo = 0;
  for (int tt = 0; tt < nt; ++tt) {
    int nb = bufo ^ 32768;
    if (tt + 1 < nt) stage((tt + 1) << 5, nb);
    char* pAh = lds + bufo;
    char* pAl = pAh + 8192;
    char* pBh = pAh + 16384;
    char* pBl = pAh + 24576;
    f16x8 ah4[4], al4[4];
    #pragma unroll
    for (int i = 0; i < 4; ++i) {
      int r = wr + i * 16 + fr;
      int ob = r * 64 + (fkB ^ swz_x(r));
      ah4[i] = *(f16x8*)(pAh + ob);
      al4[i] = *(f16x8*)(pAl + ob);
    }
    #pragma unroll
    for (int j = 0; j < 4; ++j) {
      int r = wc + j * 16 + fr;
      int ob = r * 64 + (fkB ^ swz_x(r));
      f16x8 bh_ = *(f16x8*)(pBh + ob);
      f16x8 bl_ = *(f16x8*)(pBl + ob);
      #pragma unroll
      for (int i = 0; i < 4; ++i) {
        acc1[i][j] = __builtin_amdgcn_mfma_f32_16x16x32_f16(ah4[i], bh_, acc1[i][j], 0, 0, 0);
        acc2[i][j] = __builtin_amdgcn_mfma_f32_16x16x32_f16(ah4[i], bl_, acc2[i][j], 0, 0, 0);
        acc2[i][j] = __builtin_amdgcn_mfma_f32_16x16x32_f16(al4[i], bh_, acc2[i][j], 0, 0, 0);
      }
    }
    __syncthreads();   // drains vmcnt(0): nb ready; cur free for overwrite
    bufo = nb;
  }
  // ---- epilogue ----
  #pragma unroll
  for (int j = 0; j < 4; ++j) {
    int col = bn + wc + j * 16 + fr;
    float bsv = bias[col];
    #pragma unroll
    for (int i = 0; i < 4; ++i) {
      #pragma unroll
      for (int r = 0; r < 4; ++r) {
        int row = bm + wr + i * 16 + ((l >> 4) << 2) + r;
        float v = acc1[i][j][r] + acc2[i][j][r] * (1.0f / 2048.0f) + bsv;
        if (ACT == 1) v = 0.5f * v * (1.0f + erff(v * 0.70710678118654752f));
        if (OSPLIT) {
          f16 h = (f16)v;
          Ch[(size_t)row * N + col] = h;
          Cl[(size_t)row * N + col] = (f16)((v - (float)h) * 2048.0f);
        } else {
          if (resid) v += resid[(size_t)row * N + col];
          C[(size_t)row * N + col] = v;
        }
      }
    }
  }
}

// ---------------- old MFMA GEMM (reg-staged, BK=32) — kept for distil GATHER ----------------
template<int GATHER, int ACT>
__global__ __launch_bounds__(256, 2) void k_mgemm(
    const float* __restrict__ A, const f16* __restrict__ Bh, const f16* __restrict__ Bl,
    const float* __restrict__ bias, const float* __restrict__ resid,
    const float* __restrict__ bns, const float* __restrict__ bnb,
    float* __restrict__ C, int M, int N, int K, int L) {
  __shared__ char lds[32768];
  char* pAh = lds;
  char* pAl = lds + 8192;
  char* pBh = lds + 16384;
  char* pBl = lds + 24576;
  const int t = threadIdx.x;
  const int bm = blockIdx.y << 7, bn = blockIdx.x << 7;
  const int sr = t >> 1;
  const int e0 = (t & 1) << 4;
  int ab = 0, at = 0;
  if (GATHER) { int m = bm + sr; ab = m / L; at = m - ab * L; }
  const int lane = t & 63, wid = t >> 6;
  const int wr = (wid >> 1) << 6, wc = (wid & 1) << 6;
  const int fr = lane & 15;
  const int fkB = (lane >> 4) << 4;
  const f32x4 zero = {0.f, 0.f, 0.f, 0.f};
  f32x4 acc1[4][4], acc2[4][4];
  #pragma unroll
  for (int i = 0; i < 4; ++i)
    #pragma unroll
    for (int j = 0; j < 4; ++j) { acc1[i][j] = zero; acc2[i][j] = zero; }

  const int sxor = swz_x(sr);
  for (int k0 = 0; k0 < K; k0 += 32) {
    __syncthreads();
    const float* ap;
    if (GATHER) {
      int kk = k0 + e0;
      int tap = kk >> 9, ii = kk & 511;
      int st = at + tap - 1; if (st < 0) st += L; else if (st >= L) st -= L;
      ap = A + (((size_t)(ab * L + st)) << 9) + ii;
    } else {
      ap = A + (size_t)(bm + sr) * K + k0 + e0;
    }
    float va[16];
    *(float4*)(va + 0)  = ((const float4*)ap)[0];
    *(float4*)(va + 4)  = ((const float4*)ap)[1];
    *(float4*)(va + 8)  = ((const float4*)ap)[2];
    *(float4*)(va + 12) = ((const float4*)ap)[3];
    f16 h16[16], l16[16];
    #pragma unroll
    for (int q = 0; q < 16; ++q) {
      f16 h = (f16)va[q]; h16[q] = h; l16[q] = (f16)((va[q] - (float)h) * 2048.0f);
    }
    {
      int ob0 = sr * 64 + ((e0 * 2) ^ sxor);
      int ob1 = sr * 64 + ((e0 * 2 + 16) ^ sxor);
      *(f16x8*)(pAh + ob0) = *(f16x8*)h16;
      *(f16x8*)(pAh + ob1) = *(f16x8*)(h16 + 8);
      *(f16x8*)(pAl + ob0) = *(f16x8*)l16;
      *(f16x8*)(pAl + ob1) = *(f16x8*)(l16 + 8);
    }
    {
      const f16* bhp = Bh + (size_t)(bn + sr) * K + k0 + e0;
      const f16* blp = Bl + (size_t)(bn + sr) * K + k0 + e0;
      int ob0 = sr * 64 + ((e0 * 2) ^ sxor);
      int ob1 = sr * 64 + ((e0 * 2 + 16) ^ sxor);
      *(f16x8*)(pBh + ob0) = *(const f16x8*)(bhp);
      *(f16x8*)(pBh + ob1) = *(const f16x8*)(bhp + 8);
      *(f16x8*)(pBl + ob0) = *(const f16x8*)(blp);
      *(f16x8*)(pBl + ob1) = *(const f16x8*)(blp + 8);
    }
    __syncthreads();
    f16x8 ah4[4], al4[4];
    #pragma unroll
    for (int i = 0; i < 4; ++i) {
      int r = wr + i * 16 + fr;
      int ob = r * 64 + (fkB ^ swz_x(r));
      ah4[i] = *(f16x8*)(pAh + ob);
      al4[i] = *(f16x8*)(pAl + ob);
    }
    #pragma unroll
    for (int j = 0; j < 4; ++j) {
      int r = wc + j * 16 + fr;
      int ob = r * 64 + (fkB ^ swz_x(r));
      f16x8 bh_ = *(f16x8*)(pBh + ob);
      f16x8 bl_ = *(f16x8*)(pBl + ob);
      #pragma unroll
      for (int i = 0; i < 4; ++i) {
        acc1[i][j] = __builtin_amdgcn_mfma_f32_16x16x32_f16(ah4[i], bh_, acc1[i][j], 0, 0, 0);
        acc2[i][j] = __builtin_amdgcn_mfma_f32_16x16x32_f16(ah4[i], bl_, acc2[i][j], 0, 0, 0);
        acc2[i][j] = __builtin_amdgcn_mfma_f32_16x16x32_f16(al4[i], bh_, acc2[i][j], 0, 0, 0);
      }
    }
  }
  #pragma unroll
  for (int j = 0; j < 4; ++j) {
    int col = bn + wc + j * 16 + fr;
    float bsv = bias[col];
    float g2 = 0.f, b2 = 0.f;
    if (ACT == 2) { g2 = bns[col] * 0.9999950000375f; b2 = bnb[col]; }
    #pragma unroll
    for (int i = 0; i < 4; ++i) {
      #pragma unroll
      for (int r = 0; r < 4; ++r) {
        int row = bm + wr + i * 16 + ((lane >> 4) << 2) + r;
        float v = acc1[i][j][r] + acc2[i][j][r] * (1.0f / 2048.0f) + bsv;
        if (ACT == 1) v = 0.5f * v * (1.0f + erff(v * 0.70710678118654752f));
        if (ACT == 2) { v = v * g2 + b2; v = v > 0.f ? v : expm1f(v); }
        if (resid) v += resid[(size_t)row * N + col];
        C[(size_t)row * N + col] = v;
      }
    }
  }
}

// ---------------- LayerNorm (dim 512, in-place safe) ----------------
__global__ __launch_bounds__(256) void k_ln(const float* __restrict__ x,
    const float* __restrict__ g, const float* __restrict__ b, float* __restrict__ o) {
  int row = blockIdx.x, t = threadIdx.x;
  const float* xr = x + ((size_t)row << 9);
  float v0 = xr[t], v1 = xr[t + 256];
  float s = v0 + v1;
  #pragma unroll
  for (int off = 32; off; off >>= 1) s += __shfl_down(s, off);
  __shared__ float ls[4];
  if ((t & 63) == 0) ls[t >> 6] = s;
  __syncthreads();
  float mean = (ls[0] + ls[1] + ls[2] + ls[3]) * (1.f / 512.f);
  __syncthreads();
  float d0 = v0 - mean, d1 = v1 - mean;
  float q = d0 * d0 + d1 * d1;
  #pragma unroll
  for (int off = 32; off; off >>= 1) q += __shfl_down(q, off);
  if ((t & 63) == 0) ls[t >> 6] = q;
  __syncthreads();
  float var = (ls[0] + ls[1] + ls[2] + ls[3]) * (1.f / 512.f);
  float rs = rsqrtf(var + 1e-5f);
  float* orow = o + ((size_t)row << 9);
  orow[t] = d0 * rs * g[t] + b[t];
  orow[t + 256] = d1 * rs * g[t + 256] + b[t + 256];
}

// ---------------- M[bh,l] scoring (strided Q/K) ----------------
__global__ __launch_bounds__(256) void k_qkM(const float* __restrict__ Q, int qstr,
    const float* __restrict__ Kp, int kstr, const int* __restrict__ idx,
    float* __restrict__ M, int Lq, int Lk, int U) {
  int wid = (blockIdx.x * 256 + threadIdx.x) >> 6;
  int lane = threadIdx.x & 63;
  int l = wid & (Lq - 1); int bh = wid / Lq; int h = bh & 7; int b = bh >> 3;
  float dot = 0.f;
  if (lane < U) {
    int kr = idx[l * U + lane];
    const float4* q4 = (const float4*)(Q + (size_t)(b * Lq + l) * qstr + (h << 6));
    const float4* k4 = (const float4*)(Kp + (size_t)(b * Lk + kr) * kstr + (h << 6));
    #pragma unroll
    for (int i = 0; i < 16; ++i) {
      float4 a = q4[i], c = k4[i];
      dot += a.x * c.x + a.y * c.y + a.z * c.z + a.w * c.w;
    }
  }
  float mx = (lane < U) ? dot : -INFINITY;
  float sm = (lane < U) ? dot : 0.f;
  #pragma unroll
  for (int off = 32; off; off >>= 1) {
    mx = fmaxf(mx, __shfl_xor(mx, off));
    sm += __shfl_xor(sm, off);
  }
  if (lane == 0) M[(size_t)bh * Lq + l] = mx - sm / (float)Lk;
}

// ---------------- single-wave top-u per (b,h), ties -> lower index ----------------
__global__ void k_topk64(const float* __restrict__ M, int* __restrict__ mtop, int Lq, int u) {
  __shared__ float vals[2048];
  int bh = blockIdx.x, l = threadIdx.x;
  const float* Mr = M + (size_t)bh * Lq;
  for (int i = l; i < Lq; i += 64) vals[i] = Mr[i];
  __syncthreads();
  for (int it = 0; it < u; ++it) {
    float bv = -INFINITY; int bi = 0x7fffffff;
    for (int i = l; i < Lq; i += 64) {
      float v = vals[i];
      if (v > bv || (v == bv && i < bi)) { bv = v; bi = i; }
    }
    #pragma unroll
    for (int off = 32; off; off >>= 1) {
      float vv = __shfl_xor(bv, off); int ii = __shfl_xor(bi, off);
      if (vv > bv || (vv == bv && ii < bi)) { bv = vv; bi = ii; }
    }
    if (l == 0) { mtop[bh * u + it] = bi; vals[bi] = -INFINITY; }
    __syncthreads();
  }
}

// ---------------- ctx mean ----------------
__global__ void k_cm1(const float* __restrict__ V, int vstr, float* __restrict__ PS,
                      int Lk, int rows) {
  int bid = blockIdx.x;
  int bh = bid >> 4, seg = bid & 15, d = threadIdx.x;
  int b = bh >> 3, h = bh & 7;
  const float* vp = V + (size_t)(b * Lk + seg * rows) * vstr + (h << 6) + d;
  float acc = 0.f;
  for (int r = 0; r < rows; ++r) acc += vp[(size_t)r * vstr];
  PS[(bid << 6) + d] = acc;
}
__global__ void k_cm2(const float* __restrict__ PS, float* __restrict__ AO, float invLk,
                      int Lq, int total) {
  int i = blockIdx.x * 256 + threadIdx.x;
  if (i >= total) return;
  int c = i & 511; int h = c >> 6; int d = c & 63;
  int r = i >> 9; int b = r / Lq;
  float acc = 0.f;
  #pragma unroll
  for (int s = 0; s < 16; ++s) acc += PS[(((((b << 3) + h) << 4) + s) << 6) + d];
  AO[i] = acc * invLk;
}

// ---------------- cumsum (masked ctx) ----------------
__global__ void k_cs1(const float* __restrict__ V, int vstr, float* __restrict__ PS,
                      int Lq, int rows) {
  int bid = blockIdx.x;
  int bh = bid >> 3, seg = bid & 7, d = threadIdx.x;
  int b = bh >> 3, h = bh & 7;
  const float* vp = V + (size_t)(b * Lq + seg * rows) * vstr + (h << 6) + d;
  float acc = 0.f;
  for (int r = 0; r < rows; ++r) acc += vp[(size_t)r * vstr];
  PS[(bid << 6) + d] = acc;
}
__global__ void k_cs2(float* __restrict__ PS) {
  int bh = blockIdx.x, d = threadIdx.x;
  float run = 0.f;
  for (int s = 0; s < 8; ++s) {
    int id = (((bh << 3) + s) << 6) + d;
    float t0 = PS[id]; PS[id] = run; run += t0;
  }
}
__global__ void k_cs3(const float* __restrict__ V, int vstr, const float* __restrict__ PS,
                      float* __restrict__ AO, int Lq, int rows) {
  int bid = blockIdx.x;
  int bh = bid >> 3, seg = bid & 7, d = threadIdx.x;
  int b = bh >> 3, h = bh & 7;
  float acc = PS[(bid << 6) + d];
  const float* vp = V + (size_t)(b * Lq + seg * rows) * vstr + (h << 6) + d;
  float* op = AO + ((size_t)(b * Lq + seg * rows) << 9) + (h << 6) + d;
  for (int r = 0; r < rows; ++r) { acc += vp[(size_t)r * vstr]; op[(size_t)r << 9] = acc; }
}

// ---------------- sparse attn: 4 selected rows per block ----------------
__global__ __launch_bounds__(256) void k_sattn4(
    const float* __restrict__ Q, int qstr, const float* __restrict__ Kp, int kstr,
    const float* __restrict__ Vp, int vstr, const int* __restrict__ mtop,
    float* __restrict__ AO, int Lq, int Lk, int u, int masked) {
  __shared__ float sc[4][2048];
  __shared__ float qs[4][64];
  __shared__ float red[4][256];
  __shared__ float pv[4][4][64];
  __shared__ int rowsh[4];
  __shared__ float mxs[4], sss[4];
  int nb = (u + 3) >> 2;
  int ub = blockIdx.x % nb, bh = blockIdx.x / nb;
  int b = bh >> 3, h = bh & 7;
  int t = threadIdx.x;
  if (t < 4) {
    int ui = ub * 4 + t;
    rowsh[t] = (ui < u) ? mtop[bh * u + ui] : -1;
  }
  __syncthreads();
  {
    int r = t >> 6, d = t & 63;
    int row = rowsh[r];
    qs[r][d] = (row >= 0) ? Q[(size_t)(b * Lq + row) * qstr + (h << 6) + d] : 0.f;
  }
  __syncthreads();
  float lm0 = -INFINITY, lm1 = -INFINITY, lm2 = -INFINITY, lm3 = -INFINITY;
  for (int c = t; c < Lk; c += 256) {
    const float4* kr = (const float4*)(Kp + (size_t)(b * Lk + c) * kstr + (h << 6));
    float d0 = 0.f, d1 = 0.f, d2 = 0.f, d3 = 0.f;
    #pragma unroll
    for (int e = 0; e < 16; ++e) {
      float4 kk = kr[e];
      d0 += qs[0][4*e]*kk.x + qs[0][4*e+1]*kk.y + qs[0][4*e+2]*kk.z + qs[0][4*e+3]*kk.w;
      d1 += qs[1][4*e]*kk.x + qs[1][4*e+1]*kk.y + qs[1][4*e+2]*kk.z + qs[1][4*e+3]*kk.w;
      d2 += qs[2][4*e]*kk.x + qs[2][4*e+1]*kk.y + qs[2][4*e+2]*kk.z + qs[2][4*e+3]*kk.w;
      d3 += qs[3][4*e]*kk.x + qs[3][4*e+1]*kk.y + qs[3][4*e+2]*kk.z + qs[3][4*e+3]*kk.w;
    }
    float dd[4] = {d0, d1, d2, d3};
    #pragma unroll
    for (int r = 0; r < 4; ++r) {
      float v = dd[r] * 0.125f;
      if (masked && c > rowsh[r]) v = -INFINITY;
      sc[r][c] = v;
    }
    lm0 = fmaxf(lm0, sc[0][c]); lm1 = fmaxf(lm1, sc[1][c]);
    lm2 = fmaxf(lm2, sc[2][c]); lm3 = fmaxf(lm3, sc[3][c]);
  }
  red[0][t] = lm0; red[1][t] = lm1; red[2][t] = lm2; red[3][t] = lm3;
  __syncthreads();
  {
    int w = t >> 6, lane = t & 63;
    float m = fmaxf(fmaxf(red[w][lane], red[w][lane + 64]),
                    fmaxf(red[w][lane + 128], red[w][lane + 192]));
    #pragma unroll
    for (int off = 32; off; off >>= 1) m = fmaxf(m, __shfl_xor(m, off));
    if (lane == 0) mxs[w] = m;
  }
  __syncthreads();
  float ls0 = 0.f, ls1 = 0.f, ls2 = 0.f, ls3 = 0.f;
  float m0 = mxs[0], m1 = mxs[1], m2 = mxs[2], m3 = mxs[3];
  for (int c = t; c < Lk; c += 256) {
    float e0 = expf(sc[0][c] - m0); sc[0][c] = e0; ls0 += e0;
    float e1 = expf(sc[1][c] - m1); sc[1][c] = e1; ls1 += e1;
    float e2 = expf(sc[2][c] - m2); sc[2][c] = e2; ls2 += e2;
    float e3 = expf(sc[3][c] - m3); sc[3][c] = e3; ls3 += e3;
  }
  red[0][t] = ls0; red[1][t] = ls1; red[2][t] = ls2; red[3][t] = ls3;
  __syncthreads();
  {
    int w = t >> 6, lane = t & 63;
    float s = red[w][lane] + red[w][lane + 64] + red[w][lane + 128] + red[w][lane + 192];
    #pragma unroll
    for (int off = 32; off; off >>= 1) s += __shfl_xor(s, off);
    if (lane == 0) sss[w] = s;
  }
  __syncthreads();
  {
    int g = t >> 6, d = t & 63;
    float a0 = 0.f, a1 = 0.f, a2 = 0.f, a3 = 0.f;
    for (int c = g; c < Lk; c += 4) {
      float v = Vp[(size_t)(b * Lk + c) * vstr + (h << 6) + d];
      a0 += sc[0][c] * v; a1 += sc[1][c] * v; a2 += sc[2][c] * v; a3 += sc[3][c] * v;
    }
    pv[g][0][d] = a0; pv[g][1][d] = a1; pv[g][2][d] = a2; pv[g][3][d] = a3;
  }
  __syncthreads();
  {
    int r = t >> 6, d = t & 63;
    int row = rowsh[r];
    if (row >= 0) {
      float s = pv[0][r][d] + pv[1][r][d] + pv[2][r][d] + pv[3][r][d];
      AO[((size_t)(b * Lq + row) << 9) + (h << 6) + d] = s / sss[r];
    }
  }
}

// ---------------- maxpool w3 s2 p1 along L ----------------
__global__ void k_maxpool(const float* __restrict__ y, float* __restrict__ o, int L) {
  int Lo = L >> 1;
  int i = blockIdx.x * 256 + threadIdx.x;
  int c = i & 511; int bj = i >> 9;
  int j = bj % Lo; int b = bj / Lo;
  float m = -INFINITY;
  int t0 = 2 * j - 1;
  #pragma unroll
  for (int k = 0; k < 3; ++k) {
    int tt = t0 + k;
    if (tt >= 0 && tt < L) m = fmaxf(m, y[((size_t)(b * L + tt) << 9) + c]);
  }
  o[((size_t)(b * Lo + j) << 9) + c] = m;
}

// ---------------- final projection 512->7 ----------------
__global__ void k_proj(const float* __restrict__ Xn, const float* __restrict__ pw,
                       const float* __restrict__ pb, float* __restrict__ out) {
  int i = blockIdx.x * 256 + threadIdx.x;
  if (i >= 16 * 512 * 7) return;
  int c = i % 7; int r = i / 7;
  int b = r >> 9; int j = r & 511;
  const float* xr = Xn + ((size_t)(b * 1024 + 512 + j) << 9);
  float acc = pb[c];
  for (int d2 = 0; d2 < 512; ++d2) acc += xr[d2] * pw[d2 * 7 + c];
  out[i] = acc;
}

// =====================================================================
extern "C" void kernel_launch(void* const* d_in, const int* in_sizes, int n_in,
                              void* d_out, int out_size, void* d_ws, size_t ws_size,
                              hipStream_t stream) {
  const float* x_enc      = (const float*)d_in[0];
  const float* x_mark_enc = (const float*)d_in[1];
  const float* x_dec      = (const float*)d_in[2];
  const float* x_mark_dec = (const float*)d_in[3];
  const float* enc_tok_w  = (const float*)d_in[4];
  const float* enc_mark_w = (const float*)d_in[5];
  const float* dec_tok_w  = (const float*)d_in[6];
  const float* dec_mark_w = (const float*)d_in[7];
  const float* enc_attn_w = (const float*)d_in[8];
  const float* enc_attn_b = (const float*)d_in[9];
  const float* enc_ffn1_w = (const float*)d_in[10];
  const float* enc_ffn1_b = (const float*)d_in[11];
  const float* enc_ffn2_w = (const float*)d_in[12];
  const float* enc_ffn2_b = (const float*)d_in[13];
  const float* enc_ln_g   = (const float*)d_in[14];
  const float* enc_ln_b   = (const float*)d_in[15];
  const float* distil_w   = (const float*)d_in[16];
  const float* distil_b   = (const float*)d_in[17];
  const float* distil_bn_g= (const float*)d_in[18];
  const float* distil_bn_b= (const float*)d_in[19];
  const float* enc_norm_g = (const float*)d_in[20];
  const float* enc_norm_b = (const float*)d_in[21];
  const float* dec_self_w = (const float*)d_in[22];
  const float* dec_self_b = (const float*)d_in[23];
  const float* dec_cross_w= (const float*)d_in[24];
  const float* dec_cross_b= (const float*)d_in[25];
  const float* dec_ffn1_w = (const float*)d_in[26];
  const float* dec_ffn1_b = (const float*)d_in[27];
  const float* dec_ffn2_w = (const float*)d_in[28];
  const float* dec_ffn2_b = (const float*)d_in[29];
  const float* dec_ln_g   = (const float*)d_in[30];
  const float* dec_ln_b   = (const float*)d_in[31];
  const float* dec_norm_g = (const float*)d_in[32];
  const float* dec_norm_b = (const float*)d_in[33];
  const float* proj_w     = (const float*)d_in[34];
  const float* proj_b     = (const float*)d_in[35];

  // -------- workspace layout (~181 MiB) --------
  float* ws = (float*)d_ws;
  float* X   = ws;                        // 16,777,216 f32
  float* Y   = X   + 16777216;            // 16,777,216 f32 (attn bufs / Yh|Yl split alias)
  float* ENC = Y   + 16777216;            // 4,194,304 f32
  float* PE  = ENC + 4194304;             // 1,048,576 f32
  float* Mb  = PE  + 1048576;             //    65,536
  float* PS  = Mb  + 65536;               //    32,768
  f16*  WSP  = (f16*)(PS + 32768);        // 4,194,304 f16 (weights split)
  f16*  ASPh = WSP + 4194304;             // 4,194,304 f16 (A split hi)
  f16*  ASPl = ASPh + 4194304;            // 4,194,304 f16 (A split lo)
  int* IDXi  = (int*)(ASPl + 4194304);    //    81,920
  int* MTi   = IDXi + 81920;              //     1,280
  {
    size_t needF = 16777216ull*2 + 4194304 + 1048576 + 65536 + 32768
                 + 2097152 /*WSP*/ + 4194304 /*ASP pair*/;
    size_t needB = needF * 4 + (81920 + 1280) * 4;
    if (ws_size < needB) return;
  }
  f16* Yh = (f16*)Y;                      // FFN1 split output aliases Y
  f16* Yl = Yh + 16777216;

  auto ln = [&](const float* x, const float* g, const float* b, float* o, int rows) {
    k_ln<<<rows, 256, 0, stream>>>(x, g, b, o);
  };
  auto wsplit = [&](const float* W, f16* Wh, f16* Wl, int K, int N) {
    dim3 g(K >> 5, N >> 5);
    k_wsplit<<<g, 256, 0, stream>>>(W, Wh, Wl, K, N);
  };
  auto asplit = [&](const float* A, int M, int K) {
    int t8 = (M * K) >> 3;
    k_asplit<<<(t8 + 255) / 256, 256, 0, stream>>>(A, ASPh, ASPl, t8);
  };
  auto mg2 = [&](const f16* Ah, const f16* Al, const f16* Wh, const f16* Wl,
                 const float* bias, const float* resid, float* C, int M, int N, int K) {
    dim3 g(N >> 7, M >> 7);
    k_mgemm2<0,0><<<g, 256, 0, stream>>>(Ah, Al, Wh, Wl, bias, resid, C, nullptr, nullptr, M, N, K);
  };
  auto mg2gs = [&](const f16* Ah, const f16* Al, const f16* Wh, const f16* Wl,
                   const float* bias, f16* Ch, f16* Cl, int M, int N, int K) {
    dim3 g(N >> 7, M >> 7);
    k_mgemm2<1,1><<<g, 256, 0, stream>>>(Ah, Al, Wh, Wl, bias, nullptr, nullptr, Ch, Cl, M, N, K);
  };
  auto Uof = [](int Lx) { int v = 5 * (int)ceil(log((double)Lx)); return v < Lx ? v : Lx; };

  // ProbSparse attention over 4 z-slices of 4 batches each.
  auto attn = [&](float* xq_base, const float* xkv_base, int Lq, int Lk, const float* w,
                  const float* bias, bool masked, u32 fold, bool selfa) {
    int U = Uof(Lk), uu = Uof(Lq);
    u32 r0, r1, ka, kb2;
    tf_block(0u, 42u, 0u, fold, r0, r1);   // fold_in(key(42), fold)
    tf_block(r0, r1, 0u, 1u, ka, kb2);     // randint internal split -> k2
    int n = Lq * U;
    k_idx<<<(n + 255) / 256, 256, 0, stream>>>(ka, kb2, n, Lk - 1, IDXi);

    f16 *Wqkvh = WSP,            *Wqkvl = WSP + 786432;   // selfa: [1536][512]
    f16 *WQh   = WSP,            *WQl   = WSP + 262144;   // cross: Q [512][512]
    f16 *WKVh  = WSP + 524288,   *WKVl  = WSP + 1048576;  // cross: KV [1024][512]
    f16 *WOh   = WSP + 1572864,  *WOl   = WSP + 1835008;
    if (selfa) {
      for (int i = 0; i < 3; ++i)
        wsplit(w + (size_t)i * 262144, Wqkvh + (size_t)i * 262144, Wqkvl + (size_t)i * 262144, 512, 512);
    } else {
      wsplit(w, WQh, WQl, 512, 512);
      for (int i = 0; i < 2; ++i)
        wsplit(w + 262144 + (size_t)i * 262144, WKVh + (size_t)i * 262144, WKVl + (size_t)i * 262144, 512, 512);
    }
    wsplit(w + 786432, WOh, WOl, 512, 512);

    for (int s = 0; s < 4; ++s) {
      float* xq        = xq_base  + (size_t)s * 4 * Lq * 512;
      const float* xkv = xkv_base + (size_t)s * 4 * Lk * 512;
      const float *qp, *kp, *vp;
      int qstr, kstr, vstr;
      float* AOb;
      if (selfa) {
        float* QKV = Y;
        AOb = Y + (size_t)4 * Lq * 1536;
        asplit(xq, 4 * Lq, 512);
        mg2(ASPh, ASPl, Wqkvh, Wqkvl, bias, nullptr, QKV, 4 * Lq, 1536, 512);
        qp = QKV; qstr = 1536; kp = QKV + 512; kstr = 1536; vp = QKV + 1024; vstr = 1536;
      } else {
        float* Qb  = Y;
        float* KVb = Y + (size_t)4 * Lq * 512;
        AOb        = KVb + (size_t)4 * Lk * 1024;
        asplit(xq, 4 * Lq, 512);
        mg2(ASPh, ASPl, WQh, WQl, bias, nullptr, Qb, 4 * Lq, 512, 512);
        asplit(xkv, 4 * Lk, 512);
        mg2(ASPh, ASPl, WKVh, WKVl, bias + 512, nullptr, KVb, 4 * Lk, 1024, 512);
        qp = Qb; qstr = 512; kp = KVb; kstr = 1024; vp = KVb + 512; vstr = 1024;
      }
      int wids = 32 * Lq;
      k_qkM<<<wids / 4, 256, 0, stream>>>(qp, qstr, kp, kstr, IDXi, Mb, Lq, Lk, U);
      k_topk64<<<32, 64, 0, stream>>>(Mb, MTi, Lq, uu);
      if (masked) {
        k_cs1<<<256, 64, 0, stream>>>(vp, vstr, PS, Lq, Lq >> 3);
        k_cs2<<<32, 64, 0, stream>>>(PS);
        k_cs3<<<256, 64, 0, stream>>>(vp, vstr, PS, AOb, Lq, Lq >> 3);
      } else {
        k_cm1<<<512, 64, 0, stream>>>(vp, vstr, PS, Lk, Lk >> 4);
        int tot = 4 * Lq * 512;
        k_cm2<<<tot / 256, 256, 0, stream>>>(PS, AOb, 1.0f / (float)Lk, Lq, tot);
      }
      int nb = (uu + 3) >> 2;
      k_sattn4<<<32 * nb, 256, 0, stream>>>(qp, qstr, kp, kstr, vp, vstr, MTi, AOb,
                                            Lq, Lk, uu, masked ? 1 : 0);
      asplit(AOb, 4 * Lq, 512);
      mg2(ASPh, ASPl, WOh, WOl, bias + 1536, xq, xq, 4 * Lq, 512, 512);
    }
  };

  auto ffn = [&](float* x, const float* w1, const float* b1,
                 const float* w2, const float* b2, int Mtot) {
    f16 *W1h = WSP,           *W1l = WSP + 1048576,
        *W2h = WSP + 2097152, *W2l = WSP + 3145728;
    wsplit(w1, W1h, W1l, 512, 2048);
    wsplit(w2, W2h, W2l, 2048, 512);
    for (int c0 = 0; c0 < Mtot; c0 += 8192) {
      asplit(x + (size_t)c0 * 512, 8192, 512);
      mg2gs(ASPh, ASPl, W1h, W1l, b1, Yh, Yl, 8192, 2048, 512);
      mg2(Yh, Yl, W2h, W2l, b2, x + (size_t)c0 * 512, x + (size_t)c0 * 512, 8192, 512, 2048);
    }
  };

  // ---------------- encoder ----------------
  k_pe<<<(2048 * 512) / 256, 256, 0, stream>>>(PE);
  k_embed<<<(16 * 2048 * 512) / 256, 256, 0, stream>>>(x_enc, x_mark_enc, enc_tok_w, enc_mark_w,
                                                       PE, X, 2048, 16 * 2048 * 512);
  int L = 2048;
  for (int l = 0; l < 3; ++l) {
    attn(X, X, L, L, enc_attn_w + (size_t)l * 4 * 262144, enc_attn_b + (size_t)l * 2048,
         false, (u32)l, true);
    ln(X, enc_ln_g + (size_t)(l * 2) * 512, enc_ln_b + (size_t)(l * 2) * 512, X, 16 * L);
    ffn(X, enc_ffn1_w + (size_t)l * 512 * 2048, enc_ffn1_b + (size_t)l * 2048,
        enc_ffn2_w + (size_t)l * 2048 * 512, enc_ffn2_b + (size_t)l * 512, 16 * L);
    ln(X, enc_ln_g + (size_t)(l * 2 + 1) * 512, enc_ln_b + (size_t)(l * 2 + 1) * 512, X, 16 * L);
    if (l < 2) {
      f16 *Dh = WSP, *Dl = WSP + 786432;
      k_wsplit_conv<<<(512 * 1536) / 256, 256, 0, stream>>>(distil_w + (size_t)l * 512 * 512 * 3, Dh, Dl);
      dim3 g(512 >> 7, (16 * L) >> 7);
      k_mgemm<1,2><<<g, 256, 0, stream>>>(X, Dh, Dl, distil_b + (size_t)l * 512, nullptr,
          distil_bn_g + (size_t)l * 512, distil_bn_b + (size_t)l * 512, Y, 16 * L, 512, 1536, L);
      int Lo = L >> 1;
      k_maxpool<<<(16 * Lo * 512) / 256, 256, 0, stream>>>(Y, X, L);
      L = Lo;
    }
  }
  ln(X, enc_norm_g, enc_norm_b, ENC, 16 * 512);

  // ---------------- decoder (in-place chain in X) ----------------
  k_embed<<<(16 * 1024 * 512) / 256, 256, 0, stream>>>(x_dec, x_mark_dec, dec_tok_w, dec_mark_w,
                                                       PE, X, 1024, 16 * 1024 * 512);
  for (int l = 0; l < 2; ++l) {
    attn(X, X, 1024, 1024, dec_self_w + (size_t)l * 4 * 262144, dec_self_b + (size_t)l * 2048,
         true, (u32)(100 + 2 * l), true);
    ln(X, dec_ln_g + (size_t)(l * 3) * 512, dec_ln_b + (size_t)(l * 3) * 512, X, 16384);
    attn(X, ENC, 1024, 512, dec_cross_w + (size_t)l * 4 * 262144, dec_cross_b + (size_t)l * 2048,
         false, (u32)(101 + 2 * l), false);
    ln(X, dec_ln_g + (size_t)(l * 3 + 1) * 512, dec_ln_b + (size_t)(l * 3 + 1) * 512, X, 16384);
    ffn(X, dec_ffn1_w + (size_t)l * 512 * 2048, dec_ffn1_b + (size_t)l * 2048,
        dec_ffn2_w + (size_t)l * 2048 * 512, dec_ffn2_b + (size_t)l * 512, 16384);
    ln(X, dec_ln_g + (size_t)(l * 3 + 2) * 512, dec_ln_b + (size_t)(l * 3 + 2) * 512, X, 16384);
  }
  ln(X, dec_norm_g, dec_norm_b, X, 16384);
  k_proj<<<(16 * 512 * 7 + 255) / 256, 256, 0, stream>>>(X, proj_w, proj_b, (float*)d_out);
}

// Round 9
// 13506.723 us; speedup vs baseline: 3.4479x; 1.0209x over previous
//
#include <hip/hip_runtime.h>
#include <math.h>
#include <stdint.h>

typedef unsigned int u32;
typedef _Float16 f16;
typedef __attribute__((ext_vector_type(8))) _Float16 f16x8;
typedef __attribute__((ext_vector_type(4))) float f32x4;

// ---------------- Threefry-2x32 (20 rounds), matches JAX ----------------
__host__ __device__ __forceinline__ u32 rotl32(u32 x, int r) { return (x << r) | (x >> (32 - r)); }
__host__ __device__ __forceinline__ void tf_round(u32& x0, u32& x1, int r) {
  x0 += x1; x1 = rotl32(x1, r); x1 ^= x0;
}
__host__ __device__ __forceinline__ void tf_block(u32 k0, u32 k1, u32 x0, u32 x1, u32& o0, u32& o1) {
  u32 k2 = k0 ^ k1 ^ 0x1BD11BDAu;
  x0 += k0; x1 += k1;
  tf_round(x0,x1,13); tf_round(x0,x1,15); tf_round(x0,x1,26); tf_round(x0,x1,6);
  x0 += k1; x1 += k2 + 1u;
  tf_round(x0,x1,17); tf_round(x0,x1,29); tf_round(x0,x1,16); tf_round(x0,x1,24);
  x0 += k2; x1 += k0 + 2u;
  tf_round(x0,x1,13); tf_round(x0,x1,15); tf_round(x0,x1,26); tf_round(x0,x1,6);
  x0 += k0; x1 += k1 + 3u;
  tf_round(x0,x1,17); tf_round(x0,x1,29); tf_round(x0,x1,16); tf_round(x0,x1,24);
  x0 += k1; x1 += k2 + 4u;
  tf_round(x0,x1,13); tf_round(x0,x1,15); tf_round(x0,x1,26); tf_round(x0,x1,6);
  x0 += k2; x1 += k0 + 5u;
  o0 = x0; o1 = x1;
}

__global__ void k_idx(u32 ka, u32 kb, int n, int mask, int* __restrict__ idx) {
  int i = blockIdx.x * 256 + threadIdx.x;
  if (i >= n) return;
  u32 b1, b2; tf_block(ka, kb, 0u, (u32)i, b1, b2);
  idx[i] = (int)((b1 ^ b2) & (u32)mask);
}

__device__ __forceinline__ void emit_split(float v, f16* __restrict__ oh,
                                           f16* __restrict__ ol, size_t o) {
  f16 h = (f16)v;
  oh[o] = h;
  ol[o] = (f16)((v - (float)h) * 2048.0f);
}

// ---------------- positional embedding ----------------
__global__ void k_pe(float* __restrict__ pe) {
  int i = blockIdx.x * 256 + threadIdx.x;
  if (i >= 2048 * 512) return;
  int t = i >> 9, o = i & 511;
  float arg = (float)((o >> 1) * 2) * (float)(-(log(10000.0) / 512.0));
  float div = (float)exp((double)arg);
  float ang32 = (float)t * div;
  double ang = (double)ang32;
  pe[i] = (float)((o & 1) ? cos(ang) : sin(ang));
}

// ---------------- embedding (+ optional split emit) ----------------
__global__ __launch_bounds__(256) void k_embed(
    const float* __restrict__ x, const float* __restrict__ mark,
    const float* __restrict__ tw, const float* __restrict__ mw,
    const float* __restrict__ pe, float* __restrict__ o,
    f16* __restrict__ oh, f16* __restrict__ ol, int L, int total) {
  int i = blockIdx.x * 256 + threadIdx.x;
  if (i >= total) return;
  int oo = i & 511;
  int bt = i >> 9;
  int t = bt % L;
  int b = bt / L;
  float acc = pe[(t << 9) + oo];
  #pragma unroll
  for (int k = 0; k < 3; ++k) {
    int st = t + k - 1; if (st < 0) st += L; else if (st >= L) st -= L;
    const float* xr = x + (size_t)(b * L + st) * 7;
    const float* wr = tw + oo * 21 + k;
    #pragma unroll
    for (int ii = 0; ii < 7; ++ii) acc += xr[ii] * wr[ii * 3];
  }
  const float* mr = mark + (size_t)bt * 4;
  #pragma unroll
  for (int m = 0; m < 4; ++m) acc += mr[m] * mw[(m << 9) + oo];
  size_t oi = ((size_t)bt << 9) + oo;
  o[oi] = acc;
  if (oh) emit_split(acc, oh, ol, oi);
}

// ---------------- weight transpose + f16 split ----------------
__global__ __launch_bounds__(256) void k_wsplit(const float* __restrict__ W,
    f16* __restrict__ Wh, f16* __restrict__ Wl, int K, int N) {
  __shared__ float tile[32][33];
  int kb = blockIdx.x << 5, nb = blockIdx.y << 5;
  int t = threadIdx.x;
  int tr = t >> 5, tc = t & 31;
  #pragma unroll
  for (int p = 0; p < 4; ++p)
    tile[tr + p * 8][tc] = W[(size_t)(kb + tr + p * 8) * N + nb + tc];
  __syncthreads();
  #pragma unroll
  for (int p = 0; p < 4; ++p) {
    int n = tr + p * 8, k = tc;
    float v = tile[k][n];
    f16 h = (f16)v;
    size_t o = (size_t)(nb + n) * K + kb + k;
    Wh[o] = h;
    Wl[o] = (f16)((v - (float)h) * 2048.0f);
  }
}

__global__ void k_wsplit_conv(const float* __restrict__ w, f16* __restrict__ Wh, f16* __restrict__ Wl) {
  int i = blockIdx.x * 256 + threadIdx.x;
  if (i >= 512 * 1536) return;
  int o = i / 1536, k = i - o * 1536;
  float v = w[(size_t)o * 1536 + (k & 511) * 3 + (k >> 9)];
  f16 h = (f16)v;
  Wh[i] = h;
  Wl[i] = (f16)((v - (float)h) * 2048.0f);
}

// ---------------- activation split (fallback path only) ----------------
__global__ void k_asplit(const float* __restrict__ A, f16* __restrict__ Ah,
                         f16* __restrict__ Al, int total8) {
  int i = blockIdx.x * 256 + threadIdx.x;
  if (i >= total8) return;
  const float4* ap = (const float4*)(A + (size_t)i * 8);
  float4 u0 = ap[0], u1 = ap[1];
  float uv[8] = {u0.x, u0.y, u0.z, u0.w, u1.x, u1.y, u1.z, u1.w};
  f16 h8[8], l8[8];
  #pragma unroll
  for (int e = 0; e < 8; ++e) {
    f16 h = (f16)uv[e]; h8[e] = h; l8[e] = (f16)((uv[e] - (float)h) * 2048.0f);
  }
  *(f16x8*)(Ah + (size_t)i * 8) = *(f16x8*)h8;
  *(f16x8*)(Al + (size_t)i * 8) = *(f16x8*)l8;
}

__device__ __forceinline__ int swz_x(int r) { return ((((r >> 1) & 3) ^ ((r >> 3) & 3)) << 4); }

__device__ __forceinline__ void gload16(const void* g, void* l) {
  __builtin_amdgcn_global_load_lds(
      (const __attribute__((address_space(1))) void*)g,
      (__attribute__((address_space(3))) void*)l, 16, 0, 0);
}

// ---------------- MFMA GEMM v2: pre-split f16 A/B, async LDS, dbuf ----------------
// 3 MFMA/slot (fp32-equivalent). OSPLIT: C written as split f16 pair.
// GATHER: A rows gathered circularly (distil conv), K=1536, row len 512, L=2^lgL.
// ACT: 0 none, 1 gelu, 2 bn+elu
template<int ACT, int OSPLIT, int GATHER>
__global__ __launch_bounds__(256, 2) void k_mgemm2(
    const f16* __restrict__ Ah, const f16* __restrict__ Al,
    const f16* __restrict__ Bh, const f16* __restrict__ Bl,
    const float* __restrict__ bias, const float* __restrict__ resid,
    const float* __restrict__ bns, const float* __restrict__ bnb,
    float* __restrict__ C, f16* __restrict__ Ch, f16* __restrict__ Cl,
    int M, int N, int K, int lgL) {
  __shared__ char lds[65536];          // 2 bufs x 4 arrays x 8KB (128 rows x 64B)
  const int t = threadIdx.x;
  const int bm = blockIdx.y << 7, bn = blockIdx.x << 7;
  const int w = t >> 6, l = t & 63;
  const int lr = l >> 2;
  const int qx = (l & 3) << 4;
  const int wr = (w >> 1) << 6, wc = (w & 1) << 6;
  const int fr = l & 15;
  const int fkB = (l >> 4) << 4;
  const f32x4 zero = {0.f, 0.f, 0.f, 0.f};
  f32x4 acc1[4][4], acc2[4][4];
  #pragma unroll
  for (int i = 0; i < 4; ++i)
    #pragma unroll
    for (int j = 0; j < 4; ++j) { acc1[i][j] = zero; acc2[i][j] = zero; }

  auto stage = [&](int k0, int bufo) {
    #pragma unroll
    for (int c = 0; c < 2; ++c) {
      int r = w * 32 + c * 16 + lr;
      int sx = qx ^ swz_x(r);
      const char *gAh, *gAl;
      if (GATHER) {
        int m = bm + r;
        int Lm = 1 << lgL;
        int ab = m >> lgL, at = m & (Lm - 1);
        int ke = k0 + (sx >> 1);          // 8-f16-aligned, never crosses tap
        int tap = ke >> 9, ii = ke & 511;
        int st = at + tap - 1; if (st < 0) st += Lm; else if (st >= Lm) st -= Lm;
        size_t aoff = (((size_t)((ab << lgL) + st)) << 9) + ii;
        gAh = (const char*)(Ah + aoff);
        gAl = (const char*)(Al + aoff);
      } else {
        gAh = (const char*)(Ah + (size_t)(bm + r) * K + k0) + sx;
        gAl = (const char*)(Al + (size_t)(bm + r) * K + k0) + sx;
      }
      const char* gBh = (const char*)(Bh + (size_t)(bn + r) * K + k0) + sx;
      const char* gBl = (const char*)(Bl + (size_t)(bn + r) * K + k0) + sx;
      char* base = lds + bufo + w * 2048 + c * 1024;   // + lane*16 by HW
      gload16(gAh, base);
      gload16(gAl, base + 8192);
      gload16(gBh, base + 16384);
      gload16(gBl, base + 24576);
    }
  };

  int nt = K >> 5;
  stage(0, 0);
  __syncthreads();
  int bufo = 0;
  for (int tt = 0; tt < nt; ++tt) {
    int nb = bufo ^ 32768;
    if (tt + 1 < nt) stage((tt + 1) << 5, nb);
    char* pAh = lds + bufo;
    char* pAl = pAh + 8192;
    char* pBh = pAh + 16384;
    char* pBl = pAh + 24576;
    f16x8 ah4[4], al4[4];
    #pragma unroll
    for (int i = 0; i < 4; ++i) {
      int r = wr + i * 16 + fr;
      int ob = r * 64 + (fkB ^ swz_x(r));
      ah4[i] = *(f16x8*)(pAh + ob);
      al4[i] = *(f16x8*)(pAl + ob);
    }
    #pragma unroll
    for (int j = 0; j < 4; ++j) {
      int r = wc + j * 16 + fr;
      int ob = r * 64 + (fkB ^ swz_x(r));
      f16x8 bh_ = *(f16x8*)(pBh + ob);
      f16x8 bl_ = *(f16x8*)(pBl + ob);
      #pragma unroll
      for (int i = 0; i < 4; ++i) {
        acc1[i][j] = __builtin_amdgcn_mfma_f32_16x16x32_f16(ah4[i], bh_, acc1[i][j], 0, 0, 0);
        acc2[i][j] = __builtin_amdgcn_mfma_f32_16x16x32_f16(ah4[i], bl_, acc2[i][j], 0, 0, 0);
        acc2[i][j] = __builtin_amdgcn_mfma_f32_16x16x32_f16(al4[i], bh_, acc2[i][j], 0, 0, 0);
      }
    }
    __syncthreads();
    bufo = nb;
  }
  // ---- epilogue ----
  #pragma unroll
  for (int j = 0; j < 4; ++j) {
    int col = bn + wc + j * 16 + fr;
    float bsv = bias[col];
    float g2 = 0.f, b2 = 0.f;
    if (ACT == 2) { g2 = bns[col] * 0.9999950000375f; b2 = bnb[col]; }
    #pragma unroll
    for (int i = 0; i < 4; ++i) {
      #pragma unroll
      for (int r = 0; r < 4; ++r) {
        int row = bm + wr + i * 16 + ((l >> 4) << 2) + r;
        float v = acc1[i][j][r] + acc2[i][j][r] * (1.0f / 2048.0f) + bsv;
        if (ACT == 1) v = 0.5f * v * (1.0f + erff(v * 0.70710678118654752f));
        if (ACT == 2) { v = v * g2 + b2; v = v > 0.f ? v : expm1f(v); }
        if (OSPLIT) {
          emit_split(v, Ch, Cl, (size_t)row * N + col);
        } else {
          if (resid) v += resid[(size_t)row * N + col];
          C[(size_t)row * N + col] = v;
        }
      }
    }
  }
}

// ---------------- old reg-staged GEMM (fallback distil only) ----------------
template<int GATHER, int ACT>
__global__ __launch_bounds__(256, 2) void k_mgemm(
    const float* __restrict__ A, const f16* __restrict__ Bh, const f16* __restrict__ Bl,
    const float* __restrict__ bias, const float* __restrict__ resid,
    const float* __restrict__ bns, const float* __restrict__ bnb,
    float* __restrict__ C, int M, int N, int K, int L) {
  __shared__ char lds[32768];
  char* pAh = lds;
  char* pAl = lds + 8192;
  char* pBh = lds + 16384;
  char* pBl = lds + 24576;
  const int t = threadIdx.x;
  const int bm = blockIdx.y << 7, bn = blockIdx.x << 7;
  const int sr = t >> 1;
  const int e0 = (t & 1) << 4;
  int ab = 0, at = 0;
  if (GATHER) { int m = bm + sr; ab = m / L; at = m - ab * L; }
  const int lane = t & 63, wid = t >> 6;
  const int wr = (wid >> 1) << 6, wc = (wid & 1) << 6;
  const int fr = lane & 15;
  const int fkB = (lane >> 4) << 4;
  const f32x4 zero = {0.f, 0.f, 0.f, 0.f};
  f32x4 acc1[4][4], acc2[4][4];
  #pragma unroll
  for (int i = 0; i < 4; ++i)
    #pragma unroll
    for (int j = 0; j < 4; ++j) { acc1[i][j] = zero; acc2[i][j] = zero; }

  const int sxor = swz_x(sr);
  for (int k0 = 0; k0 < K; k0 += 32) {
    __syncthreads();
    const float* ap;
    if (GATHER) {
      int kk = k0 + e0;
      int tap = kk >> 9, ii = kk & 511;
      int st = at + tap - 1; if (st < 0) st += L; else if (st >= L) st -= L;
      ap = A + (((size_t)(ab * L + st)) << 9) + ii;
    } else {
      ap = A + (size_t)(bm + sr) * K + k0 + e0;
    }
    float va[16];
    *(float4*)(va + 0)  = ((const float4*)ap)[0];
    *(float4*)(va + 4)  = ((const float4*)ap)[1];
    *(float4*)(va + 8)  = ((const float4*)ap)[2];
    *(float4*)(va + 12) = ((const float4*)ap)[3];
    f16 h16[16], l16[16];
    #pragma unroll
    for (int q = 0; q < 16; ++q) {
      f16 h = (f16)va[q]; h16[q] = h; l16[q] = (f16)((va[q] - (float)h) * 2048.0f);
    }
    {
      int ob0 = sr * 64 + ((e0 * 2) ^ sxor);
      int ob1 = sr * 64 + ((e0 * 2 + 16) ^ sxor);
      *(f16x8*)(pAh + ob0) = *(f16x8*)h16;
      *(f16x8*)(pAh + ob1) = *(f16x8*)(h16 + 8);
      *(f16x8*)(pAl + ob0) = *(f16x8*)l16;
      *(f16x8*)(pAl + ob1) = *(f16x8*)(l16 + 8);
    }
    {
      const f16* bhp = Bh + (size_t)(bn + sr) * K + k0 + e0;
      const f16* blp = Bl + (size_t)(bn + sr) * K + k0 + e0;
      int ob0 = sr * 64 + ((e0 * 2) ^ sxor);
      int ob1 = sr * 64 + ((e0 * 2 + 16) ^ sxor);
      *(f16x8*)(pBh + ob0) = *(const f16x8*)(bhp);
      *(f16x8*)(pBh + ob1) = *(const f16x8*)(bhp + 8);
      *(f16x8*)(pBl + ob0) = *(const f16x8*)(blp);
      *(f16x8*)(pBl + ob1) = *(const f16x8*)(blp + 8);
    }
    __syncthreads();
    f16x8 ah4[4], al4[4];
    #pragma unroll
    for (int i = 0; i < 4; ++i) {
      int r = wr + i * 16 + fr;
      int ob = r * 64 + (fkB ^ swz_x(r));
      ah4[i] = *(f16x8*)(pAh + ob);
      al4[i] = *(f16x8*)(pAl + ob);
    }
    #pragma unroll
    for (int j = 0; j < 4; ++j) {
      int r = wc + j * 16 + fr;
      int ob = r * 64 + (fkB ^ swz_x(r));
      f16x8 bh_ = *(f16x8*)(pBh + ob);
      f16x8 bl_ = *(f16x8*)(pBl + ob);
      #pragma unroll
      for (int i = 0; i < 4; ++i) {
        acc1[i][j] = __builtin_amdgcn_mfma_f32_16x16x32_f16(ah4[i], bh_, acc1[i][j], 0, 0, 0);
        acc2[i][j] = __builtin_amdgcn_mfma_f32_16x16x32_f16(ah4[i], bl_, acc2[i][j], 0, 0, 0);
        acc2[i][j] = __builtin_amdgcn_mfma_f32_16x16x32_f16(al4[i], bh_, acc2[i][j], 0, 0, 0);
      }
    }
  }
  #pragma unroll
  for (int j = 0; j < 4; ++j) {
    int col = bn + wc + j * 16 + fr;
    float bsv = bias[col];
    float g2 = 0.f, b2 = 0.f;
    if (ACT == 2) { g2 = bns[col] * 0.9999950000375f; b2 = bnb[col]; }
    #pragma unroll
    for (int i = 0; i < 4; ++i) {
      #pragma unroll
      for (int r = 0; r < 4; ++r) {
        int row = bm + wr + i * 16 + ((lane >> 4) << 2) + r;
        float v = acc1[i][j][r] + acc2[i][j][r] * (1.0f / 2048.0f) + bsv;
        if (ACT == 1) v = 0.5f * v * (1.0f + erff(v * 0.70710678118654752f));
        if (ACT == 2) { v = v * g2 + b2; v = v > 0.f ? v : expm1f(v); }
        if (resid) v += resid[(size_t)row * N + col];
        C[(size_t)row * N + col] = v;
      }
    }
  }
}

// ---------------- LayerNorm (dim 512, in-place safe, optional split emit) ----------------
__global__ __launch_bounds__(256) void k_ln(const float* __restrict__ x,
    const float* __restrict__ g, const float* __restrict__ b, float* __restrict__ o,
    f16* __restrict__ oh, f16* __restrict__ ol) {
  int row = blockIdx.x, t = threadIdx.x;
  const float* xr = x + ((size_t)row << 9);
  float v0 = xr[t], v1 = xr[t + 256];
  float s = v0 + v1;
  #pragma unroll
  for (int off = 32; off; off >>= 1) s += __shfl_down(s, off);
  __shared__ float ls[4];
  if ((t & 63) == 0) ls[t >> 6] = s;
  __syncthreads();
  float mean = (ls[0] + ls[1] + ls[2] + ls[3]) * (1.f / 512.f);
  __syncthreads();
  float d0 = v0 - mean, d1 = v1 - mean;
  float q = d0 * d0 + d1 * d1;
  #pragma unroll
  for (int off = 32; off; off >>= 1) q += __shfl_down(q, off);
  if ((t & 63) == 0) ls[t >> 6] = q;
  __syncthreads();
  float var = (ls[0] + ls[1] + ls[2] + ls[3]) * (1.f / 512.f);
  float rs = rsqrtf(var + 1e-5f);
  float* orow = o + ((size_t)row << 9);
  float r0 = d0 * rs * g[t] + b[t];
  float r1 = d1 * rs * g[t + 256] + b[t + 256];
  orow[t] = r0;
  orow[t + 256] = r1;
  if (oh) {
    size_t base = (size_t)row << 9;
    emit_split(r0, oh, ol, base + t);
    emit_split(r1, oh, ol, base + t + 256);
  }
}

// ---------------- M[bh,l] scoring (strided Q/K) ----------------
__global__ __launch_bounds__(256) void k_qkM(const float* __restrict__ Q, int qstr,
    const float* __restrict__ Kp, int kstr, const int* __restrict__ idx,
    float* __restrict__ M, int Lq, int Lk, int U) {
  int wid = (blockIdx.x * 256 + threadIdx.x) >> 6;
  int lane = threadIdx.x & 63;
  int l = wid & (Lq - 1); int bh = wid / Lq; int h = bh & 7; int b = bh >> 3;
  float dot = 0.f;
  if (lane < U) {
    int kr = idx[l * U + lane];
    const float4* q4 = (const float4*)(Q + (size_t)(b * Lq + l) * qstr + (h << 6));
    const float4* k4 = (const float4*)(Kp + (size_t)(b * Lk + kr) * kstr + (h << 6));
    #pragma unroll
    for (int i = 0; i < 16; ++i) {
      float4 a = q4[i], c = k4[i];
      dot += a.x * c.x + a.y * c.y + a.z * c.z + a.w * c.w;
    }
  }
  float mx = (lane < U) ? dot : -INFINITY;
  float sm = (lane < U) ? dot : 0.f;
  #pragma unroll
  for (int off = 32; off; off >>= 1) {
    mx = fmaxf(mx, __shfl_xor(mx, off));
    sm += __shfl_xor(sm, off);
  }
  if (lane == 0) M[(size_t)bh * Lq + l] = mx - sm / (float)Lk;
}

// ---------------- single-wave top-u per (b,h), ties -> lower index ----------------
__global__ void k_topk64(const float* __restrict__ M, int* __restrict__ mtop, int Lq, int u) {
  __shared__ float vals[2048];
  int bh = blockIdx.x, l = threadIdx.x;
  const float* Mr = M + (size_t)bh * Lq;
  for (int i = l; i < Lq; i += 64) vals[i] = Mr[i];
  __syncthreads();
  for (int it = 0; it < u; ++it) {
    float bv = -INFINITY; int bi = 0x7fffffff;
    for (int i = l; i < Lq; i += 64) {
      float v = vals[i];
      if (v > bv || (v == bv && i < bi)) { bv = v; bi = i; }
    }
    #pragma unroll
    for (int off = 32; off; off >>= 1) {
      float vv = __shfl_xor(bv, off); int ii = __shfl_xor(bi, off);
      if (vv > bv || (vv == bv && ii < bi)) { bv = vv; bi = ii; }
    }
    if (l == 0) { mtop[bh * u + it] = bi; vals[bi] = -INFINITY; }
    __syncthreads();
  }
}

// ---------------- ctx mean (AO written as split pair) ----------------
__global__ void k_cm1(const float* __restrict__ V, int vstr, float* __restrict__ PS,
                      int Lk, int rows) {
  int bid = blockIdx.x;
  int bh = bid >> 4, seg = bid & 15, d = threadIdx.x;
  int b = bh >> 3, h = bh & 7;
  const float* vp = V + (size_t)(b * Lk + seg * rows) * vstr + (h << 6) + d;
  float acc = 0.f;
  for (int r = 0; r < rows; ++r) acc += vp[(size_t)r * vstr];
  PS[(bid << 6) + d] = acc;
}
__global__ void k_cm2(const float* __restrict__ PS, f16* __restrict__ AOh,
                      f16* __restrict__ AOl, float invLk, int Lq, int total) {
  int i = blockIdx.x * 256 + threadIdx.x;
  if (i >= total) return;
  int c = i & 511; int h = c >> 6; int d = c & 63;
  int r = i >> 9; int b = r / Lq;
  float acc = 0.f;
  #pragma unroll
  for (int s = 0; s < 16; ++s) acc += PS[(((((b << 3) + h) << 4) + s) << 6) + d];
  emit_split(acc * invLk, AOh, AOl, (size_t)i);
}

// ---------------- cumsum (masked ctx; AO split) ----------------
__global__ void k_cs1(const float* __restrict__ V, int vstr, float* __restrict__ PS,
                      int Lq, int rows) {
  int bid = blockIdx.x;
  int bh = bid >> 3, seg = bid & 7, d = threadIdx.x;
  int b = bh >> 3, h = bh & 7;
  const float* vp = V + (size_t)(b * Lq + seg * rows) * vstr + (h << 6) + d;
  float acc = 0.f;
  for (int r = 0; r < rows; ++r) acc += vp[(size_t)r * vstr];
  PS[(bid << 6) + d] = acc;
}
__global__ void k_cs2(float* __restrict__ PS) {
  int bh = blockIdx.x, d = threadIdx.x;
  float run = 0.f;
  for (int s = 0; s < 8; ++s) {
    int id = (((bh << 3) + s) << 6) + d;
    float t0 = PS[id]; PS[id] = run; run += t0;
  }
}
__global__ void k_cs3(const float* __restrict__ V, int vstr, const float* __restrict__ PS,
                      f16* __restrict__ AOh, f16* __restrict__ AOl, int Lq, int rows) {
  int bid = blockIdx.x;
  int bh = bid >> 3, seg = bid & 7, d = threadIdx.x;
  int b = bh >> 3, h = bh & 7;
  float acc = PS[(bid << 6) + d];
  const float* vp = V + (size_t)(b * Lq + seg * rows) * vstr + (h << 6) + d;
  size_t ob = ((size_t)(b * Lq + seg * rows) << 9) + (h << 6) + d;
  for (int r = 0; r < rows; ++r) {
    acc += vp[(size_t)r * vstr];
    emit_split(acc, AOh, AOl, ob + ((size_t)r << 9));
  }
}

// ---------------- sparse attn: 4 selected rows per block (AO split) ----------------
__global__ __launch_bounds__(256) void k_sattn4(
    const float* __restrict__ Q, int qstr, const float* __restrict__ Kp, int kstr,
    const float* __restrict__ Vp, int vstr, const int* __restrict__ mtop,
    f16* __restrict__ AOh, f16* __restrict__ AOl, int Lq, int Lk, int u, int masked) {
  __shared__ float sc[4][2048];
  __shared__ float qs[4][64];
  __shared__ float red[4][256];
  __shared__ float pv[4][4][64];
  __shared__ int rowsh[4];
  __shared__ float mxs[4], sss[4];
  int nb = (u + 3) >> 2;
  int ub = blockIdx.x % nb, bh = blockIdx.x / nb;
  int b = bh >> 3, h = bh & 7;
  int t = threadIdx.x;
  if (t < 4) {
    int ui = ub * 4 + t;
    rowsh[t] = (ui < u) ? mtop[bh * u + ui] : -1;
  }
  __syncthreads();
  {
    int r = t >> 6, d = t & 63;
    int row = rowsh[r];
    qs[r][d] = (row >= 0) ? Q[(size_t)(b * Lq + row) * qstr + (h << 6) + d] : 0.f;
  }
  __syncthreads();
  float lm0 = -INFINITY, lm1 = -INFINITY, lm2 = -INFINITY, lm3 = -INFINITY;
  for (int c = t; c < Lk; c += 256) {
    const float4* kr = (const float4*)(Kp + (size_t)(b * Lk + c) * kstr + (h << 6));
    float d0 = 0.f, d1 = 0.f, d2 = 0.f, d3 = 0.f;
    #pragma unroll
    for (int e = 0; e < 16; ++e) {
      float4 kk = kr[e];
      d0 += qs[0][4*e]*kk.x + qs[0][4*e+1]*kk.y + qs[0][4*e+2]*kk.z + qs[0][4*e+3]*kk.w;
      d1 += qs[1][4*e]*kk.x + qs[1][4*e+1]*kk.y + qs[1][4*e+2]*kk.z + qs[1][4*e+3]*kk.w;
      d2 += qs[2][4*e]*kk.x + qs[2][4*e+1]*kk.y + qs[2][4*e+2]*kk.z + qs[2][4*e+3]*kk.w;
      d3 += qs[3][4*e]*kk.x + qs[3][4*e+1]*kk.y + qs[3][4*e+2]*kk.z + qs[3][4*e+3]*kk.w;
    }
    float dd[4] = {d0, d1, d2, d3};
    #pragma unroll
    for (int r = 0; r < 4; ++r) {
      float v = dd[r] * 0.125f;
      if (masked && c > rowsh[r]) v = -INFINITY;
      sc[r][c] = v;
    }
    lm0 = fmaxf(lm0, sc[0][c]); lm1 = fmaxf(lm1, sc[1][c]);
    lm2 = fmaxf(lm2, sc[2][c]); lm3 = fmaxf(lm3, sc[3][c]);
  }
  red[0][t] = lm0; red[1][t] = lm1; red[2][t] = lm2; red[3][t] = lm3;
  __syncthreads();
  {
    int w = t >> 6, lane = t & 63;
    float m = fmaxf(fmaxf(red[w][lane], red[w][lane + 64]),
                    fmaxf(red[w][lane + 128], red[w][lane + 192]));
    #pragma unroll
    for (int off = 32; off; off >>= 1) m = fmaxf(m, __shfl_xor(m, off));
    if (lane == 0) mxs[w] = m;
  }
  __syncthreads();
  float ls0 = 0.f, ls1 = 0.f, ls2 = 0.f, ls3 = 0.f;
  float m0 = mxs[0], m1 = mxs[1], m2 = mxs[2], m3 = mxs[3];
  for (int c = t; c < Lk; c += 256) {
    float e0 = expf(sc[0][c] - m0); sc[0][c] = e0; ls0 += e0;
    float e1 = expf(sc[1][c] - m1); sc[1][c] = e1; ls1 += e1;
    float e2 = expf(sc[2][c] - m2); sc[2][c] = e2; ls2 += e2;
    float e3 = expf(sc[3][c] - m3); sc[3][c] = e3; ls3 += e3;
  }
  red[0][t] = ls0; red[1][t] = ls1; red[2][t] = ls2; red[3][t] = ls3;
  __syncthreads();
  {
    int w = t >> 6, lane = t & 63;
    float s = red[w][lane] + red[w][lane + 64] + red[w][lane + 128] + red[w][lane + 192];
    #pragma unroll
    for (int off = 32; off; off >>= 1) s += __shfl_xor(s, off);
    if (lane == 0) sss[w] = s;
  }
  __syncthreads();
  {
    int g = t >> 6, d = t & 63;
    float a0 = 0.f, a1 = 0.f, a2 = 0.f, a3 = 0.f;
    for (int c = g; c < Lk; c += 4) {
      float v = Vp[(size_t)(b * Lk + c) * vstr + (h << 6) + d];
      a0 += sc[0][c] * v; a1 += sc[1][c] * v; a2 += sc[2][c] * v; a3 += sc[3][c] * v;
    }
    pv[g][0][d] = a0; pv[g][1][d] = a1; pv[g][2][d] = a2; pv[g][3][d] = a3;
  }
  __syncthreads();
  {
    int r = t >> 6, d = t & 63;
    int row = rowsh[r];
    if (row >= 0) {
      float s = (pv[0][r][d] + pv[1][r][d] + pv[2][r][d] + pv[3][r][d]) / sss[r];
      emit_split(s, AOh, AOl, ((size_t)(b * Lq + row) << 9) + (h << 6) + d);
    }
  }
}

// ---------------- maxpool w3 s2 p1 along L (+ split emit) ----------------
__global__ void k_maxpool(const float* __restrict__ y, float* __restrict__ o,
                          f16* __restrict__ oh, f16* __restrict__ ol, int L) {
  int Lo = L >> 1;
  int i = blockIdx.x * 256 + threadIdx.x;
  int c = i & 511; int bj = i >> 9;
  int j = bj % Lo; int b = bj / Lo;
  float m = -INFINITY;
  int t0 = 2 * j - 1;
  #pragma unroll
  for (int k = 0; k < 3; ++k) {
    int tt = t0 + k;
    if (tt >= 0 && tt < L) m = fmaxf(m, y[((size_t)(b * L + tt) << 9) + c]);
  }
  size_t oi = ((size_t)(b * Lo + j) << 9) + c;
  o[oi] = m;
  if (oh) emit_split(m, oh, ol, oi);
}

// ---------------- final projection 512->7 ----------------
__global__ void k_proj(const float* __restrict__ Xn, const float* __restrict__ pw,
                       const float* __restrict__ pb, float* __restrict__ out) {
  int i = blockIdx.x * 256 + threadIdx.x;
  if (i >= 16 * 512 * 7) return;
  int c = i % 7; int r = i / 7;
  int b = r >> 9; int j = r & 511;
  const float* xr = Xn + ((size_t)(b * 1024 + 512 + j) << 9);
  float acc = pb[c];
  for (int d2 = 0; d2 < 512; ++d2) acc += xr[d2] * pw[d2 * 7 + c];
  out[i] = acc;
}

// =====================================================================
extern "C" void kernel_launch(void* const* d_in, const int* in_sizes, int n_in,
                              void* d_out, int out_size, void* d_ws, size_t ws_size,
                              hipStream_t stream) {
  const float* x_enc      = (const float*)d_in[0];
  const float* x_mark_enc = (const float*)d_in[1];
  const float* x_dec      = (const float*)d_in[2];
  const float* x_mark_dec = (const float*)d_in[3];
  const float* enc_tok_w  = (const float*)d_in[4];
  const float* enc_mark_w = (const float*)d_in[5];
  const float* dec_tok_w  = (const float*)d_in[6];
  const float* dec_mark_w = (const float*)d_in[7];
  const float* enc_attn_w = (const float*)d_in[8];
  const float* enc_attn_b = (const float*)d_in[9];
  const float* enc_ffn1_w = (const float*)d_in[10];
  const float* enc_ffn1_b = (const float*)d_in[11];
  const float* enc_ffn2_w = (const float*)d_in[12];
  const float* enc_ffn2_b = (const float*)d_in[13];
  const float* enc_ln_g   = (const float*)d_in[14];
  const float* enc_ln_b   = (const float*)d_in[15];
  const float* distil_w   = (const float*)d_in[16];
  const float* distil_b   = (const float*)d_in[17];
  const float* distil_bn_g= (const float*)d_in[18];
  const float* distil_bn_b= (const float*)d_in[19];
  const float* enc_norm_g = (const float*)d_in[20];
  const float* enc_norm_b = (const float*)d_in[21];
  const float* dec_self_w = (const float*)d_in[22];
  const float* dec_self_b = (const float*)d_in[23];
  const float* dec_cross_w= (const float*)d_in[24];
  const float* dec_cross_b= (const float*)d_in[25];
  const float* dec_ffn1_w = (const float*)d_in[26];
  const float* dec_ffn1_b = (const float*)d_in[27];
  const float* dec_ffn2_w = (const float*)d_in[28];
  const float* dec_ffn2_b = (const float*)d_in[29];
  const float* dec_ln_g   = (const float*)d_in[30];
  const float* dec_ln_b   = (const float*)d_in[31];
  const float* dec_norm_g = (const float*)d_in[32];
  const float* dec_norm_b = (const float*)d_in[33];
  const float* proj_w     = (const float*)d_in[34];
  const float* proj_b     = (const float*)d_in[35];

  // -------- workspace layout --------
  float* ws = (float*)d_ws;
  size_t off = 0;
  float* X   = ws + off; off += 16777216;
  float* Y   = ws + off; off += 16777216;
  float* ENC = ws + off; off += 4194304;
  float* PE  = ws + off; off += 1048576;
  float* Mb  = ws + off; off += 65536;
  float* PS  = ws + off; off += 32768;
  f16*  WSP  = (f16*)(ws + off); off += 2097152;   // 4.19M f16
  float* SH  = ws + off;                            // shadow/ASP region
  size_t smallSH = 4194304;                         // 8.39M f16 (ASP pair)
  size_t bigSH   = 16777216 + 4194304;              // Xh/Xl (33.55M f16) + ENC split (8.39M f16)
  size_t needSmall = (off + smallSH) * 4 + (81920 + 1280) * 4;
  size_t needBig   = (off + bigSH) * 4 + (81920 + 1280) * 4;
  bool big = (ws_size >= needBig);
  if (ws_size < needSmall) return;
  f16 *Xh = nullptr, *Xl = nullptr, *ENCh = nullptr, *ENCl = nullptr;
  f16 *ASPh = nullptr, *ASPl = nullptr;
  int* IDXi;
  if (big) {
    Xh = (f16*)SH;                 // 16.78M f16
    Xl = Xh + 16777216;
    ENCh = Xl + 16777216;          // 4.19M f16
    ENCl = ENCh + 4194304;
    IDXi = (int*)(ws + off + bigSH);
  } else {
    ASPh = (f16*)SH;               // 4.19M f16
    ASPl = ASPh + 4194304;
    IDXi = (int*)(ws + off + smallSH);
  }
  int* MTi = IDXi + 81920;
  f16* Yh = (f16*)Y;               // FFN1 split output aliases Y
  f16* Yl = Yh + 16777216;

  auto ln = [&](const float* x, const float* g, const float* b, float* o, int rows,
                f16* oh, f16* ol) {
    k_ln<<<rows, 256, 0, stream>>>(x, g, b, o, oh, ol);
  };
  auto wsplit = [&](const float* W, f16* Wh, f16* Wl, int K, int N) {
    dim3 g(K >> 5, N >> 5);
    k_wsplit<<<g, 256, 0, stream>>>(W, Wh, Wl, K, N);
  };
  auto asplit = [&](const float* A, int M, int K) {
    int t8 = (M * K) >> 3;
    k_asplit<<<(t8 + 255) / 256, 256, 0, stream>>>(A, ASPh, ASPl, t8);
  };
  auto mg2 = [&](const f16* Ah, const f16* Al, const f16* Wh, const f16* Wl,
                 const float* bias, const float* resid, float* C, int M, int N, int K) {
    dim3 g(N >> 7, M >> 7);
    k_mgemm2<0,0,0><<<g, 256, 0, stream>>>(Ah, Al, Wh, Wl, bias, resid, nullptr, nullptr,
                                           C, nullptr, nullptr, M, N, K, 0);
  };
  auto mg2gs = [&](const f16* Ah, const f16* Al, const f16* Wh, const f16* Wl,
                   const float* bias, f16* Ch, f16* Cl, int M, int N, int K) {
    dim3 g(N >> 7, M >> 7);
    k_mgemm2<1,1,0><<<g, 256, 0, stream>>>(Ah, Al, Wh, Wl, bias, nullptr, nullptr, nullptr,
                                           nullptr, Ch, Cl, M, N, K, 0);
  };
  auto Uof = [](int Lx) { int v = 5 * (int)ceil(log((double)Lx)); return v < Lx ? v : Lx; };

  // ProbSparse attention over 4 z-slices of 4 batches each.
  // xqh/xql: split of xq base (or null -> fallback asplit). Same for xkv.
  auto attn = [&](float* xq_base, const f16* xqh, const f16* xql,
                  const float* xkv_base, const f16* xkvh, const f16* xkvl,
                  int Lq, int Lk, const float* w, const float* bias,
                  bool masked, u32 fold, bool selfa) {
    int U = Uof(Lk), uu = Uof(Lq);
    u32 r0, r1, ka, kb2;
    tf_block(0u, 42u, 0u, fold, r0, r1);   // fold_in(key(42), fold)
    tf_block(r0, r1, 0u, 1u, ka, kb2);     // randint internal split -> k2
    int n = Lq * U;
    k_idx<<<(n + 255) / 256, 256, 0, stream>>>(ka, kb2, n, Lk - 1, IDXi);

    f16 *Wqkvh = WSP,            *Wqkvl = WSP + 786432;
    f16 *WQh   = WSP,            *WQl   = WSP + 262144;
    f16 *WKVh  = WSP + 524288,   *WKVl  = WSP + 1048576;
    f16 *WOh   = WSP + 1572864,  *WOl   = WSP + 1835008;
    if (selfa) {
      for (int i = 0; i < 3; ++i)
        wsplit(w + (size_t)i * 262144, Wqkvh + (size_t)i * 262144, Wqkvl + (size_t)i * 262144, 512, 512);
    } else {
      wsplit(w, WQh, WQl, 512, 512);
      for (int i = 0; i < 2; ++i)
        wsplit(w + 262144 + (size_t)i * 262144, WKVh + (size_t)i * 262144, WKVl + (size_t)i * 262144, 512, 512);
    }
    wsplit(w + 786432, WOh, WOl, 512, 512);

    for (int s = 0; s < 4; ++s) {
      size_t qoff = (size_t)s * 4 * Lq * 512;
      size_t koff = (size_t)s * 4 * Lk * 512;
      float* xq = xq_base + qoff;
      const float *qp, *kp, *vp;
      int qstr, kstr, vstr;
      f16 *AOh, *AOl;
      if (selfa) {
        float* QKV = Y;
        AOh = (f16*)(Y + (size_t)4 * Lq * 1536);
        AOl = AOh + (size_t)4 * Lq * 512;
        const f16 *ah, *al;
        if (xqh) { ah = xqh + qoff; al = xql + qoff; }
        else { asplit(xq, 4 * Lq, 512); ah = ASPh; al = ASPl; }
        mg2(ah, al, Wqkvh, Wqkvl, bias, nullptr, QKV, 4 * Lq, 1536, 512);
        qp = QKV; qstr = 1536; kp = QKV + 512; kstr = 1536; vp = QKV + 1024; vstr = 1536;
      } else {
        float* Qb  = Y;
        float* KVb = Y + (size_t)4 * Lq * 512;
        AOh = (f16*)(KVb + (size_t)4 * Lk * 1024);
        AOl = AOh + (size_t)4 * Lq * 512;
        const f16 *ah, *al;
        if (xqh) { ah = xqh + qoff; al = xql + qoff; }
        else { asplit(xq, 4 * Lq, 512); ah = ASPh; al = ASPl; }
        mg2(ah, al, WQh, WQl, bias, nullptr, Qb, 4 * Lq, 512, 512);
        if (xkvh) { ah = xkvh + koff; al = xkvl + koff; }
        else { asplit(xkv_base + koff, 4 * Lk, 512); ah = ASPh; al = ASPl; }
        mg2(ah, al, WKVh, WKVl, bias + 512, nullptr, KVb, 4 * Lk, 1024, 512);
        qp = Qb; qstr = 512; kp = KVb; kstr = 1024; vp = KVb + 512; vstr = 1024;
      }
      int wids = 32 * Lq;
      k_qkM<<<wids / 4, 256, 0, stream>>>(qp, qstr, kp, kstr, IDXi, Mb, Lq, Lk, U);
      k_topk64<<<32, 64, 0, stream>>>(Mb, MTi, Lq, uu);
      if (masked) {
        k_cs1<<<256, 64, 0, stream>>>(vp, vstr, PS, Lq, Lq >> 3);
        k_cs2<<<32, 64, 0, stream>>>(PS);
        k_cs3<<<256, 64, 0, stream>>>(vp, vstr, PS, AOh, AOl, Lq, Lq >> 3);
      } else {
        k_cm1<<<512, 64, 0, stream>>>(vp, vstr, PS, Lk, Lk >> 4);
        int tot = 4 * Lq * 512;
        k_cm2<<<tot / 256, 256, 0, stream>>>(PS, AOh, AOl, 1.0f / (float)Lk, Lq, tot);
      }
      int nbb = (uu + 3) >> 2;
      k_sattn4<<<32 * nbb, 256, 0, stream>>>(qp, qstr, kp, kstr, vp, vstr, MTi, AOh, AOl,
                                             Lq, Lk, uu, masked ? 1 : 0);
      mg2(AOh, AOl, WOh, WOl, bias + 1536, xq, xq, 4 * Lq, 512, 512);
    }
  };

  auto ffn = [&](float* x, const f16* xh, const f16* xl, const float* w1, const float* b1,
                 const float* w2, const float* b2, int Mtot) {
    f16 *W1h = WSP,           *W1l = WSP + 1048576,
        *W2h = WSP + 2097152, *W2l = WSP + 3145728;
    wsplit(w1, W1h, W1l, 512, 2048);
    wsplit(w2, W2h, W2l, 2048, 512);
    for (int c0 = 0; c0 < Mtot; c0 += 8192) {
      const f16 *ah, *al;
      if (xh) { ah = xh + (size_t)c0 * 512; al = xl + (size_t)c0 * 512; }
      else { asplit(x + (size_t)c0 * 512, 8192, 512); ah = ASPh; al = ASPl; }
      mg2gs(ah, al, W1h, W1l, b1, Yh, Yl, 8192, 2048, 512);
      mg2(Yh, Yl, W2h, W2l, b2, x + (size_t)c0 * 512, x + (size_t)c0 * 512, 8192, 512, 2048);
    }
  };

  // ---------------- encoder ----------------
  k_pe<<<(2048 * 512) / 256, 256, 0, stream>>>(PE);
  k_embed<<<(16 * 2048 * 512) / 256, 256, 0, stream>>>(x_enc, x_mark_enc, enc_tok_w, enc_mark_w,
                                                       PE, X, Xh, Xl, 2048, 16 * 2048 * 512);
  int L = 2048;
  for (int l = 0; l < 3; ++l) {
    attn(X, Xh, Xl, X, Xh, Xl, L, L, enc_attn_w + (size_t)l * 4 * 262144,
         enc_attn_b + (size_t)l * 2048, false, (u32)l, true);
    ln(X, enc_ln_g + (size_t)(l * 2) * 512, enc_ln_b + (size_t)(l * 2) * 512, X, 16 * L, Xh, Xl);
    ffn(X, Xh, Xl, enc_ffn1_w + (size_t)l * 512 * 2048, enc_ffn1_b + (size_t)l * 2048,
        enc_ffn2_w + (size_t)l * 2048 * 512, enc_ffn2_b + (size_t)l * 512, 16 * L);
    // post-FFN ln: split needed for distil (big) / next attn; last layer feeds enc_norm (f32)
    bool needSplit = (l < 2);
    ln(X, enc_ln_g + (size_t)(l * 2 + 1) * 512, enc_ln_b + (size_t)(l * 2 + 1) * 512, X, 16 * L,
       needSplit ? Xh : nullptr, needSplit ? Xl : nullptr);
    if (l < 2) {
      f16 *Dh = WSP, *Dl = WSP + 786432;
      k_wsplit_conv<<<(512 * 1536) / 256, 256, 0, stream>>>(distil_w + (size_t)l * 512 * 512 * 3, Dh, Dl);
      dim3 g(512 >> 7, (16 * L) >> 7);
      if (big) {
        int lgL = (L == 2048) ? 11 : 10;
        k_mgemm2<2,0,1><<<g, 256, 0, stream>>>(Xh, Xl, Dh, Dl, distil_b + (size_t)l * 512,
            nullptr, distil_bn_g + (size_t)l * 512, distil_bn_b + (size_t)l * 512,
            Y, nullptr, nullptr, 16 * L, 512, 1536, lgL);
      } else {
        k_mgemm<1,2><<<g, 256, 0, stream>>>(X, Dh, Dl, distil_b + (size_t)l * 512, nullptr,
            distil_bn_g + (size_t)l * 512, distil_bn_b + (size_t)l * 512, Y, 16 * L, 512, 1536, L);
      }
      int Lo = L >> 1;
      k_maxpool<<<(16 * Lo * 512) / 256, 256, 0, stream>>>(Y, X, Xh, Xl, L);
      L = Lo;
    }
  }
  ln(X, enc_norm_g, enc_norm_b, ENC, 16 * 512, ENCh, ENCl);

  // ---------------- decoder (in-place chain in X) ----------------
  k_embed<<<(16 * 1024 * 512) / 256, 256, 0, stream>>>(x_dec, x_mark_dec, dec_tok_w, dec_mark_w,
                                                       PE, X, Xh, Xl, 1024, 16 * 1024 * 512);
  for (int l = 0; l < 2; ++l) {
    attn(X, Xh, Xl, X, Xh, Xl, 1024, 1024, dec_self_w + (size_t)l * 4 * 262144,
         dec_self_b + (size_t)l * 2048, true, (u32)(100 + 2 * l), true);
    ln(X, dec_ln_g + (size_t)(l * 3) * 512, dec_ln_b + (size_t)(l * 3) * 512, X, 16384, Xh, Xl);
    attn(X, Xh, Xl, ENC, ENCh, ENCl, 1024, 512, dec_cross_w + (size_t)l * 4 * 262144,
         dec_cross_b + (size_t)l * 2048, false, (u32)(101 + 2 * l), false);
    ln(X, dec_ln_g + (size_t)(l * 3 + 1) * 512, dec_ln_b + (size_t)(l * 3 + 1) * 512, X, 16384, Xh, Xl);
    ffn(X, Xh, Xl, dec_ffn1_w + (size_t)l * 512 * 2048, dec_ffn1_b + (size_t)l * 2048,
        dec_ffn2_w + (size_t)l * 2048 * 512, dec_ffn2_b + (size_t)l * 512, 16384);
    bool needSplit = (l == 0);
    ln(X, dec_ln_g + (size_t)(l * 3 + 2) * 512, dec_ln_b + (size_t)(l * 3 + 2) * 512, X, 16384,
       needSplit ? Xh : nullptr, needSplit ? Xl : nullptr);
  }
  ln(X, dec_norm_g, dec_norm_b, X, 16384, nullptr, nullptr);
  k_proj<<<(16 * 512 * 7 + 255) / 256, 256, 0, stream>>>(X, proj_w, proj_b, (float*)d_out);
}